// Round 1
// baseline (947.428 us; speedup 1.0000x reference)
//
#include <hip/hip_runtime.h>
#include <math.h>

#define NL   4
#define H    256
#define NST  64
#define CIN  64
#define COUT 8
#define BB   8
#define LL   1024
#define NFFT 2048

// ---------------------------------------------------------------------------
// 2048-point complex FFT, Stockham autosort (natural order in/out), radix-2,
// 256 threads, 11 stages, ping-pong between (sre,sim) and (dre,dim).
// Result ends in the SECOND buffer pair (b1) since 11 is odd.
// tw[t] = (cos(pi t/1024), -sin(pi t/1024)), t in [0,1024).
// SGN = -1 forward (e^{-i}), +1 inverse (e^{+i}, unscaled).
// ---------------------------------------------------------------------------
template <int SGN>
__device__ __forceinline__ void fft2048(float* sre, float* sim, float* dre, float* dim,
                                        const float2* __restrict__ tw, int tid) {
#pragma unroll
  for (int s = 0; s < 11; ++s) {
    const int m = 1 << s;
    __syncthreads();
#pragma unroll
    for (int q = 0; q < 4; ++q) {
      const int i  = tid + (q << 8);
      const int k  = i & (m - 1);
      const int jm = i - k;              // twiddle index j*m in [0,1024)
      float ar = sre[i],        ai = sim[i];
      float br = sre[i + 1024], bi = sim[i + 1024];
      float2 w = tw[jm];
      float wr = w.x;
      float wi = (SGN < 0) ? w.y : -w.y;
      float xr = ar - br, xi = ai - bi;
      dre[i + jm]     = ar + br;
      dim[i + jm]     = ai + bi;
      dre[i + jm + m] = xr * wr - xi * wi;
      dim[i + jm + m] = xr * wi + xi * wr;
    }
    float* t;
    t = sre; sre = dre; dre = t;
    t = sim; sim = dim; dim = t;
  }
  __syncthreads();
}

__global__ __launch_bounds__(256) void k_init_tw(float2* tw) {
  int t = blockIdx.x * 256 + threadIdx.x;
  if (t < 1024) {
    float s, c;
    sincosf(3.14159265358979323846f * (float)t / 1024.0f, &s, &c);
    tw[t] = make_float2(c, -s);
  }
}

// W1 [NL][512][256] -> W1T [NL][256][512]; W2 [NL][256][512] -> W2T [NL][512][256];
// Win [256][64] -> WinT [64][256]
__global__ __launch_bounds__(256) void k_transpose_weights(
    const float* __restrict__ W1, const float* __restrict__ W2, const float* __restrict__ Win,
    float* __restrict__ W1T, float* __restrict__ W2T, float* __restrict__ WinT) {
  int idx = blockIdx.x * 256 + threadIdx.x;
  if (idx < NL * 512 * 256) {
    int i = idx / (512 * 256), r = idx % (512 * 256);
    int j = r / 256, k = r % 256;
    W1T[(i * 256 + k) * 512 + j] = W1[idx];
  }
  if (idx < NL * 256 * 512) {
    int i = idx / (256 * 512), r = idx % (256 * 512);
    int hh = r / 512, j = r % 512;
    W2T[(i * 512 + j) * 256 + hh] = W2[idx];
  }
  if (idx < 256 * 64) {
    int hh = idx / 64, c = idx % 64;
    WinT[c * 256 + hh] = Win[idx];
  }
}

// sp[b][h] = b_in[h] + b_st[h] + sum_c init[b][c]*Wst[h][c]
__global__ __launch_bounds__(256) void k_state_proj(
    const float* __restrict__ init, const float* __restrict__ Wst,
    const float* __restrict__ bst, const float* __restrict__ bin, float* __restrict__ sp) {
  int b = blockIdx.x, h = threadIdx.x;
  float acc = bin[h] + bst[h];
#pragma unroll
  for (int c = 0; c < COUT; ++c) acc += init[b * COUT + c] * Wst[h * COUT + c];
  sp[b * H + h] = acc;
}

// x[b,l,h] = sp[b,h] + sum_c stim[b,c,l]*Win[h,c]
__global__ __launch_bounds__(256) void k_input_proj(
    const float* __restrict__ stim, const float* __restrict__ WinT,
    const float* __restrict__ sp, float* __restrict__ x) {
  int row = blockIdx.x;               // b*L + l
  int b = row >> 10, l = row & 1023;
  int h = threadIdx.x;
  __shared__ float sc[CIN];
  if (h < CIN) sc[h] = stim[(b * CIN + h) * LL + l];
  __syncthreads();
  float acc = sp[b * H + h];
#pragma unroll 8
  for (int c = 0; c < CIN; ++c) acc += sc[c] * WinT[c * H + h];
  x[row * H + h] = acc;
}

__device__ __forceinline__ float blk_sum(float v, float* red) {
  int tid = threadIdx.x;
#pragma unroll
  for (int o = 32; o > 0; o >>= 1) v += __shfl_down(v, o, 64);
  __syncthreads();                       // protect red reuse across calls
  if ((tid & 63) == 0) red[tid >> 6] = v;
  __syncthreads();
  return red[0] + red[1] + red[2] + red[3];
}

// LN over H; write transposed xnT[b][h][l]
__global__ __launch_bounds__(256) void k_ln1(
    const float* __restrict__ x, const float* __restrict__ w, const float* __restrict__ b,
    float* __restrict__ xnT) {
  int row = blockIdx.x;
  int b_ = row >> 10, l = row & 1023;
  int h = threadIdx.x;
  __shared__ float red[4];
  float v = x[row * H + h];
  float m = blk_sum(v, red) * (1.0f / H);
  float d = v - m;
  float var = blk_sum(d * d, red) * (1.0f / H);
  float xn = d * rsqrtf(var + 1e-5f) * w[h] + b[h];
  xnT[((size_t)(b_ * H + h)) * LL + l] = xn;
}

// Per h: time-domain K[l] = sum_n C_bar_n * exp(l*dA_n)  (mirrors reference f32 ops),
// then forward FFT (zero-padded to 2048), store half-spectrum kf[h][0..1024].
__global__ __launch_bounds__(256) void k_kernelfft(
    const float* __restrict__ A_re, const float* __restrict__ A_im,
    const float* __restrict__ C_re, const float* __restrict__ C_im,
    const float* __restrict__ log_step, const float2* __restrict__ tw,
    float2* __restrict__ kf) {
  int h = blockIdx.x, tid = threadIdx.x;
  __shared__ float cbr[NST], cbi[NST], dar[NST], dai[NST];
  __shared__ float b0r[NFFT], b0i[NFFT], b1r[NFFT], b1i[NFFT];
  float step = expf(log_step[h]);
  if (tid < NST) {
    int n = tid;
    float Ar = A_re[n], Ai = A_im[n];
    float dr = step * Ar, di = step * Ai;
    float er = expf(dr);
    float sn, cs; sincosf(di, &sn, &cs);
    float lr = er * cs, li = er * sn;        // exp(dA)
    float nr = lr - 1.0f, ni = li;
    float dnm = Ar * Ar + Ai * Ai;
    float qr = (nr * Ar + ni * Ai) / dnm;    // (exp(dA)-1)/A
    float qi = (ni * Ar - nr * Ai) / dnm;
    float Cr = C_re[h * NST + n], Ci = C_im[h * NST + n];
    cbr[n] = Cr * qr - Ci * qi;
    cbi[n] = Cr * qi + Ci * qr;
    dar[n] = dr; dai[n] = di;
  }
  __syncthreads();
#pragma unroll
  for (int q = 0; q < 4; ++q) {
    int l = tid + (q << 8);
    float fl = (float)l;
    float kr = 0.f, ki = 0.f;
    for (int n = 0; n < NST; ++n) {
      float er = expf(fl * dar[n]);
      float sn, cs; sincosf(fl * dai[n], &sn, &cs);
      kr += er * (cbr[n] * cs - cbi[n] * sn);
      ki += er * (cbr[n] * sn + cbi[n] * cs);
    }
    b0r[l] = kr; b0i[l] = ki;
    b0r[l + 1024] = 0.f; b0i[l + 1024] = 0.f;
  }
  fft2048<-1>(b0r, b0i, b1r, b1i, tw, tid);   // result in b1
#pragma unroll
  for (int q = 0; q < 4; ++q) {
    int k = tid + (q << 8);
    kf[h * 1025 + k] = make_float2(b1r[k], b1i[k]);
  }
  if (tid == 0) kf[h * 1025 + 1024] = make_float2(b1r[1024], b1i[1024]);
}

// Per (b,h): u=xnT row (real, pad to 2048) -> FFT -> *kf -> hermitian extension
// (imag of bins 0 and 1024 dropped, as np.irfft does) -> iFFT -> y/2048 + D*u
__global__ __launch_bounds__(256) void k_conv(
    const float* __restrict__ xnT, const float2* __restrict__ kf,
    const float* __restrict__ D, const float2* __restrict__ tw, float* __restrict__ yT) {
  int blk = blockIdx.x;                 // b*H + h
  int h = blk & (H - 1);
  int tid = threadIdx.x;
  __shared__ float b0r[NFFT], b0i[NFFT], b1r[NFFT], b1i[NFFT];
  float u[4];
  const float* xrow = xnT + (size_t)blk * LL;
#pragma unroll
  for (int q = 0; q < 4; ++q) {
    int l = tid + (q << 8);
    float v = xrow[l];
    u[q] = v;
    b0r[l] = v;          b0i[l] = 0.f;
    b0r[l + 1024] = 0.f; b0i[l + 1024] = 0.f;
  }
  fft2048<-1>(b0r, b0i, b1r, b1i, tw, tid);   // U in b1
  const float2* kfh = kf + h * 1025;
#pragma unroll
  for (int q = 0; q < 4; ++q) {
    int k = tid + (q << 8);
    float2 kv = kfh[k];
    float ur = b1r[k], ui = b1i[k];
    float zr = ur * kv.x - ui * kv.y;
    float zi = ur * kv.y + ui * kv.x;
    if (k == 0) {
      b0r[0] = zr; b0i[0] = 0.f;
      float2 kn = kfh[1024];
      float vr = b1r[1024], vi = b1i[1024];
      b0r[1024] = vr * kn.x - vi * kn.y;
      b0i[1024] = 0.f;
    } else {
      b0r[k] = zr;         b0i[k] = zi;
      b0r[2048 - k] = zr;  b0i[2048 - k] = -zi;
    }
  }
  fft2048<1>(b0r, b0i, b1r, b1i, tw, tid);    // result in b1 (real signal)
  float* yrow = yT + (size_t)blk * LL;
  float Dh = D[h];
#pragma unroll
  for (int q = 0; q < 4; ++q) {
    int l = tid + (q << 8);
    yrow[l] = b1r[l] * (1.0f / NFFT) + Dh * u[q];
  }
}

// x += y (transposed gather); LN -> xn2
__global__ __launch_bounds__(256) void k_ln2(
    float* __restrict__ x, const float* __restrict__ yT,
    const float* __restrict__ w, const float* __restrict__ b, float* __restrict__ xn2) {
  int row = blockIdx.x;
  int b_ = row >> 10, l = row & 1023;
  int h = threadIdx.x;
  __shared__ float red[4];
  float v = x[row * H + h] + yT[((size_t)(b_ * H + h)) * LL + l];
  x[row * H + h] = v;
  float m = blk_sum(v, red) * (1.0f / H);
  float d = v - m;
  float var = blk_sum(d * d, red) * (1.0f / H);
  xn2[row * H + h] = d * rsqrtf(var + 1e-5f) * w[h] + b[h];
}

// g1 = gelu_exact(xn2 @ W1T + b1) : [8192,256]x[256,512]
__global__ __launch_bounds__(256) void k_mlp1(
    const float* __restrict__ xn2, const float* __restrict__ W1T,
    const float* __restrict__ b1, float* __restrict__ g1) {
  int row0 = blockIdx.x * 8;
  int tid = threadIdx.x;
  __shared__ float a[8][H];
#pragma unroll
  for (int it = 0; it < 8; ++it) {
    int f = tid + (it << 8);
    a[f >> 8][f & 255] = xn2[row0 * H + f];
  }
  __syncthreads();
  float acc0[8], acc1[8];
  float bb0 = b1[tid], bb1 = b1[tid + 256];
#pragma unroll
  for (int r = 0; r < 8; ++r) { acc0[r] = bb0; acc1[r] = bb1; }
  for (int k = 0; k < H; ++k) {
    float w0 = W1T[k * 512 + tid];
    float w1 = W1T[k * 512 + tid + 256];
#pragma unroll
    for (int r = 0; r < 8; ++r) {
      float av = a[r][k];
      acc0[r] += av * w0;
      acc1[r] += av * w1;
    }
  }
#pragma unroll
  for (int r = 0; r < 8; ++r) {
    float v0 = acc0[r], v1 = acc1[r];
    g1[(row0 + r) * 512 + tid]       = 0.5f * v0 * (1.0f + erff(v0 * 0.70710678118654752f));
    g1[(row0 + r) * 512 + tid + 256] = 0.5f * v1 * (1.0f + erff(v1 * 0.70710678118654752f));
  }
}

// x += g1 @ W2T + b2 : [8192,512]x[512,256]
__global__ __launch_bounds__(256) void k_mlp2(
    const float* __restrict__ g1, const float* __restrict__ W2T,
    const float* __restrict__ b2, float* __restrict__ x) {
  int row0 = blockIdx.x * 8;
  int tid = threadIdx.x;
  __shared__ float g[8][512];
#pragma unroll
  for (int it = 0; it < 16; ++it) {
    int f = tid + (it << 8);
    g[f >> 9][f & 511] = g1[row0 * 512 + f];
  }
  __syncthreads();
  float acc[8];
#pragma unroll
  for (int r = 0; r < 8; ++r) acc[r] = 0.f;
  for (int k = 0; k < 512; ++k) {
    float w = W2T[k * H + tid];
#pragma unroll
    for (int r = 0; r < 8; ++r) acc[r] += g[r][k] * w;
  }
  float bb = b2[tid];
#pragma unroll
  for (int r = 0; r < 8; ++r) x[(row0 + r) * H + tid] += acc[r] + bb;
}

// out[b,co,l] = sum_h x[b,l,h]*Wout[co,h] + b_out[co]
__global__ __launch_bounds__(256) void k_out(
    const float* __restrict__ x, const float* __restrict__ Wout,
    const float* __restrict__ bout, float* __restrict__ out) {
  int row = blockIdx.x;
  int b_ = row >> 10, l = row & 1023;
  int tid = threadIdx.x;
  __shared__ float xr[H];
  xr[tid] = x[row * H + tid];
  __syncthreads();
  int co = tid >> 5, ln = tid & 31;
  float p = 0.f;
#pragma unroll 8
  for (int h2 = ln; h2 < H; h2 += 32) p += xr[h2] * Wout[co * H + h2];
#pragma unroll
  for (int o = 16; o > 0; o >>= 1) p += __shfl_xor(p, o, 64);
  if (ln == 0) out[(b_ * COUT + co) * LL + l] = p + bout[co];
}

extern "C" void kernel_launch(void* const* d_in, const int* in_sizes, int n_in,
                              void* d_out, int out_size, void* d_ws, size_t ws_size,
                              hipStream_t stream) {
  const float* stim  = (const float*)d_in[0];
  const float* init  = (const float*)d_in[1];
  const float* A_re  = (const float*)d_in[2];
  const float* A_im  = (const float*)d_in[3];
  const float* C_re  = (const float*)d_in[4];
  const float* C_im  = (const float*)d_in[5];
  const float* Dp    = (const float*)d_in[6];
  const float* lstep = (const float*)d_in[7];
  const float* ln1w  = (const float*)d_in[8];
  const float* ln1b  = (const float*)d_in[9];
  const float* ln2w  = (const float*)d_in[10];
  const float* ln2b  = (const float*)d_in[11];
  const float* W1    = (const float*)d_in[12];
  const float* b1    = (const float*)d_in[13];
  const float* W2    = (const float*)d_in[14];
  const float* b2    = (const float*)d_in[15];
  const float* Win   = (const float*)d_in[16];
  const float* Wst   = (const float*)d_in[18];
  const float* bst   = (const float*)d_in[19];
  const float* bin   = (const float*)d_in[17];
  const float* Wout  = (const float*)d_in[20];
  const float* bout  = (const float*)d_in[21];
  float* out = (float*)d_out;
  float* ws = (float*)d_ws;

  size_t o = 0;
  auto alloc = [&](size_t n) { size_t r = o; o += (n + 63) & ~(size_t)63; return r; };
  float*  x    = ws + alloc((size_t)BB * LL * H);
  float*  xnT  = ws + alloc((size_t)BB * H * LL);
  float*  yT   = ws + alloc((size_t)BB * H * LL);
  float*  xn2  = ws + alloc((size_t)BB * LL * H);
  float*  g1   = ws + alloc((size_t)BB * LL * 512);
  float2* kf   = (float2*)(ws + alloc((size_t)H * 1025 * 2));
  float*  W1T  = ws + alloc((size_t)NL * 256 * 512);
  float*  W2T  = ws + alloc((size_t)NL * 512 * 256);
  float*  WinT = ws + alloc((size_t)64 * 256);
  float*  sp   = ws + alloc((size_t)BB * H);
  float2* tw   = (float2*)(ws + alloc((size_t)1024 * 2));
  (void)ws_size; (void)in_sizes; (void)n_in; (void)out_size;

  k_init_tw<<<4, 256, 0, stream>>>(tw);
  k_transpose_weights<<<2048, 256, 0, stream>>>(W1, W2, Win, W1T, W2T, WinT);
  k_state_proj<<<BB, 256, 0, stream>>>(init, Wst, bst, bin, sp);
  k_input_proj<<<BB * LL, 256, 0, stream>>>(stim, WinT, sp, x);

  for (int i = 0; i < NL; ++i) {
    k_ln1<<<BB * LL, 256, 0, stream>>>(x, ln1w + i * H, ln1b + i * H, xnT);
    k_kernelfft<<<H, 256, 0, stream>>>(A_re + i * NST, A_im + i * NST,
                                       C_re + i * H * NST, C_im + i * H * NST,
                                       lstep + i * H, tw, kf);
    k_conv<<<BB * H, 256, 0, stream>>>(xnT, kf, Dp + i * H, tw, yT);
    k_ln2<<<BB * LL, 256, 0, stream>>>(x, yT, ln2w + i * H, ln2b + i * H, xn2);
    k_mlp1<<<BB * LL / 8, 256, 0, stream>>>(xn2, W1T + i * 256 * 512, b1 + i * 512, g1);
    k_mlp2<<<BB * LL / 8, 256, 0, stream>>>(g1, W2T + i * 512 * 256, b2 + i * H, x);
  }
  k_out<<<BB * LL, 256, 0, stream>>>(x, Wout, bout, out);
}

// Round 2
// 717.767 us; speedup vs baseline: 1.3200x; 1.3200x over previous
//
#include <hip/hip_runtime.h>
#include <math.h>

#define NL   4
#define H    256
#define NST  64
#define CIN  64
#define COUT 8
#define BB   8
#define LL   1024
#define NFFT 2048

// ---------------------------------------------------------------------------
// 2048-point complex FFT, Stockham autosort (natural order in/out), radix-2,
// 256 threads, 11 stages, ping-pong between (sre,sim) and (dre,dim).
// Result ends in the SECOND buffer pair (b1) since 11 is odd.
// tw[t] = (cos(pi t/1024), -sin(pi t/1024)), t in [0,1024).
// SGN = -1 forward (e^{-i}), +1 inverse (e^{+i}, unscaled).
// ---------------------------------------------------------------------------
template <int SGN>
__device__ __forceinline__ void fft2048(float* sre, float* sim, float* dre, float* dim,
                                        const float2* __restrict__ tw, int tid) {
#pragma unroll
  for (int s = 0; s < 11; ++s) {
    const int m = 1 << s;
    __syncthreads();
#pragma unroll
    for (int q = 0; q < 4; ++q) {
      const int i  = tid + (q << 8);
      const int k  = i & (m - 1);
      const int jm = i - k;              // twiddle index j*m in [0,1024)
      float ar = sre[i],        ai = sim[i];
      float br = sre[i + 1024], bi = sim[i + 1024];
      float2 w = tw[jm];
      float wr = w.x;
      float wi = (SGN < 0) ? w.y : -w.y;
      float xr = ar - br, xi = ai - bi;
      dre[i + jm]     = ar + br;
      dim[i + jm]     = ai + bi;
      dre[i + jm + m] = xr * wr - xi * wi;
      dim[i + jm + m] = xr * wi + xi * wr;
    }
    float* t;
    t = sre; sre = dre; dre = t;
    t = sim; sim = dim; dim = t;
  }
  __syncthreads();
}

__global__ __launch_bounds__(256) void k_init_tw(float2* tw) {
  int t = blockIdx.x * 256 + threadIdx.x;
  if (t < 1024) {
    float s, c;
    sincosf(3.14159265358979323846f * (float)t / 1024.0f, &s, &c);
    tw[t] = make_float2(c, -s);
  }
}

// W1 [NL][512][256] -> W1T [NL][256][512]; W2 [NL][256][512] -> W2T [NL][512][256];
// Win [256][64] -> WinT [64][256]
__global__ __launch_bounds__(256) void k_transpose_weights(
    const float* __restrict__ W1, const float* __restrict__ W2, const float* __restrict__ Win,
    float* __restrict__ W1T, float* __restrict__ W2T, float* __restrict__ WinT) {
  int idx = blockIdx.x * 256 + threadIdx.x;
  if (idx < NL * 512 * 256) {
    int i = idx / (512 * 256), r = idx % (512 * 256);
    int j = r / 256, k = r % 256;
    W1T[(i * 256 + k) * 512 + j] = W1[idx];
  }
  if (idx < NL * 256 * 512) {
    int i = idx / (256 * 512), r = idx % (256 * 512);
    int hh = r / 512, j = r % 512;
    W2T[(i * 512 + j) * 256 + hh] = W2[idx];
  }
  if (idx < 256 * 64) {
    int hh = idx / 64, c = idx % 64;
    WinT[c * 256 + hh] = Win[idx];
  }
}

// sp[b][h] = b_in[h] + b_st[h] + sum_c init[b][c]*Wst[h][c]
__global__ __launch_bounds__(256) void k_state_proj(
    const float* __restrict__ init, const float* __restrict__ Wst,
    const float* __restrict__ bst, const float* __restrict__ bin, float* __restrict__ sp) {
  int b = blockIdx.x, h = threadIdx.x;
  float acc = bin[h] + bst[h];
#pragma unroll
  for (int c = 0; c < COUT; ++c) acc += init[b * COUT + c] * Wst[h * COUT + c];
  sp[b * H + h] = acc;
}

// x[b,l,h] = sp[b,h] + sum_c stim[b,c,l]*Win[h,c]
__global__ __launch_bounds__(256) void k_input_proj(
    const float* __restrict__ stim, const float* __restrict__ WinT,
    const float* __restrict__ sp, float* __restrict__ x) {
  int row = blockIdx.x;               // b*L + l
  int b = row >> 10, l = row & 1023;
  int h = threadIdx.x;
  __shared__ float sc[CIN];
  if (h < CIN) sc[h] = stim[(b * CIN + h) * LL + l];
  __syncthreads();
  float acc = sp[b * H + h];
#pragma unroll 8
  for (int c = 0; c < CIN; ++c) acc += sc[c] * WinT[c * H + h];
  x[row * H + h] = acc;
}

__device__ __forceinline__ float blk_sum(float v, float* red) {
  int tid = threadIdx.x;
#pragma unroll
  for (int o = 32; o > 0; o >>= 1) v += __shfl_down(v, o, 64);
  __syncthreads();                       // protect red reuse across calls
  if ((tid & 63) == 0) red[tid >> 6] = v;
  __syncthreads();
  return red[0] + red[1] + red[2] + red[3];
}

// LN over H; write transposed xnT[b][h][l]
__global__ __launch_bounds__(256) void k_ln1(
    const float* __restrict__ x, const float* __restrict__ w, const float* __restrict__ b,
    float* __restrict__ xnT) {
  int row = blockIdx.x;
  int b_ = row >> 10, l = row & 1023;
  int h = threadIdx.x;
  __shared__ float red[4];
  float v = x[row * H + h];
  float m = blk_sum(v, red) * (1.0f / H);
  float d = v - m;
  float var = blk_sum(d * d, red) * (1.0f / H);
  float xn = d * rsqrtf(var + 1e-5f) * w[h] + b[h];
  xnT[((size_t)(b_ * H + h)) * LL + l] = xn;
}

// All layers at once: blk = i*H + h. Time-domain K[l] = sum_n C_bar_n * exp(l*dA_n)
// via binary powering (no per-(l,n) transcendentals), then forward FFT (zero-pad
// to 2048), store half-spectrum kf[i][h][0..1024].
__global__ __launch_bounds__(256) void k_kernelfft(
    const float* __restrict__ A_re, const float* __restrict__ A_im,
    const float* __restrict__ C_re, const float* __restrict__ C_im,
    const float* __restrict__ log_step, const float2* __restrict__ tw,
    float2* __restrict__ kf) {
  int blk = blockIdx.x;                 // i*H + h
  int i = blk >> 8, h = blk & (H - 1);
  int tid = threadIdx.x;
  __shared__ float cbr[NST], cbi[NST];
  __shared__ float Ejr[8][NST], Eji[8][NST], Mr[NST], Mi[NST];
  __shared__ float b0r[NFFT], b0i[NFFT], b1r[NFFT], b1i[NFFT];
  float step = expf(log_step[blk]);
  if (tid < NST) {
    int n = tid;
    float Ar = A_re[i * NST + n], Ai = A_im[i * NST + n];
    float dr = step * Ar, di = step * Ai;
    float er = expf(dr);
    float sn, cs; sincosf(di, &sn, &cs);
    float lr = er * cs, li = er * sn;        // exp(dA)
    float nr = lr - 1.0f, ni = li;
    float dnm = Ar * Ar + Ai * Ai;
    float qr = (nr * Ar + ni * Ai) / dnm;    // (exp(dA)-1)/A
    float qi = (ni * Ar - nr * Ai) / dnm;
    float Cr = C_re[(size_t)blk * NST + n], Ci = C_im[(size_t)blk * NST + n];
    cbr[n] = Cr * qr - Ci * qi;
    cbi[n] = Cr * qi + Ci * qr;
    // E_j = exp(2^j * dA) by successive squaring; M = exp(256*dA)
    float xr = lr, xi = li;
#pragma unroll
    for (int j = 0; j < 8; ++j) {
      Ejr[j][n] = xr; Eji[j][n] = xi;
      float t2 = xr * xr - xi * xi;
      xi = 2.0f * xr * xi;
      xr = t2;
    }
    Mr[n] = xr; Mi[n] = xi;
  }
  __syncthreads();
  float kr[4] = {0.f, 0.f, 0.f, 0.f}, ki[4] = {0.f, 0.f, 0.f, 0.f};
  for (int n = 0; n < NST; ++n) {
    // p = exp(tid * dA_n) via bits of tid
    float pr = 1.f, pi = 0.f;
#pragma unroll
    for (int j = 0; j < 8; ++j) {
      float er = Ejr[j][n], ei = Eji[j][n];
      float trr = pr * er - pi * ei;
      float tii = pr * ei + pi * er;
      if ((tid >> j) & 1) { pr = trr; pi = tii; }
    }
    float cr = cbr[n], ci = cbi[n];
    float mr = Mr[n], mi = Mi[n];
#pragma unroll
    for (int q = 0; q < 4; ++q) {
      kr[q] += cr * pr - ci * pi;
      ki[q] += cr * pi + ci * pr;
      float t2 = pr * mr - pi * mi;     // p *= exp(256*dA)
      pi = pr * mi + pi * mr;
      pr = t2;
    }
  }
#pragma unroll
  for (int q = 0; q < 4; ++q) {
    int l = tid + (q << 8);
    b0r[l] = kr[q]; b0i[l] = ki[q];
    b0r[l + 1024] = 0.f; b0i[l + 1024] = 0.f;
  }
  fft2048<-1>(b0r, b0i, b1r, b1i, tw, tid);   // result in b1
  float2* kfh = kf + (size_t)blk * 1025;
#pragma unroll
  for (int q = 0; q < 4; ++q) {
    int k = tid + (q << 8);
    kfh[k] = make_float2(b1r[k], b1i[k]);
  }
  if (tid == 0) kfh[1024] = make_float2(b1r[1024], b1i[1024]);
}

// Two rows (h0=2*hp, h1=2*hp+1) packed into one complex FFT.
// Forward FFT of u0 + i*u1, Hermitian split, per-row spectral multiply with
// irfft bin-0/1024 imag-drop, Hermitian extension, packed inverse Z0 + i*Z1.
__global__ __launch_bounds__(256) void k_conv(
    const float* __restrict__ xnT, const float2* __restrict__ kf,
    const float* __restrict__ D, const float2* __restrict__ tw, float* __restrict__ yT) {
  int blk = blockIdx.x;                 // b*128 + hp
  int b_ = blk >> 7, hp = blk & 127;
  int h0 = hp * 2, h1 = h0 + 1;
  int r0 = b_ * H + h0;
  int tid = threadIdx.x;
  __shared__ float b0r[NFFT], b0i[NFFT], b1r[NFFT], b1i[NFFT];
  float u0[4], u1[4];
  const float* x0 = xnT + (size_t)r0 * LL;
  const float* x1 = x0 + LL;
#pragma unroll
  for (int q = 0; q < 4; ++q) {
    int l = tid + (q << 8);
    float v0 = x0[l], v1 = x1[l];
    u0[q] = v0; u1[q] = v1;
    b0r[l] = v0;          b0i[l] = v1;
    b0r[l + 1024] = 0.f;  b0i[l + 1024] = 0.f;
  }
  fft2048<-1>(b0r, b0i, b1r, b1i, tw, tid);   // F = FFT(u0 + i*u1) in b1
  const float2* kf0 = kf + (size_t)h0 * 1025;
  const float2* kf1 = kf + (size_t)h1 * 1025;
#pragma unroll
  for (int q = 0; q < 4; ++q) {
    int k = tid + (q << 8);
    if (k == 0) {
      // bin 0: U0 = Re F[0], U1 = Im F[0] (both real); drop imag of products
      float2 k0 = kf0[0], k1 = kf1[0];
      b0r[0] = b1r[0] * k0.x;
      b0i[0] = b1i[0] * k1.x;
      // bin 1024: U0 = Re F[1024], U1 = Im F[1024]; drop imag of products
      float2 k0n = kf0[1024], k1n = kf1[1024];
      b0r[1024] = b1r[1024] * k0n.x;
      b0i[1024] = b1i[1024] * k1n.x;
    } else {
      float Fr = b1r[k], Fi = b1i[k];
      float Gr = b1r[2048 - k], Gi = b1i[2048 - k];
      float u0r = 0.5f * (Fr + Gr), u0i = 0.5f * (Fi - Gi);   // U0[k]
      float dr_ = 0.5f * (Fr - Gr), di_ = 0.5f * (Fi + Gi);
      float u1r = di_, u1i = -dr_;                            // U1[k] = (F-conjG)/(2i)
      float2 k0 = kf0[k], k1 = kf1[k];
      float z0r = u0r * k0.x - u0i * k0.y, z0i = u0r * k0.y + u0i * k0.x;
      float z1r = u1r * k1.x - u1i * k1.y, z1i = u1r * k1.y + u1i * k1.x;
      // packed G[k] = Z0 + i*Z1 ; G[2048-k] = conj(Z0) + i*conj(Z1)
      b0r[k] = z0r - z1i;        b0i[k] = z0i + z1r;
      b0r[2048 - k] = z0r + z1i; b0i[2048 - k] = z1r - z0i;
    }
  }
  fft2048<1>(b0r, b0i, b1r, b1i, tw, tid);    // z0 + i*z1 in b1 (both real)
  float Dh0 = D[h0], Dh1 = D[h1];
  float* y0 = yT + (size_t)r0 * LL;
  float* y1 = y0 + LL;
#pragma unroll
  for (int q = 0; q < 4; ++q) {
    int l = tid + (q << 8);
    y0[l] = b1r[l] * (1.0f / NFFT) + Dh0 * u0[q];
    y1[l] = b1i[l] * (1.0f / NFFT) + Dh1 * u1[q];
  }
}

// x += y (transposed gather); LN -> xn2
__global__ __launch_bounds__(256) void k_ln2(
    float* __restrict__ x, const float* __restrict__ yT,
    const float* __restrict__ w, const float* __restrict__ b, float* __restrict__ xn2) {
  int row = blockIdx.x;
  int b_ = row >> 10, l = row & 1023;
  int h = threadIdx.x;
  __shared__ float red[4];
  float v = x[row * H + h] + yT[((size_t)(b_ * H + h)) * LL + l];
  x[row * H + h] = v;
  float m = blk_sum(v, red) * (1.0f / H);
  float d = v - m;
  float var = blk_sum(d * d, red) * (1.0f / H);
  xn2[row * H + h] = d * rsqrtf(var + 1e-5f) * w[h] + b[h];
}

// g1 = gelu_exact(xn2 @ W1T + b1) : [8192,256]x[256,512]
__global__ __launch_bounds__(256) void k_mlp1(
    const float* __restrict__ xn2, const float* __restrict__ W1T,
    const float* __restrict__ b1, float* __restrict__ g1) {
  int row0 = blockIdx.x * 8;
  int tid = threadIdx.x;
  __shared__ float a[8][H];
#pragma unroll
  for (int it = 0; it < 8; ++it) {
    int f = tid + (it << 8);
    a[f >> 8][f & 255] = xn2[row0 * H + f];
  }
  __syncthreads();
  float acc0[8], acc1[8];
  float bb0 = b1[tid], bb1 = b1[tid + 256];
#pragma unroll
  for (int r = 0; r < 8; ++r) { acc0[r] = bb0; acc1[r] = bb1; }
  for (int k = 0; k < H; ++k) {
    float w0 = W1T[k * 512 + tid];
    float w1 = W1T[k * 512 + tid + 256];
#pragma unroll
    for (int r = 0; r < 8; ++r) {
      float av = a[r][k];
      acc0[r] += av * w0;
      acc1[r] += av * w1;
    }
  }
#pragma unroll
  for (int r = 0; r < 8; ++r) {
    float v0 = acc0[r], v1 = acc1[r];
    g1[(row0 + r) * 512 + tid]       = 0.5f * v0 * (1.0f + erff(v0 * 0.70710678118654752f));
    g1[(row0 + r) * 512 + tid + 256] = 0.5f * v1 * (1.0f + erff(v1 * 0.70710678118654752f));
  }
}

// x += g1 @ W2T + b2 : [8192,512]x[512,256]
__global__ __launch_bounds__(256) void k_mlp2(
    const float* __restrict__ g1, const float* __restrict__ W2T,
    const float* __restrict__ b2, float* __restrict__ x) {
  int row0 = blockIdx.x * 8;
  int tid = threadIdx.x;
  __shared__ float g[8][512];
#pragma unroll
  for (int it = 0; it < 16; ++it) {
    int f = tid + (it << 8);
    g[f >> 9][f & 511] = g1[row0 * 512 + f];
  }
  __syncthreads();
  float acc[8];
#pragma unroll
  for (int r = 0; r < 8; ++r) acc[r] = 0.f;
  for (int k = 0; k < 512; ++k) {
    float w = W2T[k * H + tid];
#pragma unroll
    for (int r = 0; r < 8; ++r) acc[r] += g[r][k] * w;
  }
  float bb = b2[tid];
#pragma unroll
  for (int r = 0; r < 8; ++r) x[(row0 + r) * H + tid] += acc[r] + bb;
}

// out[b,co,l] = sum_h x[b,l,h]*Wout[co,h] + b_out[co]
__global__ __launch_bounds__(256) void k_out(
    const float* __restrict__ x, const float* __restrict__ Wout,
    const float* __restrict__ bout, float* __restrict__ out) {
  int row = blockIdx.x;
  int b_ = row >> 10, l = row & 1023;
  int tid = threadIdx.x;
  __shared__ float xr[H];
  xr[tid] = x[row * H + tid];
  __syncthreads();
  int co = tid >> 5, ln = tid & 31;
  float p = 0.f;
#pragma unroll 8
  for (int h2 = ln; h2 < H; h2 += 32) p += xr[h2] * Wout[co * H + h2];
#pragma unroll
  for (int o = 16; o > 0; o >>= 1) p += __shfl_xor(p, o, 64);
  if (ln == 0) out[(b_ * COUT + co) * LL + l] = p + bout[co];
}

extern "C" void kernel_launch(void* const* d_in, const int* in_sizes, int n_in,
                              void* d_out, int out_size, void* d_ws, size_t ws_size,
                              hipStream_t stream) {
  const float* stim  = (const float*)d_in[0];
  const float* init  = (const float*)d_in[1];
  const float* A_re  = (const float*)d_in[2];
  const float* A_im  = (const float*)d_in[3];
  const float* C_re  = (const float*)d_in[4];
  const float* C_im  = (const float*)d_in[5];
  const float* Dp    = (const float*)d_in[6];
  const float* lstep = (const float*)d_in[7];
  const float* ln1w  = (const float*)d_in[8];
  const float* ln1b  = (const float*)d_in[9];
  const float* ln2w  = (const float*)d_in[10];
  const float* ln2b  = (const float*)d_in[11];
  const float* W1    = (const float*)d_in[12];
  const float* b1    = (const float*)d_in[13];
  const float* W2    = (const float*)d_in[14];
  const float* b2    = (const float*)d_in[15];
  const float* Win   = (const float*)d_in[16];
  const float* Wst   = (const float*)d_in[18];
  const float* bst   = (const float*)d_in[19];
  const float* bin   = (const float*)d_in[17];
  const float* Wout  = (const float*)d_in[20];
  const float* bout  = (const float*)d_in[21];
  float* out = (float*)d_out;
  float* ws = (float*)d_ws;

  size_t o = 0;
  auto alloc = [&](size_t n) { size_t r = o; o += (n + 63) & ~(size_t)63; return r; };
  float*  x    = ws + alloc((size_t)BB * LL * H);
  float*  xnT  = ws + alloc((size_t)BB * H * LL);
  float*  yT   = ws + alloc((size_t)BB * H * LL);
  float*  xn2  = ws + alloc((size_t)BB * LL * H);
  float*  g1   = ws + alloc((size_t)BB * LL * 512);
  float2* kf   = (float2*)(ws + alloc((size_t)NL * H * 1025 * 2));
  float*  W1T  = ws + alloc((size_t)NL * 256 * 512);
  float*  W2T  = ws + alloc((size_t)NL * 512 * 256);
  float*  WinT = ws + alloc((size_t)64 * 256);
  float*  sp   = ws + alloc((size_t)BB * H);
  float2* tw   = (float2*)(ws + alloc((size_t)1024 * 2));
  (void)ws_size; (void)in_sizes; (void)n_in; (void)out_size;

  k_init_tw<<<4, 256, 0, stream>>>(tw);
  k_kernelfft<<<NL * H, 256, 0, stream>>>(A_re, A_im, C_re, C_im, lstep, tw, kf);
  k_transpose_weights<<<2048, 256, 0, stream>>>(W1, W2, Win, W1T, W2T, WinT);
  k_state_proj<<<BB, 256, 0, stream>>>(init, Wst, bst, bin, sp);
  k_input_proj<<<BB * LL, 256, 0, stream>>>(stim, WinT, sp, x);

  for (int i = 0; i < NL; ++i) {
    k_ln1<<<BB * LL, 256, 0, stream>>>(x, ln1w + i * H, ln1b + i * H, xnT);
    k_conv<<<BB * H / 2, 256, 0, stream>>>(xnT, kf + (size_t)i * H * 1025,
                                           Dp + i * H, tw, yT);
    k_ln2<<<BB * LL, 256, 0, stream>>>(x, yT, ln2w + i * H, ln2b + i * H, xn2);
    k_mlp1<<<BB * LL / 8, 256, 0, stream>>>(xn2, W1T + i * 256 * 512, b1 + i * 512, g1);
    k_mlp2<<<BB * LL / 8, 256, 0, stream>>>(g1, W2T + i * 512 * 256, b2 + i * H, x);
  }
  k_out<<<BB * LL, 256, 0, stream>>>(x, Wout, bout, out);
}

// Round 3
// 357.719 us; speedup vs baseline: 2.6485x; 2.0065x over previous
//
#include <hip/hip_runtime.h>
#include <math.h>

#define NL   4
#define H    256
#define NST  64
#define CIN  64
#define COUT 8
#define BB   8
#define LL   1024
#define NFFT 2048

typedef __attribute__((ext_vector_type(8))) short bf16x8;
typedef __attribute__((ext_vector_type(4))) short short4v;
typedef __attribute__((ext_vector_type(4))) int   int4v;
typedef __attribute__((ext_vector_type(4))) float f32x4;

__device__ __forceinline__ short f2bf(float f) {
  union { float f; unsigned u; } v; v.f = f;
  unsigned r = (v.u + 0x7fffu + ((v.u >> 16) & 1u)) >> 16;
  return (short)r;
}
__device__ __forceinline__ int idxp(int a) { return a + (a >> 5); }  // LDS pad

// ---------------------------------------------------------------------------
// 2048-pt FFT: 5 radix-4 Stockham stages (m=1,4,16,64,256) + final radix-2
// (m=1024, twiddle-free). Derived by composing the verified radix-2 stage
// dst[i+jm]=a+b; dst[i+jm+m]=(a-b)W^jm twice. Input in (b0r,b0i) at idxp();
// OUTPUT lands back in (b0r,b0i). Buffers are 2112 floats (padded).
// tw[t] = (cos(pi t/1024), -sin(pi t/1024)), t in [0,1536).
// ---------------------------------------------------------------------------
template <int SGN>
__device__ __forceinline__ void fft2048r4(float* b0r, float* b0i, float* b1r, float* b1i,
                                          const float2* __restrict__ tw, int tid) {
  float *sr = b0r, *si = b0i, *dr = b1r, *di = b1i;
#pragma unroll
  for (int s = 0; s < 5; ++s) {
    const int m = 1 << (2 * s);
    __syncthreads();
#pragma unroll
    for (int q = 0; q < 2; ++q) {
      const int t  = tid + (q << 8);          // [0,512)
      const int k  = t & (m - 1);
      const int jm = t - k;                   // multiple of m, < 512
      float a0r = sr[idxp(t)],        a0i = si[idxp(t)];
      float a1r = sr[idxp(t + 512)],  a1i = si[idxp(t + 512)];
      float a2r = sr[idxp(t + 1024)], a2i = si[idxp(t + 1024)];
      float a3r = sr[idxp(t + 1536)], a3i = si[idxp(t + 1536)];
      float s0r = a0r + a2r, s0i = a0i + a2i;   // A+C
      float s1r = a0r - a2r, s1i = a0i - a2i;   // A-C
      float s2r = a1r + a3r, s2i = a1i + a3i;   // B+D
      float s3r = a1r - a3r, s3i = a1i - a3i;   // B-D
      float mir, mii;                            // -i(B-D) fwd, +i(B-D) inv
      if (SGN < 0) { mir =  s3i; mii = -s3r; }
      else         { mir = -s3i; mii =  s3r; }
      float o0r = s0r + s2r, o0i = s0i + s2i;   // * W^0
      float o1r = s1r + mir, o1i = s1i + mii;   // * W^jm
      float o2r = s0r - s2r, o2i = s0i - s2i;   // * W^2jm
      float o3r = s1r - mir, o3i = s1i - mii;   // * W^3jm
      float2 w1 = tw[jm], w2 = tw[2 * jm], w3 = tw[3 * jm];
      float w1r = w1.x, w1i = (SGN < 0) ? w1.y : -w1.y;
      float w2r = w2.x, w2i = (SGN < 0) ? w2.y : -w2.y;
      float w3r = w3.x, w3i = (SGN < 0) ? w3.y : -w3.y;
      const int base = 4 * jm + k;
      dr[idxp(base)]         = o0r;
      di[idxp(base)]         = o0i;
      dr[idxp(base + m)]     = o1r * w1r - o1i * w1i;
      di[idxp(base + m)]     = o1r * w1i + o1i * w1r;
      dr[idxp(base + 2*m)]   = o2r * w2r - o2i * w2i;
      di[idxp(base + 2*m)]   = o2r * w2i + o2i * w2r;
      dr[idxp(base + 3*m)]   = o3r * w3r - o3i * w3i;
      di[idxp(base + 3*m)]   = o3r * w3i + o3i * w3r;
    }
    float* t0;
    t0 = sr; sr = dr; dr = t0;
    t0 = si; si = di; di = t0;
  }
  // final radix-2 stage, m=1024: jm=0 -> no twiddle
  __syncthreads();
#pragma unroll
  for (int q = 0; q < 4; ++q) {
    const int i = tid + (q << 8);
    float ar = sr[idxp(i)],        ai = si[idxp(i)];
    float br = sr[idxp(i + 1024)], bi = si[idxp(i + 1024)];
    dr[idxp(i)]        = ar + br;
    di[idxp(i)]        = ai + bi;
    dr[idxp(i + 1024)] = ar - br;
    di[idxp(i + 1024)] = ai - bi;
  }
  __syncthreads();   // result in dr/di == b0r/b0i (6 swaps total)
}

__global__ __launch_bounds__(256) void k_init_tw(float2* tw) {
  int t = blockIdx.x * 256 + threadIdx.x;
  if (t < 1536) {
    float s, c;
    sincosf(3.14159265358979323846f * (float)t / 1024.0f, &s, &c);
    tw[t] = make_float2(c, -s);
  }
}

// bf16 weight copies + Win transpose
__global__ __launch_bounds__(256) void k_prep(
    const float* __restrict__ W1, const float* __restrict__ W2, const float* __restrict__ Win,
    short* __restrict__ W1bf, short* __restrict__ W2bf, float* __restrict__ WinT) {
  int idx = blockIdx.x * 256 + threadIdx.x;
  if (idx < NL * 512 * 256) {
    W1bf[idx] = f2bf(W1[idx]);
    W2bf[idx] = f2bf(W2[idx]);
  }
  if (idx < 256 * 64) {
    int hh = idx / 64, c = idx % 64;
    WinT[c * 256 + hh] = Win[idx];
  }
}

__global__ __launch_bounds__(256) void k_state_proj(
    const float* __restrict__ init, const float* __restrict__ Wst,
    const float* __restrict__ bst, const float* __restrict__ bin, float* __restrict__ sp) {
  int b = blockIdx.x, h = threadIdx.x;
  float acc = bin[h] + bst[h];
#pragma unroll
  for (int c = 0; c < COUT; ++c) acc += init[b * COUT + c] * Wst[h * COUT + c];
  sp[b * H + h] = acc;
}

__global__ __launch_bounds__(256) void k_input_proj(
    const float* __restrict__ stim, const float* __restrict__ WinT,
    const float* __restrict__ sp, float* __restrict__ x) {
  int row = blockIdx.x;               // b*L + l
  int b = row >> 10, l = row & 1023;
  int h = threadIdx.x;
  __shared__ float sc[CIN];
  if (h < CIN) sc[h] = stim[(b * CIN + h) * LL + l];
  __syncthreads();
  float acc = sp[b * H + h];
#pragma unroll 8
  for (int c = 0; c < CIN; ++c) acc += sc[c] * WinT[c * H + h];
  x[row * H + h] = acc;
}

// LN over H for a 16-row l-tile; transposed write via LDS, 64B/thread.
__global__ __launch_bounds__(256) void k_ln1(
    const float* __restrict__ x, const float* __restrict__ lw, const float* __restrict__ lb,
    float* __restrict__ xnT) {
  int blk = blockIdx.x;               // b*64 + ltile
  int b_ = blk >> 6, l0 = (blk & 63) << 4;
  int tid = threadIdx.x, wv = tid >> 6, lane = tid & 63;
  __shared__ float T[16][256];
  float4 w4 = *(const float4*)&lw[lane * 4];
  float4 c4 = *(const float4*)&lb[lane * 4];
#pragma unroll
  for (int rr = 0; rr < 4; ++rr) {
    int lr = wv * 4 + rr;
    const float* row = x + (((size_t)(b_ << 10) + l0 + lr)) * H;
    float4 v = *(const float4*)&row[lane * 4];
    float s = v.x + v.y + v.z + v.w;
#pragma unroll
    for (int o = 32; o > 0; o >>= 1) s += __shfl_xor(s, o, 64);
    float m = s * (1.0f / H);
    float dx = v.x - m, dy = v.y - m, dz = v.z - m, dw = v.w - m;
    float q = dx * dx + dy * dy + dz * dz + dw * dw;
#pragma unroll
    for (int o = 32; o > 0; o >>= 1) q += __shfl_xor(q, o, 64);
    float rs = rsqrtf(q * (1.0f / H) + 1e-5f);
    float4 o4;
    o4.x = dx * rs * w4.x + c4.x; o4.y = dy * rs * w4.y + c4.y;
    o4.z = dz * rs * w4.z + c4.z; o4.w = dw * rs * w4.w + c4.w;
    *(float4*)&T[lr][lane * 4] = o4;
  }
  __syncthreads();
  float tmp[16];
#pragma unroll
  for (int l = 0; l < 16; ++l) tmp[l] = T[l][tid];
  float* dst = xnT + ((size_t)(b_ * H + tid)) * LL + l0;
#pragma unroll
  for (int l = 0; l < 16; l += 4) {
    float4 v = {tmp[l], tmp[l + 1], tmp[l + 2], tmp[l + 3]};
    *(float4*)&dst[l] = v;
  }
}

// All layers: blk = i*H + h. K[l] = sum_n cb_n exp(l*dA_n) via binary powering,
// then forward FFT, store half-spectrum.
__global__ __launch_bounds__(256) void k_kernelfft(
    const float* __restrict__ A_re, const float* __restrict__ A_im,
    const float* __restrict__ C_re, const float* __restrict__ C_im,
    const float* __restrict__ log_step, const float2* __restrict__ tw,
    float2* __restrict__ kf) {
  int blk = blockIdx.x;                 // i*H + h
  int i = blk >> 8;
  int tid = threadIdx.x;
  __shared__ float cbr[NST], cbi[NST];
  __shared__ float Ejr[8][NST], Eji[8][NST], Mr[NST], Mi[NST];
  __shared__ float b0r[2112], b0i[2112], b1r[2112], b1i[2112];
  float step = expf(log_step[blk]);
  if (tid < NST) {
    int n = tid;
    float Ar = A_re[i * NST + n], Ai = A_im[i * NST + n];
    float dr = step * Ar, di = step * Ai;
    float er = expf(dr);
    float sn, cs; sincosf(di, &sn, &cs);
    float lr = er * cs, li = er * sn;        // exp(dA)
    float nr = lr - 1.0f, ni = li;
    float dnm = Ar * Ar + Ai * Ai;
    float qr = (nr * Ar + ni * Ai) / dnm;    // (exp(dA)-1)/A
    float qi = (ni * Ar - nr * Ai) / dnm;
    float Cr = C_re[(size_t)blk * NST + n], Ci = C_im[(size_t)blk * NST + n];
    cbr[n] = Cr * qr - Ci * qi;
    cbi[n] = Cr * qi + Ci * qr;
    float xr = lr, xi = li;
#pragma unroll
    for (int j = 0; j < 8; ++j) {
      Ejr[j][n] = xr; Eji[j][n] = xi;
      float t2 = xr * xr - xi * xi;
      xi = 2.0f * xr * xi;
      xr = t2;
    }
    Mr[n] = xr; Mi[n] = xi;
  }
  __syncthreads();
  float kr[4] = {0.f, 0.f, 0.f, 0.f}, ki[4] = {0.f, 0.f, 0.f, 0.f};
  for (int n = 0; n < NST; ++n) {
    float pr = 1.f, pi = 0.f;
#pragma unroll
    for (int j = 0; j < 8; ++j) {
      float er = Ejr[j][n], ei = Eji[j][n];
      float trr = pr * er - pi * ei;
      float tii = pr * ei + pi * er;
      if ((tid >> j) & 1) { pr = trr; pi = tii; }
    }
    float cr = cbr[n], ci = cbi[n];
    float mr = Mr[n], mi = Mi[n];
#pragma unroll
    for (int q = 0; q < 4; ++q) {
      kr[q] += cr * pr - ci * pi;
      ki[q] += cr * pi + ci * pr;
      float t2 = pr * mr - pi * mi;
      pi = pr * mi + pi * mr;
      pr = t2;
    }
  }
#pragma unroll
  for (int q = 0; q < 4; ++q) {
    int l = tid + (q << 8);
    b0r[idxp(l)] = kr[q]; b0i[idxp(l)] = ki[q];
    b0r[idxp(l + 1024)] = 0.f; b0i[idxp(l + 1024)] = 0.f;
  }
  fft2048r4<-1>(b0r, b0i, b1r, b1i, tw, tid);   // result in b0
  float2* kfh = kf + (size_t)blk * 1025;
#pragma unroll
  for (int q = 0; q < 4; ++q) {
    int k = tid + (q << 8);
    kfh[k] = make_float2(b0r[idxp(k)], b0i[idxp(k)]);
  }
  if (tid == 0) kfh[1024] = make_float2(b0r[idxp(1024)], b0i[idxp(1024)]);
}

// Two rows packed per complex FFT; spectral multiply + Hermitian extension
// (irfft bin 0/1024 imag-drop); packed inverse.
__global__ __launch_bounds__(256) void k_conv(
    const float* __restrict__ xnT, const float2* __restrict__ kf,
    const float* __restrict__ D, const float2* __restrict__ tw, float* __restrict__ yT) {
  int blk = blockIdx.x;                 // b*128 + hp
  int b_ = blk >> 7, hp = blk & 127;
  int h0 = hp * 2, h1 = h0 + 1;
  int r0 = b_ * H + h0;
  int tid = threadIdx.x;
  __shared__ float b0r[2112], b0i[2112], b1r[2112], b1i[2112];
  float u0[4], u1[4];
  const float* x0 = xnT + (size_t)r0 * LL;
  const float* x1 = x0 + LL;
#pragma unroll
  for (int q = 0; q < 4; ++q) {
    int l = tid + (q << 8);
    float v0 = x0[l], v1 = x1[l];
    u0[q] = v0; u1[q] = v1;
    b0r[idxp(l)] = v0;          b0i[idxp(l)] = v1;
    b0r[idxp(l + 1024)] = 0.f;  b0i[idxp(l + 1024)] = 0.f;
  }
  fft2048r4<-1>(b0r, b0i, b1r, b1i, tw, tid);   // F in b0
  const float2* kf0 = kf + (size_t)h0 * 1025;
  const float2* kf1 = kf + (size_t)h1 * 1025;
#pragma unroll
  for (int q = 0; q < 4; ++q) {
    int k = tid + (q << 8);
    if (k == 0) {
      float2 k0 = kf0[0], k1 = kf1[0];
      b1r[idxp(0)] = b0r[idxp(0)] * k0.x;
      b1i[idxp(0)] = b0i[idxp(0)] * k1.x;
      float2 k0n = kf0[1024], k1n = kf1[1024];
      b1r[idxp(1024)] = b0r[idxp(1024)] * k0n.x;
      b1i[idxp(1024)] = b0i[idxp(1024)] * k1n.x;
    } else {
      float Fr = b0r[idxp(k)],        Fi = b0i[idxp(k)];
      float Gr = b0r[idxp(2048 - k)], Gi = b0i[idxp(2048 - k)];
      float u0r = 0.5f * (Fr + Gr), u0i = 0.5f * (Fi - Gi);
      float dr_ = 0.5f * (Fr - Gr), di_ = 0.5f * (Fi + Gi);
      float u1r = di_, u1i = -dr_;
      float2 k0 = kf0[k], k1 = kf1[k];
      float z0r = u0r * k0.x - u0i * k0.y, z0i = u0r * k0.y + u0i * k0.x;
      float z1r = u1r * k1.x - u1i * k1.y, z1i = u1r * k1.y + u1i * k1.x;
      b1r[idxp(k)] = z0r - z1i;        b1i[idxp(k)] = z0i + z1r;
      b1r[idxp(2048 - k)] = z0r + z1i; b1i[idxp(2048 - k)] = z1r - z0i;
    }
  }
  fft2048r4<1>(b1r, b1i, b0r, b0i, tw, tid);    // result in b1
  float Dh0 = D[h0], Dh1 = D[h1];
  float* y0 = yT + (size_t)r0 * LL;
  float* y1 = y0 + LL;
#pragma unroll
  for (int q = 0; q < 4; ++q) {
    int l = tid + (q << 8);
    y0[l] = b1r[idxp(l)] * (1.0f / NFFT) + Dh0 * u0[q];
    y1[l] = b1i[idxp(l)] * (1.0f / NFFT) + Dh1 * u1[q];
  }
}

// x += yT (gathered via LDS tile, 64B/thread reads); LN -> xn2 (bf16)
__global__ __launch_bounds__(256) void k_ln2(
    float* __restrict__ x, const float* __restrict__ yT,
    const float* __restrict__ lw, const float* __restrict__ lb, short* __restrict__ xn2) {
  int blk = blockIdx.x;
  int b_ = blk >> 6, l0 = (blk & 63) << 4;
  int tid = threadIdx.x, wv = tid >> 6, lane = tid & 63;
  __shared__ float T[16][256];
  {
    const float* src = yT + ((size_t)(b_ * H + tid)) * LL + l0;
    float tmp[16];
#pragma unroll
    for (int l = 0; l < 16; l += 4) {
      float4 v = *(const float4*)&src[l];
      tmp[l] = v.x; tmp[l + 1] = v.y; tmp[l + 2] = v.z; tmp[l + 3] = v.w;
    }
#pragma unroll
    for (int l = 0; l < 16; ++l) T[l][tid] = tmp[l];
  }
  __syncthreads();
  float4 w4 = *(const float4*)&lw[lane * 4];
  float4 c4 = *(const float4*)&lb[lane * 4];
#pragma unroll
  for (int rr = 0; rr < 4; ++rr) {
    int lr = wv * 4 + rr;
    float* rowx = x + (((size_t)(b_ << 10) + l0 + lr)) * H;
    float4 v = *(const float4*)&rowx[lane * 4];
    float4 yv = *(const float4*)&T[lr][lane * 4];
    v.x += yv.x; v.y += yv.y; v.z += yv.z; v.w += yv.w;
    *(float4*)&rowx[lane * 4] = v;
    float s = v.x + v.y + v.z + v.w;
#pragma unroll
    for (int o = 32; o > 0; o >>= 1) s += __shfl_xor(s, o, 64);
    float m = s * (1.0f / H);
    float dx = v.x - m, dy = v.y - m, dz = v.z - m, dw = v.w - m;
    float q = dx * dx + dy * dy + dz * dz + dw * dw;
#pragma unroll
    for (int o = 32; o > 0; o >>= 1) q += __shfl_xor(q, o, 64);
    float rs = rsqrtf(q * (1.0f / H) + 1e-5f);
    short4v s4;
    s4.x = f2bf(dx * rs * w4.x + c4.x);
    s4.y = f2bf(dy * rs * w4.y + c4.y);
    s4.z = f2bf(dz * rs * w4.z + c4.z);
    s4.w = f2bf(dw * rs * w4.w + c4.w);
    *(short4v*)&xn2[(((size_t)(b_ << 10) + l0 + lr)) * H + lane * 4] = s4;
  }
}

// MFMA bf16 GEMM: C[M,N] = A[M,K] @ Bw[N,K]^T (+bias). Tile 64x128, 4 waves
// (2x2), wave tile 32x64 = 2x4 fragments of 16x16, K-step 64.
// GELU_OUT: Gout[row*Nfull+col] = bf16(gelu(v)).  else: Xres[row*Nfull+col] += v.
template <int K, bool GELU_OUT>
__global__ __launch_bounds__(256) void k_gemm(
    const short* __restrict__ A, const short* __restrict__ Bw,
    const float* __restrict__ bias, short* __restrict__ Gout,
    float* __restrict__ Xres, int Nfull) {
  const int m0 = blockIdx.x * 64;
  const int c0 = blockIdx.y * 128;
  const int tid = threadIdx.x;
  const int lane = tid & 63;
  const int wr = (tid >> 6) >> 1, wc = (tid >> 6) & 1;
  __shared__ short Al[64][72];
  __shared__ short Bl[128][72];
  f32x4 acc[2][4];
#pragma unroll
  for (int m = 0; m < 2; ++m)
#pragma unroll
    for (int n = 0; n < 4; ++n) acc[m][n] = (f32x4){0.f, 0.f, 0.f, 0.f};

  for (int kk = 0; kk < K; kk += 64) {
    __syncthreads();
#pragma unroll
    for (int it = 0; it < 2; ++it) {
      int c = tid + (it << 8);
      int row = c >> 3, off = (c & 7) * 8;
      *(int4v*)&Al[row][off] = *(const int4v*)(A + (size_t)(m0 + row) * K + kk + off);
    }
#pragma unroll
    for (int it = 0; it < 4; ++it) {
      int c = tid + (it << 8);
      int row = c >> 3, off = (c & 7) * 8;
      *(int4v*)&Bl[row][off] = *(const int4v*)(Bw + (size_t)(c0 + row) * K + kk + off);
    }
    __syncthreads();
#pragma unroll
    for (int kc = 0; kc < 2; ++kc) {
      const int ko = kc * 32 + (lane >> 4) * 8;
      bf16x8 af[2], bf[4];
#pragma unroll
      for (int m = 0; m < 2; ++m)
        af[m] = *(const bf16x8*)&Al[wr * 32 + m * 16 + (lane & 15)][ko];
#pragma unroll
      for (int n = 0; n < 4; ++n)
        bf[n] = *(const bf16x8*)&Bl[wc * 64 + n * 16 + (lane & 15)][ko];
#pragma unroll
      for (int m = 0; m < 2; ++m)
#pragma unroll
        for (int n = 0; n < 4; ++n)
          acc[m][n] = __builtin_amdgcn_mfma_f32_16x16x32_bf16(af[m], bf[n], acc[m][n], 0, 0, 0);
    }
  }
#pragma unroll
  for (int m = 0; m < 2; ++m)
#pragma unroll
    for (int n = 0; n < 4; ++n) {
      int col = c0 + wc * 64 + n * 16 + (lane & 15);
      float bv = bias[col];
#pragma unroll
      for (int r = 0; r < 4; ++r) {
        int row = m0 + wr * 32 + m * 16 + (lane >> 4) * 4 + r;
        float v = acc[m][n][r] + bv;
        if (GELU_OUT) {
          v = 0.5f * v * (1.0f + erff(v * 0.70710678118654752f));
          Gout[(size_t)row * Nfull + col] = f2bf(v);
        } else {
          Xres[(size_t)row * Nfull + col] += v;
        }
      }
    }
}

// out[b,co,l] = sum_h x[b,l,h]*Wout[co,h] + b_out[co]
__global__ __launch_bounds__(256) void k_out(
    const float* __restrict__ x, const float* __restrict__ Wout,
    const float* __restrict__ bout, float* __restrict__ out) {
  int row = blockIdx.x;
  int b_ = row >> 10, l = row & 1023;
  int tid = threadIdx.x;
  __shared__ float xr[H];
  xr[tid] = x[row * H + tid];
  __syncthreads();
  int co = tid >> 5, ln = tid & 31;
  float p = 0.f;
#pragma unroll 8
  for (int h2 = ln; h2 < H; h2 += 32) p += xr[h2] * Wout[co * H + h2];
#pragma unroll
  for (int o = 16; o > 0; o >>= 1) p += __shfl_xor(p, o, 64);
  if (ln == 0) out[(b_ * COUT + co) * LL + l] = p + bout[co];
}

extern "C" void kernel_launch(void* const* d_in, const int* in_sizes, int n_in,
                              void* d_out, int out_size, void* d_ws, size_t ws_size,
                              hipStream_t stream) {
  const float* stim  = (const float*)d_in[0];
  const float* init  = (const float*)d_in[1];
  const float* A_re  = (const float*)d_in[2];
  const float* A_im  = (const float*)d_in[3];
  const float* C_re  = (const float*)d_in[4];
  const float* C_im  = (const float*)d_in[5];
  const float* Dp    = (const float*)d_in[6];
  const float* lstep = (const float*)d_in[7];
  const float* ln1w  = (const float*)d_in[8];
  const float* ln1b  = (const float*)d_in[9];
  const float* ln2w  = (const float*)d_in[10];
  const float* ln2b  = (const float*)d_in[11];
  const float* W1    = (const float*)d_in[12];
  const float* b1    = (const float*)d_in[13];
  const float* W2    = (const float*)d_in[14];
  const float* b2    = (const float*)d_in[15];
  const float* Win   = (const float*)d_in[16];
  const float* bin   = (const float*)d_in[17];
  const float* Wst   = (const float*)d_in[18];
  const float* bst   = (const float*)d_in[19];
  const float* Wout  = (const float*)d_in[20];
  const float* bout  = (const float*)d_in[21];
  float* out = (float*)d_out;
  float* ws = (float*)d_ws;

  size_t o = 0;
  auto alloc = [&](size_t nfloats) { size_t r = o; o += (nfloats + 63) & ~(size_t)63; return r; };
  float*  x    = ws + alloc((size_t)BB * LL * H);
  float*  xnT  = ws + alloc((size_t)BB * H * LL);
  float*  yT   = ws + alloc((size_t)BB * H * LL);
  short*  xn2  = (short*)(ws + alloc((size_t)BB * LL * H / 2));
  short*  g1   = (short*)(ws + alloc((size_t)BB * LL * 512 / 2));
  float2* kf   = (float2*)(ws + alloc((size_t)NL * H * 1025 * 2));
  short*  W1bf = (short*)(ws + alloc((size_t)NL * 512 * 256 / 2));
  short*  W2bf = (short*)(ws + alloc((size_t)NL * 256 * 512 / 2));
  float*  WinT = ws + alloc((size_t)64 * 256);
  float*  sp   = ws + alloc((size_t)BB * H);
  float2* tw   = (float2*)(ws + alloc((size_t)1536 * 2));
  (void)ws_size; (void)in_sizes; (void)n_in; (void)out_size;

  k_init_tw<<<6, 256, 0, stream>>>(tw);
  k_kernelfft<<<NL * H, 256, 0, stream>>>(A_re, A_im, C_re, C_im, lstep, tw, kf);
  k_prep<<<2048, 256, 0, stream>>>(W1, W2, Win, W1bf, W2bf, WinT);
  k_state_proj<<<BB, 256, 0, stream>>>(init, Wst, bst, bin, sp);
  k_input_proj<<<BB * LL, 256, 0, stream>>>(stim, WinT, sp, x);

  for (int i = 0; i < NL; ++i) {
    k_ln1<<<BB * 64, 256, 0, stream>>>(x, ln1w + i * H, ln1b + i * H, xnT);
    k_conv<<<BB * H / 2, 256, 0, stream>>>(xnT, kf + (size_t)i * H * 1025,
                                           Dp + i * H, tw, yT);
    k_ln2<<<BB * 64, 256, 0, stream>>>(x, yT, ln2w + i * H, ln2b + i * H, xn2);
    dim3 g1grid(128, 4);
    k_gemm<256, true><<<g1grid, 256, 0, stream>>>(
        xn2, W1bf + (size_t)i * 512 * 256, b1 + i * 512, g1, nullptr, 512);
    dim3 g2grid(128, 2);
    k_gemm<512, false><<<g2grid, 256, 0, stream>>>(
        g1, W2bf + (size_t)i * 256 * 512, b2 + i * H, nullptr, x, 256);
  }
  k_out<<<BB * LL, 256, 0, stream>>>(x, Wout, bout, out);
}

// Round 4
// 324.102 us; speedup vs baseline: 2.9232x; 1.1037x over previous
//
#include <hip/hip_runtime.h>
#include <math.h>

#define NL   4
#define H    256
#define NST  64
#define CIN  64
#define COUT 8
#define BB   8
#define LL   1024
#define NFFT 2048

typedef __attribute__((ext_vector_type(8))) short bf16x8;
typedef __attribute__((ext_vector_type(4))) short short4v;
typedef __attribute__((ext_vector_type(4))) int   int4v;
typedef __attribute__((ext_vector_type(4))) float f32x4;

__device__ __forceinline__ short f2bf(float f) {
  union { float f; unsigned u; } v; v.f = f;
  unsigned r = (v.u + 0x7fffu + ((v.u >> 16) & 1u)) >> 16;
  return (short)r;
}
// pad every 16 float2 (128B) -> stage-0 stride-4 writes become ~4-way (free-ish)
__device__ __forceinline__ int IDX2(int a) { return a + (a >> 4); }
#define FBUF 2176   // 2048 + 128 pad

// ---------------------------------------------------------------------------
// 2048-pt FFT, float2 LDS: 5 radix-4 Stockham stages (m=1,4,16,64,256) +
// final twiddle-free radix-2 (m=1024). Input in b0 at IDX2(); result in b0.
// PADDED: input has zero upper half (bins 1024..2047) -> stage 0 skips C/D.
// tw[t] = (cos(pi t/1024), -sin(pi t/1024)), t in [0,1536).
// ---------------------------------------------------------------------------
template <int SGN, bool PADDED>
__device__ __forceinline__ void fft2048r4(float2* b0, float2* b1,
                                          const float2* __restrict__ tw, int tid) {
  float2 *s = b0, *d = b1;
#pragma unroll
  for (int st = 0; st < 5; ++st) {
    const int m = 1 << (2 * st);
    __syncthreads();
#pragma unroll
    for (int q = 0; q < 2; ++q) {
      const int t  = tid + (q << 8);          // [0,512)
      const int k  = t & (m - 1);
      const int jm = t - k;                   // multiple of m, < 512
      float2 A = s[IDX2(t)], B = s[IDX2(t + 512)];
      float2 C, Dv;
      if (PADDED && st == 0) { C = make_float2(0.f, 0.f); Dv = make_float2(0.f, 0.f); }
      else { C = s[IDX2(t + 1024)]; Dv = s[IDX2(t + 1536)]; }
      float s0r = A.x + C.x,  s0i = A.y + C.y;    // A+C
      float s1r = A.x - C.x,  s1i = A.y - C.y;    // A-C
      float s2r = B.x + Dv.x, s2i = B.y + Dv.y;   // B+D
      float s3r = B.x - Dv.x, s3i = B.y - Dv.y;   // B-D
      float mir, mii;                              // -i(B-D) fwd, +i(B-D) inv
      if (SGN < 0) { mir =  s3i; mii = -s3r; }
      else         { mir = -s3i; mii =  s3r; }
      float o0r = s0r + s2r, o0i = s0i + s2i;     // * W^0
      float o1r = s1r + mir, o1i = s1i + mii;     // * W^jm
      float o2r = s0r - s2r, o2i = s0i - s2i;     // * W^2jm
      float o3r = s1r - mir, o3i = s1i - mii;     // * W^3jm
      float2 w1 = tw[jm], w2 = tw[2 * jm], w3 = tw[3 * jm];
      float w1i = (SGN < 0) ? w1.y : -w1.y;
      float w2i = (SGN < 0) ? w2.y : -w2.y;
      float w3i = (SGN < 0) ? w3.y : -w3.y;
      const int base = 4 * jm + k;
      d[IDX2(base)]         = make_float2(o0r, o0i);
      d[IDX2(base + m)]     = make_float2(o1r * w1.x - o1i * w1i, o1r * w1i + o1i * w1.x);
      d[IDX2(base + 2*m)]   = make_float2(o2r * w2.x - o2i * w2i, o2r * w2i + o2i * w2.x);
      d[IDX2(base + 3*m)]   = make_float2(o3r * w3.x - o3i * w3i, o3r * w3i + o3i * w3.x);
    }
    float2* tp = s; s = d; d = tp;
  }
  // final radix-2, m=1024, jm=0 -> no twiddle. s==b1, d==b0 here.
  __syncthreads();
#pragma unroll
  for (int q = 0; q < 4; ++q) {
    const int i = tid + (q << 8);
    float2 a = s[IDX2(i)], b = s[IDX2(i + 1024)];
    d[IDX2(i)]        = make_float2(a.x + b.x, a.y + b.y);
    d[IDX2(i + 1024)] = make_float2(a.x - b.x, a.y - b.y);
  }
  __syncthreads();   // result in b0
}

__global__ __launch_bounds__(256) void k_init_tw(float2* tw) {
  int t = blockIdx.x * 256 + threadIdx.x;
  if (t < 1536) {
    float s, c;
    sincosf(3.14159265358979323846f * (float)t / 1024.0f, &s, &c);
    tw[t] = make_float2(c, -s);
  }
}

// bf16 weight copies + Win transpose
__global__ __launch_bounds__(256) void k_prep(
    const float* __restrict__ W1, const float* __restrict__ W2, const float* __restrict__ Win,
    short* __restrict__ W1bf, short* __restrict__ W2bf, float* __restrict__ WinT) {
  int idx = blockIdx.x * 256 + threadIdx.x;
  if (idx < NL * 512 * 256) {
    W1bf[idx] = f2bf(W1[idx]);
    W2bf[idx] = f2bf(W2[idx]);
  }
  if (idx < 256 * 64) {
    int hh = idx / 64, c = idx % 64;
    WinT[c * 256 + hh] = Win[idx];
  }
}

__global__ __launch_bounds__(256) void k_state_proj(
    const float* __restrict__ init, const float* __restrict__ Wst,
    const float* __restrict__ bst, const float* __restrict__ bin, float* __restrict__ sp) {
  int b = blockIdx.x, h = threadIdx.x;
  float acc = bin[h] + bst[h];
#pragma unroll
  for (int c = 0; c < COUT; ++c) acc += init[b * COUT + c] * Wst[h * COUT + c];
  sp[b * H + h] = acc;
}

__global__ __launch_bounds__(256) void k_input_proj(
    const float* __restrict__ stim, const float* __restrict__ WinT,
    const float* __restrict__ sp, float* __restrict__ x) {
  int row = blockIdx.x;               // b*L + l
  int b = row >> 10, l = row & 1023;
  int h = threadIdx.x;
  __shared__ float sc[CIN];
  if (h < CIN) sc[h] = stim[(b * CIN + h) * LL + l];
  __syncthreads();
  float acc = sp[b * H + h];
#pragma unroll 8
  for (int c = 0; c < CIN; ++c) acc += sc[c] * WinT[c * H + h];
  x[row * H + h] = acc;
}

// LN over H for a 16-row l-tile; transposed write via LDS, 64B/thread.
__global__ __launch_bounds__(256) void k_ln1(
    const float* __restrict__ x, const float* __restrict__ lw, const float* __restrict__ lb,
    float* __restrict__ xnT) {
  int blk = blockIdx.x;               // b*64 + ltile
  int b_ = blk >> 6, l0 = (blk & 63) << 4;
  int tid = threadIdx.x, wv = tid >> 6, lane = tid & 63;
  __shared__ float T[16][256];
  float4 w4 = *(const float4*)&lw[lane * 4];
  float4 c4 = *(const float4*)&lb[lane * 4];
#pragma unroll
  for (int rr = 0; rr < 4; ++rr) {
    int lr = wv * 4 + rr;
    const float* row = x + (((size_t)(b_ << 10) + l0 + lr)) * H;
    float4 v = *(const float4*)&row[lane * 4];
    float s = v.x + v.y + v.z + v.w;
#pragma unroll
    for (int o = 32; o > 0; o >>= 1) s += __shfl_xor(s, o, 64);
    float m = s * (1.0f / H);
    float dx = v.x - m, dy = v.y - m, dz = v.z - m, dw = v.w - m;
    float q = dx * dx + dy * dy + dz * dz + dw * dw;
#pragma unroll
    for (int o = 32; o > 0; o >>= 1) q += __shfl_xor(q, o, 64);
    float rs = rsqrtf(q * (1.0f / H) + 1e-5f);
    float4 o4;
    o4.x = dx * rs * w4.x + c4.x; o4.y = dy * rs * w4.y + c4.y;
    o4.z = dz * rs * w4.z + c4.z; o4.w = dw * rs * w4.w + c4.w;
    *(float4*)&T[lr][lane * 4] = o4;
  }
  __syncthreads();
  float tmp[16];
#pragma unroll
  for (int l = 0; l < 16; ++l) tmp[l] = T[l][tid];
  float* dst = xnT + ((size_t)(b_ * H + tid)) * LL + l0;
#pragma unroll
  for (int l = 0; l < 16; l += 4) {
    float4 v = {tmp[l], tmp[l + 1], tmp[l + 2], tmp[l + 3]};
    *(float4*)&dst[l] = v;
  }
}

// All layers: blk = i*H + h. K[l] = sum_n cb_n * E_n^l with E^l = T1[l&15] *
// T2[l>>4 & 15] * M^(l>>8) from per-n LDS tables (no per-(l,n) transcendentals,
// no per-n powering chain). Then forward FFT, store half-spectrum.
__global__ __launch_bounds__(256) void k_kernelfft(
    const float* __restrict__ A_re, const float* __restrict__ A_im,
    const float* __restrict__ C_re, const float* __restrict__ C_im,
    const float* __restrict__ log_step, const float2* __restrict__ tw,
    float2* __restrict__ kf) {
  int blk = blockIdx.x;                 // i*H + h
  int i = blk >> 8;
  int tid = threadIdx.x;
  __shared__ float2 cb[NST], Mv[NST];
  __shared__ float2 bufA[FBUF], bufB[FBUF];
  float2* T1 = bufB;                    // [n][16], overlays FFT scratch
  float2* T2 = bufB + 1024;             // [n][16]
  float step = expf(log_step[blk]);
  int n = tid & 63, g = tid >> 6;
  float Ar = A_re[i * NST + n], Ai = A_im[i * NST + n];
  float dr = step * Ar, di = step * Ai;
  float er = expf(dr);
  float sn, cs; sincosf(di, &sn, &cs);
  float Er = er * cs, Ei = er * sn;     // E = exp(dA)
  if (g == 0) {
    float nr = Er - 1.0f, ni = Ei;
    float dnm = Ar * Ar + Ai * Ai;
    float qr = (nr * Ar + ni * Ai) / dnm;    // (exp(dA)-1)/A
    float qi = (ni * Ar - nr * Ai) / dnm;
    float Cr = C_re[(size_t)blk * NST + n], Ci = C_im[(size_t)blk * NST + n];
    cb[n] = make_float2(Cr * qr - Ci * qi, Cr * qi + Ci * qr);
    float pr = 1.f, pi = 0.f;
    T1[n * 16] = make_float2(1.f, 0.f);
    for (int a = 1; a < 16; ++a) {
      float t2 = pr * Er - pi * Ei; pi = pr * Ei + pi * Er; pr = t2;
      T1[n * 16 + a] = make_float2(pr, pi);
    }
  } else if (g == 1) {
    float xr = Er, xi = Ei;
#pragma unroll
    for (int j = 0; j < 4; ++j) { float t2 = xr * xr - xi * xi; xi = 2.f * xr * xi; xr = t2; }
    // xr,xi = E^16
    float pr = 1.f, pi = 0.f;
    T2[n * 16] = make_float2(1.f, 0.f);
    for (int a = 1; a < 16; ++a) {
      float t2 = pr * xr - pi * xi; pi = pr * xi + pi * xr; pr = t2;
      T2[n * 16 + a] = make_float2(pr, pi);
    }
    float mr2 = pr * xr - pi * xi, mi2 = pr * xi + pi * xr;   // E^256
    Mv[n] = make_float2(mr2, mi2);
  }
  __syncthreads();
  float kr[4] = {0.f, 0.f, 0.f, 0.f}, ki[4] = {0.f, 0.f, 0.f, 0.f};
  const int a_lo = tid & 15, a_hi = tid >> 4;
  for (int nn = 0; nn < NST; ++nn) {
    float2 t1 = T1[nn * 16 + a_lo];
    float2 t2v = T2[nn * 16 + a_hi];
    float pr = t1.x * t2v.x - t1.y * t2v.y;   // E^tid
    float pi = t1.x * t2v.y + t1.y * t2v.x;
    float2 c = cb[nn], m = Mv[nn];
#pragma unroll
    for (int q = 0; q < 4; ++q) {
      kr[q] += c.x * pr - c.y * pi;
      ki[q] += c.x * pi + c.y * pr;
      float t2 = pr * m.x - pi * m.y;         // p *= E^256
      pi = pr * m.y + pi * m.x;
      pr = t2;
    }
  }
  __syncthreads();   // powering done before bufB (tables) is clobbered by FFT
#pragma unroll
  for (int q = 0; q < 4; ++q) {
    int l = tid + (q << 8);
    bufA[IDX2(l)] = make_float2(kr[q], ki[q]);
  }
  fft2048r4<-1, true>(bufA, bufB, tw, tid);   // result in bufA
  float2* kfh = kf + (size_t)blk * 1025;
#pragma unroll
  for (int q = 0; q < 4; ++q) {
    int k = tid + (q << 8);
    kfh[k] = bufA[IDX2(k)];
  }
  if (tid == 0) kfh[1024] = bufA[IDX2(1024)];
}

// Two rows packed per complex FFT; spectral multiply + Hermitian extension
// (irfft bin 0/1024 imag-drop); packed inverse.
__global__ __launch_bounds__(256) void k_conv(
    const float* __restrict__ xnT, const float2* __restrict__ kf,
    const float* __restrict__ D, const float2* __restrict__ tw, float* __restrict__ yT) {
  int blk = blockIdx.x;                 // b*128 + hp
  int b_ = blk >> 7, hp = blk & 127;
  int h0 = hp * 2, h1 = h0 + 1;
  int r0 = b_ * H + h0;
  int tid = threadIdx.x;
  __shared__ float2 bufA[FBUF], bufB[FBUF];
  float u0[4], u1[4];
  const float* x0 = xnT + (size_t)r0 * LL;
  const float* x1 = x0 + LL;
#pragma unroll
  for (int q = 0; q < 4; ++q) {
    int l = tid + (q << 8);
    float v0 = x0[l], v1 = x1[l];
    u0[q] = v0; u1[q] = v1;
    bufA[IDX2(l)] = make_float2(v0, v1);      // upper half implicit zero (PADDED)
  }
  fft2048r4<-1, true>(bufA, bufB, tw, tid);   // F = FFT(u0 + i*u1) in bufA
  const float2* kf0 = kf + (size_t)h0 * 1025;
  const float2* kf1 = kf + (size_t)h1 * 1025;
#pragma unroll
  for (int q = 0; q < 4; ++q) {
    int k = tid + (q << 8);
    if (k == 0) {
      float2 k0 = kf0[0], k1 = kf1[0];
      float2 F0 = bufA[IDX2(0)], Fn = bufA[IDX2(1024)];
      bufB[IDX2(0)]    = make_float2(F0.x * k0.x, F0.y * k1.x);
      float2 k0n = kf0[1024], k1n = kf1[1024];
      bufB[IDX2(1024)] = make_float2(Fn.x * k0n.x, Fn.y * k1n.x);
    } else {
      float2 F = bufA[IDX2(k)], G = bufA[IDX2(2048 - k)];
      float u0r = 0.5f * (F.x + G.x), u0i = 0.5f * (F.y - G.y);   // U0[k]
      float dr_ = 0.5f * (F.x - G.x), di_ = 0.5f * (F.y + G.y);
      float u1r = di_, u1i = -dr_;                                // U1[k]
      float2 k0 = kf0[k], k1 = kf1[k];
      float z0r = u0r * k0.x - u0i * k0.y, z0i = u0r * k0.y + u0i * k0.x;
      float z1r = u1r * k1.x - u1i * k1.y, z1i = u1r * k1.y + u1i * k1.x;
      bufB[IDX2(k)]        = make_float2(z0r - z1i, z0i + z1r);
      bufB[IDX2(2048 - k)] = make_float2(z0r + z1i, z1r - z0i);
    }
  }
  fft2048r4<1, false>(bufB, bufA, tw, tid);   // z0 + i*z1 in bufB (both real)
  float Dh0 = D[h0], Dh1 = D[h1];
  float* y0 = yT + (size_t)r0 * LL;
  float* y1 = y0 + LL;
#pragma unroll
  for (int q = 0; q < 4; ++q) {
    int l = tid + (q << 8);
    float2 z = bufB[IDX2(l)];
    y0[l] = z.x * (1.0f / NFFT) + Dh0 * u0[q];
    y1[l] = z.y * (1.0f / NFFT) + Dh1 * u1[q];
  }
}

// x += yT (gathered via LDS tile, 64B/thread reads); LN -> xn2 (bf16)
__global__ __launch_bounds__(256) void k_ln2(
    float* __restrict__ x, const float* __restrict__ yT,
    const float* __restrict__ lw, const float* __restrict__ lb, short* __restrict__ xn2) {
  int blk = blockIdx.x;
  int b_ = blk >> 6, l0 = (blk & 63) << 4;
  int tid = threadIdx.x, wv = tid >> 6, lane = tid & 63;
  __shared__ float T[16][256];
  {
    const float* src = yT + ((size_t)(b_ * H + tid)) * LL + l0;
    float tmp[16];
#pragma unroll
    for (int l = 0; l < 16; l += 4) {
      float4 v = *(const float4*)&src[l];
      tmp[l] = v.x; tmp[l + 1] = v.y; tmp[l + 2] = v.z; tmp[l + 3] = v.w;
    }
#pragma unroll
    for (int l = 0; l < 16; ++l) T[l][tid] = tmp[l];
  }
  __syncthreads();
  float4 w4 = *(const float4*)&lw[lane * 4];
  float4 c4 = *(const float4*)&lb[lane * 4];
#pragma unroll
  for (int rr = 0; rr < 4; ++rr) {
    int lr = wv * 4 + rr;
    float* rowx = x + (((size_t)(b_ << 10) + l0 + lr)) * H;
    float4 v = *(const float4*)&rowx[lane * 4];
    float4 yv = *(const float4*)&T[lr][lane * 4];
    v.x += yv.x; v.y += yv.y; v.z += yv.z; v.w += yv.w;
    *(float4*)&rowx[lane * 4] = v;
    float s = v.x + v.y + v.z + v.w;
#pragma unroll
    for (int o = 32; o > 0; o >>= 1) s += __shfl_xor(s, o, 64);
    float m = s * (1.0f / H);
    float dx = v.x - m, dy = v.y - m, dz = v.z - m, dw = v.w - m;
    float q = dx * dx + dy * dy + dz * dz + dw * dw;
#pragma unroll
    for (int o = 32; o > 0; o >>= 1) q += __shfl_xor(q, o, 64);
    float rs = rsqrtf(q * (1.0f / H) + 1e-5f);
    short4v s4;
    s4.x = f2bf(dx * rs * w4.x + c4.x);
    s4.y = f2bf(dy * rs * w4.y + c4.y);
    s4.z = f2bf(dz * rs * w4.z + c4.z);
    s4.w = f2bf(dw * rs * w4.w + c4.w);
    *(short4v*)&xn2[(((size_t)(b_ << 10) + l0 + lr)) * H + lane * 4] = s4;
  }
}

// MFMA bf16 GEMM: C[M,N] = A[M,K] @ Bw[N,K]^T (+bias). Tile 64x128, 4 waves
// (2x2), wave tile 32x64 = 2x4 fragments of 16x16, K-step 64.
template <int K, bool GELU_OUT>
__global__ __launch_bounds__(256) void k_gemm(
    const short* __restrict__ A, const short* __restrict__ Bw,
    const float* __restrict__ bias, short* __restrict__ Gout,
    float* __restrict__ Xres, int Nfull) {
  const int m0 = blockIdx.x * 64;
  const int c0 = blockIdx.y * 128;
  const int tid = threadIdx.x;
  const int lane = tid & 63;
  const int wr = (tid >> 6) >> 1, wc = (tid >> 6) & 1;
  __shared__ short Al[64][72];
  __shared__ short Bl[128][72];
  f32x4 acc[2][4];
#pragma unroll
  for (int m = 0; m < 2; ++m)
#pragma unroll
    for (int n = 0; n < 4; ++n) acc[m][n] = (f32x4){0.f, 0.f, 0.f, 0.f};

  for (int kk = 0; kk < K; kk += 64) {
    __syncthreads();
#pragma unroll
    for (int it = 0; it < 2; ++it) {
      int c = tid + (it << 8);
      int row = c >> 3, off = (c & 7) * 8;
      *(int4v*)&Al[row][off] = *(const int4v*)(A + (size_t)(m0 + row) * K + kk + off);
    }
#pragma unroll
    for (int it = 0; it < 4; ++it) {
      int c = tid + (it << 8);
      int row = c >> 3, off = (c & 7) * 8;
      *(int4v*)&Bl[row][off] = *(const int4v*)(Bw + (size_t)(c0 + row) * K + kk + off);
    }
    __syncthreads();
#pragma unroll
    for (int kc = 0; kc < 2; ++kc) {
      const int ko = kc * 32 + (lane >> 4) * 8;
      bf16x8 af[2], bf[4];
#pragma unroll
      for (int m = 0; m < 2; ++m)
        af[m] = *(const bf16x8*)&Al[wr * 32 + m * 16 + (lane & 15)][ko];
#pragma unroll
      for (int n = 0; n < 4; ++n)
        bf[n] = *(const bf16x8*)&Bl[wc * 64 + n * 16 + (lane & 15)][ko];
#pragma unroll
      for (int m = 0; m < 2; ++m)
#pragma unroll
        for (int n = 0; n < 4; ++n)
          acc[m][n] = __builtin_amdgcn_mfma_f32_16x16x32_bf16(af[m], bf[n], acc[m][n], 0, 0, 0);
    }
  }
#pragma unroll
  for (int m = 0; m < 2; ++m)
#pragma unroll
    for (int n = 0; n < 4; ++n) {
      int col = c0 + wc * 64 + n * 16 + (lane & 15);
      float bv = bias[col];
#pragma unroll
      for (int r = 0; r < 4; ++r) {
        int row = m0 + wr * 32 + m * 16 + (lane >> 4) * 4 + r;
        float v = acc[m][n][r] + bv;
        if (GELU_OUT) {
          v = 0.5f * v * (1.0f + erff(v * 0.70710678118654752f));
          Gout[(size_t)row * Nfull + col] = f2bf(v);
        } else {
          Xres[(size_t)row * Nfull + col] += v;
        }
      }
    }
}

// out[b,co,l] = sum_h x[b,l,h]*Wout[co,h] + b_out[co]
__global__ __launch_bounds__(256) void k_out(
    const float* __restrict__ x, const float* __restrict__ Wout,
    const float* __restrict__ bout, float* __restrict__ out) {
  int row = blockIdx.x;
  int b_ = row >> 10, l = row & 1023;
  int tid = threadIdx.x;
  __shared__ float xr[H];
  xr[tid] = x[row * H + tid];
  __syncthreads();
  int co = tid >> 5, ln = tid & 31;
  float p = 0.f;
#pragma unroll 8
  for (int h2 = ln; h2 < H; h2 += 32) p += xr[h2] * Wout[co * H + h2];
#pragma unroll
  for (int o = 16; o > 0; o >>= 1) p += __shfl_xor(p, o, 64);
  if (ln == 0) out[(b_ * COUT + co) * LL + l] = p + bout[co];
}

extern "C" void kernel_launch(void* const* d_in, const int* in_sizes, int n_in,
                              void* d_out, int out_size, void* d_ws, size_t ws_size,
                              hipStream_t stream) {
  const float* stim  = (const float*)d_in[0];
  const float* init  = (const float*)d_in[1];
  const float* A_re  = (const float*)d_in[2];
  const float* A_im  = (const float*)d_in[3];
  const float* C_re  = (const float*)d_in[4];
  const float* C_im  = (const float*)d_in[5];
  const float* Dp    = (const float*)d_in[6];
  const float* lstep = (const float*)d_in[7];
  const float* ln1w  = (const float*)d_in[8];
  const float* ln1b  = (const float*)d_in[9];
  const float* ln2w  = (const float*)d_in[10];
  const float* ln2b  = (const float*)d_in[11];
  const float* W1    = (const float*)d_in[12];
  const float* b1    = (const float*)d_in[13];
  const float* W2    = (const float*)d_in[14];
  const float* b2    = (const float*)d_in[15];
  const float* Win   = (const float*)d_in[16];
  const float* bin   = (const float*)d_in[17];
  const float* Wst   = (const float*)d_in[18];
  const float* bst   = (const float*)d_in[19];
  const float* Wout  = (const float*)d_in[20];
  const float* bout  = (const float*)d_in[21];
  float* out = (float*)d_out;
  float* ws = (float*)d_ws;

  size_t o = 0;
  auto alloc = [&](size_t nfloats) { size_t r = o; o += (nfloats + 63) & ~(size_t)63; return r; };
  float*  x    = ws + alloc((size_t)BB * LL * H);
  float*  xnT  = ws + alloc((size_t)BB * H * LL);
  float*  yT   = ws + alloc((size_t)BB * H * LL);
  short*  xn2  = (short*)(ws + alloc((size_t)BB * LL * H / 2));
  short*  g1   = (short*)(ws + alloc((size_t)BB * LL * 512 / 2));
  float2* kf   = (float2*)(ws + alloc((size_t)NL * H * 1025 * 2));
  short*  W1bf = (short*)(ws + alloc((size_t)NL * 512 * 256 / 2));
  short*  W2bf = (short*)(ws + alloc((size_t)NL * 256 * 512 / 2));
  float*  WinT = ws + alloc((size_t)64 * 256);
  float*  sp   = ws + alloc((size_t)BB * H);
  float2* tw   = (float2*)(ws + alloc((size_t)1536 * 2));
  (void)ws_size; (void)in_sizes; (void)n_in; (void)out_size;

  k_init_tw<<<6, 256, 0, stream>>>(tw);
  k_kernelfft<<<NL * H, 256, 0, stream>>>(A_re, A_im, C_re, C_im, lstep, tw, kf);
  k_prep<<<2048, 256, 0, stream>>>(W1, W2, Win, W1bf, W2bf, WinT);
  k_state_proj<<<BB, 256, 0, stream>>>(init, Wst, bst, bin, sp);
  k_input_proj<<<BB * LL, 256, 0, stream>>>(stim, WinT, sp, x);

  for (int i = 0; i < NL; ++i) {
    k_ln1<<<BB * 64, 256, 0, stream>>>(x, ln1w + i * H, ln1b + i * H, xnT);
    k_conv<<<BB * H / 2, 256, 0, stream>>>(xnT, kf + (size_t)i * H * 1025,
                                           Dp + i * H, tw, yT);
    k_ln2<<<BB * 64, 256, 0, stream>>>(x, yT, ln2w + i * H, ln2b + i * H, xn2);
    dim3 g1grid(128, 4);
    k_gemm<256, true><<<g1grid, 256, 0, stream>>>(
        xn2, W1bf + (size_t)i * 512 * 256, b1 + i * 512, g1, nullptr, 512);
    dim3 g2grid(128, 2);
    k_gemm<512, false><<<g2grid, 256, 0, stream>>>(
        g1, W2bf + (size_t)i * 256 * 512, b2 + i * H, nullptr, x, 256);
  }
  k_out<<<BB * LL, 256, 0, stream>>>(x, Wout, bout, out);
}

// Round 5
// 299.598 us; speedup vs baseline: 3.1623x; 1.0818x over previous
//
#include <hip/hip_runtime.h>
#include <math.h>

#define NL   4
#define H    256
#define NST  64
#define CIN  64
#define COUT 8
#define BB   8
#define LL   1024
#define NFFT 2048

typedef __attribute__((ext_vector_type(8))) short bf16x8;
typedef __attribute__((ext_vector_type(4))) short short4v;
typedef __attribute__((ext_vector_type(4))) int   int4v;
typedef __attribute__((ext_vector_type(4))) float f32x4;

__device__ __forceinline__ short f2bf(float f) {
  union { float f; unsigned u; } v; v.f = f;
  unsigned r = (v.u + 0x7fffu + ((v.u >> 16) & 1u)) >> 16;
  return (short)r;
}
// pad every 16 float2 (128B) -> strided stage writes stay ~2-way (free)
__device__ __forceinline__ int IDX2(int a) { return a + (a >> 4); }
#define FBUF 2176   // 2048 + 128 pad

__device__ __forceinline__ float2 cadd(float2 a, float2 b) { return make_float2(a.x + b.x, a.y + b.y); }
__device__ __forceinline__ float2 csub(float2 a, float2 b) { return make_float2(a.x - b.x, a.y - b.y); }

// ---------------------------------------------------------------------------
// 2048-pt FFT, float2 LDS: 3 radix-8 Stockham stages (m=1,8,64) + final
// twiddle-free radix-4 (m=512). Stage rule (verified vs radix-2/4 composition
// and N=8 delta test): dst[R*jm + k + d*m] = DFT_R(a)_d * W_N^{d*jm}.
// Input in b0 at IDX2(); result lands in b0. PADDED: upper half (>=1024) is
// zero -> stage 0 skips those reads. tw[t] = W_2048^t = e^{-i pi t/1024}.
// ---------------------------------------------------------------------------
template <int SGN, bool PADDED>
__device__ __forceinline__ void fft2048(float2* b0, float2* b1,
                                        const float2* __restrict__ tw, int tid) {
  const float RH = 0.70710678118654752f;
  float2 *s = b0, *d = b1;
#pragma unroll
  for (int st = 0; st < 3; ++st) {
    const int m = 1 << (3 * st);            // 1, 8, 64
    __syncthreads();
    const int k  = tid & (m - 1);
    const int jm = tid - k;                 // multiple of m, < 256
    float2 a0 = s[IDX2(tid)];
    float2 a1 = s[IDX2(tid + 256)];
    float2 a2 = s[IDX2(tid + 512)];
    float2 a3 = s[IDX2(tid + 768)];
    float2 a4, a5, a6, a7;
    if (PADDED && st == 0) {
      a4 = make_float2(0.f, 0.f); a5 = a4; a6 = a4; a7 = a4;
    } else {
      a4 = s[IDX2(tid + 1024)];
      a5 = s[IDX2(tid + 1280)];
      a6 = s[IDX2(tid + 1536)];
      a7 = s[IDX2(tid + 1792)];
    }
    // even 4-pt DFT on (a0,a2,a4,a6)
    float2 s0 = cadd(a0, a4), s1 = csub(a0, a4), s2 = cadd(a2, a6), s3 = csub(a2, a6);
    float2 mi = (SGN < 0) ? make_float2(s3.y, -s3.x) : make_float2(-s3.y, s3.x);
    float2 E0 = cadd(s0, s2), E1 = cadd(s1, mi), E2 = csub(s0, s2), E3 = csub(s1, mi);
    // odd 4-pt DFT on (a1,a3,a5,a7)
    float2 t0 = cadd(a1, a5), t1 = csub(a1, a5), t2 = cadd(a3, a7), t3 = csub(a3, a7);
    float2 mj = (SGN < 0) ? make_float2(t3.y, -t3.x) : make_float2(-t3.y, t3.x);
    float2 O0 = cadd(t0, t2), O1 = cadd(t1, mj), O2 = csub(t0, t2), O3 = csub(t1, mj);
    // W_d = omega8^(+-d) * O_d
    float2 W0 = O0;
    float2 W1 = (SGN < 0) ? make_float2((O1.x + O1.y) * RH, (O1.y - O1.x) * RH)
                          : make_float2((O1.x - O1.y) * RH, (O1.x + O1.y) * RH);
    float2 W2 = (SGN < 0) ? make_float2(O2.y, -O2.x) : make_float2(-O2.y, O2.x);
    float2 W3 = (SGN < 0) ? make_float2((O3.y - O3.x) * RH, -(O3.x + O3.y) * RH)
                          : make_float2(-(O3.x + O3.y) * RH, (O3.x - O3.y) * RH);
    float2 A[8];
    A[0] = cadd(E0, W0); A[4] = csub(E0, W0);
    A[1] = cadd(E1, W1); A[5] = csub(E1, W1);
    A[2] = cadd(E2, W2); A[6] = csub(E2, W2);
    A[3] = cadd(E3, W3); A[7] = csub(E3, W3);
    const int base = 8 * jm + k;
    d[IDX2(base)] = A[0];
#pragma unroll
    for (int dd = 1; dd < 8; ++dd) {
      float2 w = tw[dd * jm];
      float wi = (SGN < 0) ? w.y : -w.y;
      float2 v = A[dd];
      d[IDX2(base + dd * m)] = make_float2(v.x * w.x - v.y * wi, v.x * wi + v.y * w.x);
    }
    float2* tp = s; s = d; d = tp;
  }
  // final radix-4 stage, m=512: jm=0 -> twiddle-free. s==b1, d==b0 here.
  __syncthreads();
#pragma unroll
  for (int q = 0; q < 2; ++q) {
    const int t = tid + (q << 8);           // [0,512)
    float2 x0 = s[IDX2(t)], x1 = s[IDX2(t + 512)];
    float2 x2 = s[IDX2(t + 1024)], x3 = s[IDX2(t + 1536)];
    float2 s0 = cadd(x0, x2), s1 = csub(x0, x2), s2 = cadd(x1, x3), s3 = csub(x1, x3);
    float2 mi = (SGN < 0) ? make_float2(s3.y, -s3.x) : make_float2(-s3.y, s3.x);
    d[IDX2(t)]        = cadd(s0, s2);
    d[IDX2(t + 512)]  = cadd(s1, mi);
    d[IDX2(t + 1024)] = csub(s0, s2);
    d[IDX2(t + 1536)] = csub(s1, mi);
  }
  __syncthreads();   // result in b0
}

// setup: twiddles (2048), bf16 weight copies, Win transpose, state projection
__global__ __launch_bounds__(256) void k_setup(
    const float* __restrict__ W1, const float* __restrict__ W2, const float* __restrict__ Win,
    const float* __restrict__ init, const float* __restrict__ Wst,
    const float* __restrict__ bst, const float* __restrict__ bin,
    short* __restrict__ W1bf, short* __restrict__ W2bf, float* __restrict__ WinT,
    float* __restrict__ sp, float2* __restrict__ tw) {
  int idx = blockIdx.x * 256 + threadIdx.x;
  if (idx < 2048) {
    float s, c;
    sincosf(3.14159265358979323846f * (float)idx / 1024.0f, &s, &c);
    tw[idx] = make_float2(c, -s);
  }
  if (idx < NL * 512 * 256) {
    W1bf[idx] = f2bf(W1[idx]);
    W2bf[idx] = f2bf(W2[idx]);
  }
  if (idx < 256 * 64) {
    int hh = idx / 64, c = idx % 64;
    WinT[c * 256 + hh] = Win[idx];
  }
  if (idx < BB * H) {
    int b = idx >> 8, h = idx & 255;
    float acc = bin[h] + bst[h];
#pragma unroll
    for (int c = 0; c < COUT; ++c) acc += init[b * COUT + c] * Wst[h * COUT + c];
    sp[idx] = acc;
  }
}

// 4 rows per block: x[b,l,h] = sp[b,h] + sum_c stim[b,c,l]*Win[h,c]
__global__ __launch_bounds__(256) void k_input_proj(
    const float* __restrict__ stim, const float* __restrict__ WinT,
    const float* __restrict__ sp, float* __restrict__ x) {
  int row0 = blockIdx.x * 4;          // b*L + l0
  int b = row0 >> 10, l0 = row0 & 1023;
  int tid = threadIdx.x;
  __shared__ float sc[4][CIN];
  if (tid < 4 * CIN) {
    int r = tid >> 6, c = tid & 63;
    sc[r][c] = stim[(b * CIN + c) * LL + l0 + r];
  }
  __syncthreads();
  float base = sp[b * H + tid];
  float acc[4] = {base, base, base, base};
  for (int c = 0; c < CIN; ++c) {
    float wv = WinT[c * H + tid];
#pragma unroll
    for (int r = 0; r < 4; ++r) acc[r] += sc[r][c] * wv;
  }
#pragma unroll
  for (int r = 0; r < 4; ++r) x[(size_t)(row0 + r) * H + tid] = acc[r];
}

// LN over H for a 16-row l-tile; transposed write via LDS, 64B/thread.
__global__ __launch_bounds__(256) void k_ln1(
    const float* __restrict__ x, const float* __restrict__ lw, const float* __restrict__ lb,
    float* __restrict__ xnT) {
  int blk = blockIdx.x;               // b*64 + ltile
  int b_ = blk >> 6, l0 = (blk & 63) << 4;
  int tid = threadIdx.x, wv = tid >> 6, lane = tid & 63;
  __shared__ float T[16][256];
  float4 w4 = *(const float4*)&lw[lane * 4];
  float4 c4 = *(const float4*)&lb[lane * 4];
#pragma unroll
  for (int rr = 0; rr < 4; ++rr) {
    int lr = wv * 4 + rr;
    const float* row = x + (((size_t)(b_ << 10) + l0 + lr)) * H;
    float4 v = *(const float4*)&row[lane * 4];
    float s = v.x + v.y + v.z + v.w;
#pragma unroll
    for (int o = 32; o > 0; o >>= 1) s += __shfl_xor(s, o, 64);
    float m = s * (1.0f / H);
    float dx = v.x - m, dy = v.y - m, dz = v.z - m, dw = v.w - m;
    float q = dx * dx + dy * dy + dz * dz + dw * dw;
#pragma unroll
    for (int o = 32; o > 0; o >>= 1) q += __shfl_xor(q, o, 64);
    float rs = rsqrtf(q * (1.0f / H) + 1e-5f);
    float4 o4;
    o4.x = dx * rs * w4.x + c4.x; o4.y = dy * rs * w4.y + c4.y;
    o4.z = dz * rs * w4.z + c4.z; o4.w = dw * rs * w4.w + c4.w;
    *(float4*)&T[lr][lane * 4] = o4;
  }
  __syncthreads();
  float tmp[16];
#pragma unroll
  for (int l = 0; l < 16; ++l) tmp[l] = T[l][tid];
  float* dst = xnT + ((size_t)(b_ * H + tid)) * LL + l0;
#pragma unroll
  for (int l = 0; l < 16; l += 4) {
    float4 v = {tmp[l], tmp[l + 1], tmp[l + 2], tmp[l + 3]};
    *(float4*)&dst[l] = v;
  }
}

// All layers: blk = i*H + h. K[l] = sum_n cb_n * E_n^l with E^l = T1[l&15] *
// T2[l>>4 & 15] * M^(l>>8) from per-n LDS tables. Then forward FFT.
__global__ __launch_bounds__(256) void k_kernelfft(
    const float* __restrict__ A_re, const float* __restrict__ A_im,
    const float* __restrict__ C_re, const float* __restrict__ C_im,
    const float* __restrict__ log_step, const float2* __restrict__ tw,
    float2* __restrict__ kf) {
  int blk = blockIdx.x;                 // i*H + h
  int i = blk >> 8;
  int tid = threadIdx.x;
  __shared__ float2 cb[NST], Mv[NST];
  __shared__ float2 bufA[FBUF], bufB[FBUF];
  float2* T1 = bufB;                    // [n][16], overlays FFT scratch
  float2* T2 = bufB + 1024;             // [n][16]
  float step = expf(log_step[blk]);
  int n = tid & 63, g = tid >> 6;
  float Ar = A_re[i * NST + n], Ai = A_im[i * NST + n];
  float dr = step * Ar, di = step * Ai;
  float er = expf(dr);
  float sn, cs; sincosf(di, &sn, &cs);
  float Er = er * cs, Ei = er * sn;     // E = exp(dA)
  if (g == 0) {
    float nr = Er - 1.0f, ni = Ei;
    float dnm = Ar * Ar + Ai * Ai;
    float qr = (nr * Ar + ni * Ai) / dnm;    // (exp(dA)-1)/A
    float qi = (ni * Ar - nr * Ai) / dnm;
    float Cr = C_re[(size_t)blk * NST + n], Ci = C_im[(size_t)blk * NST + n];
    cb[n] = make_float2(Cr * qr - Ci * qi, Cr * qi + Ci * qr);
    float pr = 1.f, pi = 0.f;
    T1[n * 16] = make_float2(1.f, 0.f);
    for (int a = 1; a < 16; ++a) {
      float t2 = pr * Er - pi * Ei; pi = pr * Ei + pi * Er; pr = t2;
      T1[n * 16 + a] = make_float2(pr, pi);
    }
  } else if (g == 1) {
    float xr = Er, xi = Ei;
#pragma unroll
    for (int j = 0; j < 4; ++j) { float t2 = xr * xr - xi * xi; xi = 2.f * xr * xi; xr = t2; }
    // xr,xi = E^16
    float pr = 1.f, pi = 0.f;
    T2[n * 16] = make_float2(1.f, 0.f);
    for (int a = 1; a < 16; ++a) {
      float t2 = pr * xr - pi * xi; pi = pr * xi + pi * xr; pr = t2;
      T2[n * 16 + a] = make_float2(pr, pi);
    }
    float mr2 = pr * xr - pi * xi, mi2 = pr * xi + pi * xr;   // E^256
    Mv[n] = make_float2(mr2, mi2);
  }
  __syncthreads();
  float kr[4] = {0.f, 0.f, 0.f, 0.f}, ki[4] = {0.f, 0.f, 0.f, 0.f};
  const int a_lo = tid & 15, a_hi = tid >> 4;
  for (int nn = 0; nn < NST; ++nn) {
    float2 t1 = T1[nn * 16 + a_lo];
    float2 t2v = T2[nn * 16 + a_hi];
    float pr = t1.x * t2v.x - t1.y * t2v.y;   // E^tid
    float pi = t1.x * t2v.y + t1.y * t2v.x;
    float2 c = cb[nn], m = Mv[nn];
#pragma unroll
    for (int q = 0; q < 4; ++q) {
      kr[q] += c.x * pr - c.y * pi;
      ki[q] += c.x * pi + c.y * pr;
      float t2 = pr * m.x - pi * m.y;         // p *= E^256
      pi = pr * m.y + pi * m.x;
      pr = t2;
    }
  }
  __syncthreads();   // powering done before bufB (tables) is clobbered by FFT
#pragma unroll
  for (int q = 0; q < 4; ++q) {
    int l = tid + (q << 8);
    bufA[IDX2(l)] = make_float2(kr[q], ki[q]);
  }
  fft2048<-1, true>(bufA, bufB, tw, tid);   // result in bufA
  float2* kfh = kf + (size_t)blk * 1025;
#pragma unroll
  for (int q = 0; q < 4; ++q) {
    int k = tid + (q << 8);
    kfh[k] = bufA[IDX2(k)];
  }
  if (tid == 0) kfh[1024] = bufA[IDX2(1024)];
}

// Two rows packed per complex FFT; spectral multiply + Hermitian extension
// (irfft bin 0/1024 imag-drop); packed inverse.
__global__ __launch_bounds__(256) void k_conv(
    const float* __restrict__ xnT, const float2* __restrict__ kf,
    const float* __restrict__ D, const float2* __restrict__ tw, float* __restrict__ yT) {
  int blk = blockIdx.x;                 // b*128 + hp
  int b_ = blk >> 7, hp = blk & 127;
  int h0 = hp * 2, h1 = h0 + 1;
  int r0 = b_ * H + h0;
  int tid = threadIdx.x;
  __shared__ float2 bufA[FBUF], bufB[FBUF];
  float u0[4], u1[4];
  const float* x0 = xnT + (size_t)r0 * LL;
  const float* x1 = x0 + LL;
#pragma unroll
  for (int q = 0; q < 4; ++q) {
    int l = tid + (q << 8);
    float v0 = x0[l], v1 = x1[l];
    u0[q] = v0; u1[q] = v1;
    bufA[IDX2(l)] = make_float2(v0, v1);      // upper half implicit zero (PADDED)
  }
  fft2048<-1, true>(bufA, bufB, tw, tid);     // F = FFT(u0 + i*u1) in bufA
  const float2* kf0 = kf + (size_t)h0 * 1025;
  const float2* kf1 = kf + (size_t)h1 * 1025;
#pragma unroll
  for (int q = 0; q < 4; ++q) {
    int k = tid + (q << 8);
    if (k == 0) {
      float2 k0 = kf0[0], k1 = kf1[0];
      float2 F0 = bufA[IDX2(0)], Fn = bufA[IDX2(1024)];
      bufB[IDX2(0)]    = make_float2(F0.x * k0.x, F0.y * k1.x);
      float2 k0n = kf0[1024], k1n = kf1[1024];
      bufB[IDX2(1024)] = make_float2(Fn.x * k0n.x, Fn.y * k1n.x);
    } else {
      float2 F = bufA[IDX2(k)], G = bufA[IDX2(2048 - k)];
      float u0r = 0.5f * (F.x + G.x), u0i = 0.5f * (F.y - G.y);   // U0[k]
      float dr_ = 0.5f * (F.x - G.x), di_ = 0.5f * (F.y + G.y);
      float u1r = di_, u1i = -dr_;                                // U1[k]
      float2 k0 = kf0[k], k1 = kf1[k];
      float z0r = u0r * k0.x - u0i * k0.y, z0i = u0r * k0.y + u0i * k0.x;
      float z1r = u1r * k1.x - u1i * k1.y, z1i = u1r * k1.y + u1i * k1.x;
      bufB[IDX2(k)]        = make_float2(z0r - z1i, z0i + z1r);
      bufB[IDX2(2048 - k)] = make_float2(z0r + z1i, z1r - z0i);
    }
  }
  fft2048<1, false>(bufB, bufA, tw, tid);     // z0 + i*z1 in bufB (both real)
  float Dh0 = D[h0], Dh1 = D[h1];
  float* y0 = yT + (size_t)r0 * LL;
  float* y1 = y0 + LL;
#pragma unroll
  for (int q = 0; q < 4; ++q) {
    int l = tid + (q << 8);
    float2 z = bufB[IDX2(l)];
    y0[l] = z.x * (1.0f / NFFT) + Dh0 * u0[q];
    y1[l] = z.y * (1.0f / NFFT) + Dh1 * u1[q];
  }
}

// x += yT (gathered via LDS tile, 64B/thread reads); LN -> xn2 (bf16)
__global__ __launch_bounds__(256) void k_ln2(
    float* __restrict__ x, const float* __restrict__ yT,
    const float* __restrict__ lw, const float* __restrict__ lb, short* __restrict__ xn2) {
  int blk = blockIdx.x;
  int b_ = blk >> 6, l0 = (blk & 63) << 4;
  int tid = threadIdx.x, wv = tid >> 6, lane = tid & 63;
  __shared__ float T[16][256];
  {
    const float* src = yT + ((size_t)(b_ * H + tid)) * LL + l0;
    float tmp[16];
#pragma unroll
    for (int l = 0; l < 16; l += 4) {
      float4 v = *(const float4*)&src[l];
      tmp[l] = v.x; tmp[l + 1] = v.y; tmp[l + 2] = v.z; tmp[l + 3] = v.w;
    }
#pragma unroll
    for (int l = 0; l < 16; ++l) T[l][tid] = tmp[l];
  }
  __syncthreads();
  float4 w4 = *(const float4*)&lw[lane * 4];
  float4 c4 = *(const float4*)&lb[lane * 4];
#pragma unroll
  for (int rr = 0; rr < 4; ++rr) {
    int lr = wv * 4 + rr;
    float* rowx = x + (((size_t)(b_ << 10) + l0 + lr)) * H;
    float4 v = *(const float4*)&rowx[lane * 4];
    float4 yv = *(const float4*)&T[lr][lane * 4];
    v.x += yv.x; v.y += yv.y; v.z += yv.z; v.w += yv.w;
    *(float4*)&rowx[lane * 4] = v;
    float s = v.x + v.y + v.z + v.w;
#pragma unroll
    for (int o = 32; o > 0; o >>= 1) s += __shfl_xor(s, o, 64);
    float m = s * (1.0f / H);
    float dx = v.x - m, dy = v.y - m, dz = v.z - m, dw = v.w - m;
    float q = dx * dx + dy * dy + dz * dz + dw * dw;
#pragma unroll
    for (int o = 32; o > 0; o >>= 1) q += __shfl_xor(q, o, 64);
    float rs = rsqrtf(q * (1.0f / H) + 1e-5f);
    short4v s4;
    s4.x = f2bf(dx * rs * w4.x + c4.x);
    s4.y = f2bf(dy * rs * w4.y + c4.y);
    s4.z = f2bf(dz * rs * w4.z + c4.z);
    s4.w = f2bf(dw * rs * w4.w + c4.w);
    *(short4v*)&xn2[(((size_t)(b_ << 10) + l0 + lr)) * H + lane * 4] = s4;
  }
}

// MFMA bf16 GEMM: C[M,N] = A[M,K] @ Bw[N,K]^T (+bias). Tile 64x128, 4 waves
// (2x2), wave tile 32x64 = 2x4 fragments of 16x16, K-step 64.
template <int K, bool GELU_OUT>
__global__ __launch_bounds__(256) void k_gemm(
    const short* __restrict__ A, const short* __restrict__ Bw,
    const float* __restrict__ bias, short* __restrict__ Gout,
    float* __restrict__ Xres, int Nfull) {
  const int m0 = blockIdx.x * 64;
  const int c0 = blockIdx.y * 128;
  const int tid = threadIdx.x;
  const int lane = tid & 63;
  const int wr = (tid >> 6) >> 1, wc = (tid >> 6) & 1;
  __shared__ short Al[64][72];
  __shared__ short Bl[128][72];
  f32x4 acc[2][4];
#pragma unroll
  for (int m = 0; m < 2; ++m)
#pragma unroll
    for (int n = 0; n < 4; ++n) acc[m][n] = (f32x4){0.f, 0.f, 0.f, 0.f};

  for (int kk = 0; kk < K; kk += 64) {
    __syncthreads();
#pragma unroll
    for (int it = 0; it < 2; ++it) {
      int c = tid + (it << 8);
      int row = c >> 3, off = (c & 7) * 8;
      *(int4v*)&Al[row][off] = *(const int4v*)(A + (size_t)(m0 + row) * K + kk + off);
    }
#pragma unroll
    for (int it = 0; it < 4; ++it) {
      int c = tid + (it << 8);
      int row = c >> 3, off = (c & 7) * 8;
      *(int4v*)&Bl[row][off] = *(const int4v*)(Bw + (size_t)(c0 + row) * K + kk + off);
    }
    __syncthreads();
#pragma unroll
    for (int kc = 0; kc < 2; ++kc) {
      const int ko = kc * 32 + (lane >> 4) * 8;
      bf16x8 af[2], bf[4];
#pragma unroll
      for (int m = 0; m < 2; ++m)
        af[m] = *(const bf16x8*)&Al[wr * 32 + m * 16 + (lane & 15)][ko];
#pragma unroll
      for (int n = 0; n < 4; ++n)
        bf[n] = *(const bf16x8*)&Bl[wc * 64 + n * 16 + (lane & 15)][ko];
#pragma unroll
      for (int m = 0; m < 2; ++m)
#pragma unroll
        for (int n = 0; n < 4; ++n)
          acc[m][n] = __builtin_amdgcn_mfma_f32_16x16x32_bf16(af[m], bf[n], acc[m][n], 0, 0, 0);
    }
  }
#pragma unroll
  for (int m = 0; m < 2; ++m)
#pragma unroll
    for (int n = 0; n < 4; ++n) {
      int col = c0 + wc * 64 + n * 16 + (lane & 15);
      float bv = bias[col];
#pragma unroll
      for (int r = 0; r < 4; ++r) {
        int row = m0 + wr * 32 + m * 16 + (lane >> 4) * 4 + r;
        float v = acc[m][n][r] + bv;
        if (GELU_OUT) {
          v = 0.5f * v * (1.0f + erff(v * 0.70710678118654752f));
          Gout[(size_t)row * Nfull + col] = f2bf(v);
        } else {
          Xres[(size_t)row * Nfull + col] += v;
        }
      }
    }
}

// out[b,co,l] = sum_h x[b,l,h]*Wout[co,h] + b_out[co]; thread per (co,row)
__global__ __launch_bounds__(256) void k_out(
    const float* __restrict__ x, const float* __restrict__ Wout,
    const float* __restrict__ bout, float* __restrict__ out) {
  int idx = blockIdx.x * 256 + threadIdx.x;   // co*8192 + row
  int co = idx >> 13, row = idx & 8191;
  int b_ = row >> 10, l = row & 1023;
  const float* xr = x + (size_t)row * H;
  const float* wr = Wout + co * H;
  float p = bout[co];
#pragma unroll 4
  for (int h2 = 0; h2 < H; h2 += 4) {
    float4 xv = *(const float4*)&xr[h2];
    float4 wv = *(const float4*)&wr[h2];
    p += xv.x * wv.x + xv.y * wv.y + xv.z * wv.z + xv.w * wv.w;
  }
  out[(b_ * COUT + co) * LL + l] = p;
}

extern "C" void kernel_launch(void* const* d_in, const int* in_sizes, int n_in,
                              void* d_out, int out_size, void* d_ws, size_t ws_size,
                              hipStream_t stream) {
  const float* stim  = (const float*)d_in[0];
  const float* init  = (const float*)d_in[1];
  const float* A_re  = (const float*)d_in[2];
  const float* A_im  = (const float*)d_in[3];
  const float* C_re  = (const float*)d_in[4];
  const float* C_im  = (const float*)d_in[5];
  const float* Dp    = (const float*)d_in[6];
  const float* lstep = (const float*)d_in[7];
  const float* ln1w  = (const float*)d_in[8];
  const float* ln1b  = (const float*)d_in[9];
  const float* ln2w  = (const float*)d_in[10];
  const float* ln2b  = (const float*)d_in[11];
  const float* W1    = (const float*)d_in[12];
  const float* b1    = (const float*)d_in[13];
  const float* W2    = (const float*)d_in[14];
  const float* b2    = (const float*)d_in[15];
  const float* Win   = (const float*)d_in[16];
  const float* bin   = (const float*)d_in[17];
  const float* Wst   = (const float*)d_in[18];
  const float* bst   = (const float*)d_in[19];
  const float* Wout  = (const float*)d_in[20];
  const float* bout  = (const float*)d_in[21];
  float* out = (float*)d_out;
  float* ws = (float*)d_ws;

  size_t o = 0;
  auto alloc = [&](size_t nfloats) { size_t r = o; o += (nfloats + 63) & ~(size_t)63; return r; };
  float*  x    = ws + alloc((size_t)BB * LL * H);
  float*  xnT  = ws + alloc((size_t)BB * H * LL);
  float*  yT   = ws + alloc((size_t)BB * H * LL);
  short*  xn2  = (short*)(ws + alloc((size_t)BB * LL * H / 2));
  short*  g1   = (short*)(ws + alloc((size_t)BB * LL * 512 / 2));
  float2* kf   = (float2*)(ws + alloc((size_t)NL * H * 1025 * 2));
  short*  W1bf = (short*)(ws + alloc((size_t)NL * 512 * 256 / 2));
  short*  W2bf = (short*)(ws + alloc((size_t)NL * 256 * 512 / 2));
  float*  WinT = ws + alloc((size_t)64 * 256);
  float*  sp   = ws + alloc((size_t)BB * H);
  float2* tw   = (float2*)(ws + alloc((size_t)2048 * 2));
  (void)ws_size; (void)in_sizes; (void)n_in; (void)out_size;

  k_setup<<<2048, 256, 0, stream>>>(W1, W2, Win, init, Wst, bst, bin,
                                    W1bf, W2bf, WinT, sp, tw);
  k_kernelfft<<<NL * H, 256, 0, stream>>>(A_re, A_im, C_re, C_im, lstep, tw, kf);
  k_input_proj<<<BB * LL / 4, 256, 0, stream>>>(stim, WinT, sp, x);

  for (int i = 0; i < NL; ++i) {
    k_ln1<<<BB * 64, 256, 0, stream>>>(x, ln1w + i * H, ln1b + i * H, xnT);
    k_conv<<<BB * H / 2, 256, 0, stream>>>(xnT, kf + (size_t)i * H * 1025,
                                           Dp + i * H, tw, yT);
    k_ln2<<<BB * 64, 256, 0, stream>>>(x, yT, ln2w + i * H, ln2b + i * H, xn2);
    dim3 g1grid(128, 4);
    k_gemm<256, true><<<g1grid, 256, 0, stream>>>(
        xn2, W1bf + (size_t)i * 512 * 256, b1 + i * 512, g1, nullptr, 512);
    dim3 g2grid(128, 2);
    k_gemm<512, false><<<g2grid, 256, 0, stream>>>(
        g1, W2bf + (size_t)i * 256 * 512, b2 + i * H, nullptr, x, 256);
  }
  k_out<<<BB * LL * COUT / 256, 256, 0, stream>>>(x, Wout, bout, out);
}

// Round 6
// 254.536 us; speedup vs baseline: 3.7222x; 1.1770x over previous
//
#include <hip/hip_runtime.h>
#include <math.h>

#define NL   4
#define H    256
#define NST  64
#define CIN  64
#define COUT 8
#define BB   8
#define LL   1024
#define NFFT 2048

typedef __attribute__((ext_vector_type(8))) short bf16x8;
typedef __attribute__((ext_vector_type(4))) short short4v;
typedef __attribute__((ext_vector_type(4))) int   int4v;
typedef __attribute__((ext_vector_type(4))) float f32x4;

__device__ __forceinline__ short f2bf(float f) {
  union { float f; unsigned u; } v; v.f = f;
  unsigned r = (v.u + 0x7fffu + ((v.u >> 16) & 1u)) >> 16;
  return (short)r;
}
// pad every 16 float2 (128B) -> strided stage writes stay ~2-way (free)
__device__ __forceinline__ int IDX2(int a) { return a + (a >> 4); }
#define FBUF 2176   // 2048 + 128 pad

__device__ __forceinline__ float2 cadd(float2 a, float2 b) { return make_float2(a.x + b.x, a.y + b.y); }
__device__ __forceinline__ float2 csub(float2 a, float2 b) { return make_float2(a.x - b.x, a.y - b.y); }

// ---------------------------------------------------------------------------
// 2048-pt FFT, float2 LDS: 3 radix-8 Stockham stages (m=1,8,64) + final
// twiddle-free radix-4 (m=512). dst[R*jm + k + d*m] = DFT_R(a)_d * W_N^{d*jm}.
// Input in b0 at IDX2(); result lands in b0. PADDED: upper half (>=1024) zero.
// tw[t] = W_2048^t = e^{-i pi t/1024}, t in [0,2048).
// ---------------------------------------------------------------------------
template <int SGN, bool PADDED>
__device__ __forceinline__ void fft2048(float2* b0, float2* b1,
                                        const float2* __restrict__ tw, int tid) {
  const float RH = 0.70710678118654752f;
  float2 *s = b0, *d = b1;
#pragma unroll
  for (int st = 0; st < 3; ++st) {
    const int m = 1 << (3 * st);            // 1, 8, 64
    __syncthreads();
    const int k  = tid & (m - 1);
    const int jm = tid - k;                 // multiple of m, < 256
    float2 a0 = s[IDX2(tid)];
    float2 a1 = s[IDX2(tid + 256)];
    float2 a2 = s[IDX2(tid + 512)];
    float2 a3 = s[IDX2(tid + 768)];
    float2 a4, a5, a6, a7;
    if (PADDED && st == 0) {
      a4 = make_float2(0.f, 0.f); a5 = a4; a6 = a4; a7 = a4;
    } else {
      a4 = s[IDX2(tid + 1024)];
      a5 = s[IDX2(tid + 1280)];
      a6 = s[IDX2(tid + 1536)];
      a7 = s[IDX2(tid + 1792)];
    }
    float2 s0 = cadd(a0, a4), s1 = csub(a0, a4), s2 = cadd(a2, a6), s3 = csub(a2, a6);
    float2 mi = (SGN < 0) ? make_float2(s3.y, -s3.x) : make_float2(-s3.y, s3.x);
    float2 E0 = cadd(s0, s2), E1 = cadd(s1, mi), E2 = csub(s0, s2), E3 = csub(s1, mi);
    float2 t0 = cadd(a1, a5), t1 = csub(a1, a5), t2 = cadd(a3, a7), t3 = csub(a3, a7);
    float2 mj = (SGN < 0) ? make_float2(t3.y, -t3.x) : make_float2(-t3.y, t3.x);
    float2 O0 = cadd(t0, t2), O1 = cadd(t1, mj), O2 = csub(t0, t2), O3 = csub(t1, mj);
    float2 W0 = O0;
    float2 W1 = (SGN < 0) ? make_float2((O1.x + O1.y) * RH, (O1.y - O1.x) * RH)
                          : make_float2((O1.x - O1.y) * RH, (O1.x + O1.y) * RH);
    float2 W2 = (SGN < 0) ? make_float2(O2.y, -O2.x) : make_float2(-O2.y, O2.x);
    float2 W3 = (SGN < 0) ? make_float2((O3.y - O3.x) * RH, -(O3.x + O3.y) * RH)
                          : make_float2(-(O3.x + O3.y) * RH, (O3.x - O3.y) * RH);
    float2 A[8];
    A[0] = cadd(E0, W0); A[4] = csub(E0, W0);
    A[1] = cadd(E1, W1); A[5] = csub(E1, W1);
    A[2] = cadd(E2, W2); A[6] = csub(E2, W2);
    A[3] = cadd(E3, W3); A[7] = csub(E3, W3);
    const int base = 8 * jm + k;
    d[IDX2(base)] = A[0];
#pragma unroll
    for (int dd = 1; dd < 8; ++dd) {
      float2 w = tw[dd * jm];
      float wi = (SGN < 0) ? w.y : -w.y;
      float2 v = A[dd];
      d[IDX2(base + dd * m)] = make_float2(v.x * w.x - v.y * wi, v.x * wi + v.y * w.x);
    }
    float2* tp = s; s = d; d = tp;
  }
  __syncthreads();
#pragma unroll
  for (int q = 0; q < 2; ++q) {
    const int t = tid + (q << 8);           // [0,512)
    float2 x0 = s[IDX2(t)], x1 = s[IDX2(t + 512)];
    float2 x2 = s[IDX2(t + 1024)], x3 = s[IDX2(t + 1536)];
    float2 s0 = cadd(x0, x2), s1 = csub(x0, x2), s2 = cadd(x1, x3), s3 = csub(x1, x3);
    float2 mi = (SGN < 0) ? make_float2(s3.y, -s3.x) : make_float2(-s3.y, s3.x);
    d[IDX2(t)]        = cadd(s0, s2);
    d[IDX2(t + 512)]  = cadd(s1, mi);
    d[IDX2(t + 1024)] = csub(s0, s2);
    d[IDX2(t + 1536)] = csub(s1, mi);
  }
  __syncthreads();   // result in b0
}

// setup: twiddles (2048), bf16 weight copies, Win transpose, state projection
__global__ __launch_bounds__(256) void k_setup(
    const float* __restrict__ W1, const float* __restrict__ W2, const float* __restrict__ Win,
    const float* __restrict__ init, const float* __restrict__ Wst,
    const float* __restrict__ bst, const float* __restrict__ bin,
    short* __restrict__ W1bf, short* __restrict__ W2bf, float* __restrict__ WinT,
    float* __restrict__ sp, float2* __restrict__ tw) {
  int idx = blockIdx.x * 256 + threadIdx.x;
  if (idx < 2048) {
    float s, c;
    sincosf(3.14159265358979323846f * (float)idx / 1024.0f, &s, &c);
    tw[idx] = make_float2(c, -s);
  }
  if (idx < NL * 512 * 256) {
    W1bf[idx] = f2bf(W1[idx]);
    W2bf[idx] = f2bf(W2[idx]);
  }
  if (idx < 256 * 64) {
    int hh = idx / 64, c = idx % 64;
    WinT[c * 256 + hh] = Win[idx];
  }
  if (idx < BB * H) {
    int b = idx >> 8, h = idx & 255;
    float acc = bin[h] + bst[h];
#pragma unroll
    for (int c = 0; c < COUT; ++c) acc += init[b * COUT + c] * Wst[h * COUT + c];
    sp[idx] = acc;
  }
}

// Fused input-proj + LN1(layer0): 16 l-rows per block; writes x (pre-LN) and
// xnT (transposed normalized).
__global__ __launch_bounds__(256) void k_in_ln1(
    const float* __restrict__ stim, const float* __restrict__ WinT,
    const float* __restrict__ sp, const float* __restrict__ lw, const float* __restrict__ lb,
    float* __restrict__ x, float* __restrict__ xnT) {
  int blk = blockIdx.x;               // b*64 + ltile
  int b_ = blk >> 6, l0 = (blk & 63) << 4;
  int tid = threadIdx.x, wv = tid >> 6, lane = tid & 63;
  __shared__ float sc[16][CIN];
  __shared__ float T[16][256];
#pragma unroll
  for (int it = 0; it < 4; ++it) {
    int idx = tid + (it << 8);
    int r = idx & 15, c = idx >> 4;
    sc[r][c] = stim[(b_ * CIN + c) * LL + l0 + r];
  }
  __syncthreads();
  float4 sp4 = *(const float4*)&sp[b_ * H + lane * 4];
  float4 acc[4] = {sp4, sp4, sp4, sp4};
  for (int c = 0; c < CIN; ++c) {
    float4 wv4 = *(const float4*)&WinT[c * H + lane * 4];
#pragma unroll
    for (int rr = 0; rr < 4; ++rr) {
      float s = sc[wv * 4 + rr][c];
      acc[rr].x += s * wv4.x; acc[rr].y += s * wv4.y;
      acc[rr].z += s * wv4.z; acc[rr].w += s * wv4.w;
    }
  }
  float4 w4 = *(const float4*)&lw[lane * 4];
  float4 c4 = *(const float4*)&lb[lane * 4];
#pragma unroll
  for (int rr = 0; rr < 4; ++rr) {
    int lr = wv * 4 + rr;
    float4 v = acc[rr];
    *(float4*)&x[(((size_t)(b_ << 10) + l0 + lr)) * H + lane * 4] = v;
    float s = v.x + v.y + v.z + v.w;
#pragma unroll
    for (int o = 32; o > 0; o >>= 1) s += __shfl_xor(s, o, 64);
    float m = s * (1.0f / H);
    float dx = v.x - m, dy = v.y - m, dz = v.z - m, dw = v.w - m;
    float q = dx * dx + dy * dy + dz * dz + dw * dw;
#pragma unroll
    for (int o = 32; o > 0; o >>= 1) q += __shfl_xor(q, o, 64);
    float rs = rsqrtf(q * (1.0f / H) + 1e-5f);
    float4 o4;
    o4.x = dx * rs * w4.x + c4.x; o4.y = dy * rs * w4.y + c4.y;
    o4.z = dz * rs * w4.z + c4.z; o4.w = dw * rs * w4.w + c4.w;
    *(float4*)&T[lr][lane * 4] = o4;
  }
  __syncthreads();
  float tmp[16];
#pragma unroll
  for (int l = 0; l < 16; ++l) tmp[l] = T[l][tid];
  float* dst = xnT + ((size_t)(b_ * H + tid)) * LL + l0;
#pragma unroll
  for (int l = 0; l < 16; l += 4) {
    float4 v = {tmp[l], tmp[l + 1], tmp[l + 2], tmp[l + 3]};
    *(float4*)&dst[l] = v;
  }
}

// All layers: blk = i*H + h. K[l] = sum_n cb_n * E_n^l with E^l = T1[l&15] *
// T2[l>>4 & 15] * M^(l>>8) from per-n LDS tables. Then forward FFT.
__global__ __launch_bounds__(256) void k_kernelfft(
    const float* __restrict__ A_re, const float* __restrict__ A_im,
    const float* __restrict__ C_re, const float* __restrict__ C_im,
    const float* __restrict__ log_step, const float2* __restrict__ tw,
    float2* __restrict__ kf) {
  int blk = blockIdx.x;                 // i*H + h
  int i = blk >> 8;
  int tid = threadIdx.x;
  __shared__ float2 cb[NST], Mv[NST];
  __shared__ float2 bufA[FBUF], bufB[FBUF];
  float2* T1 = bufB;                    // [n][16], overlays FFT scratch
  float2* T2 = bufB + 1024;             // [n][16]
  float step = expf(log_step[blk]);
  int n = tid & 63, g = tid >> 6;
  float Ar = A_re[i * NST + n], Ai = A_im[i * NST + n];
  float dr = step * Ar, di = step * Ai;
  float er = expf(dr);
  float sn, cs; sincosf(di, &sn, &cs);
  float Er = er * cs, Ei = er * sn;     // E = exp(dA)
  if (g == 0) {
    float nr = Er - 1.0f, ni = Ei;
    float dnm = Ar * Ar + Ai * Ai;
    float qr = (nr * Ar + ni * Ai) / dnm;    // (exp(dA)-1)/A
    float qi = (ni * Ar - nr * Ai) / dnm;
    float Cr = C_re[(size_t)blk * NST + n], Ci = C_im[(size_t)blk * NST + n];
    cb[n] = make_float2(Cr * qr - Ci * qi, Cr * qi + Ci * qr);
    float pr = 1.f, pi = 0.f;
    T1[n * 16] = make_float2(1.f, 0.f);
    for (int a = 1; a < 16; ++a) {
      float t2 = pr * Er - pi * Ei; pi = pr * Ei + pi * Er; pr = t2;
      T1[n * 16 + a] = make_float2(pr, pi);
    }
  } else if (g == 1) {
    float xr = Er, xi = Ei;
#pragma unroll
    for (int j = 0; j < 4; ++j) { float t2 = xr * xr - xi * xi; xi = 2.f * xr * xi; xr = t2; }
    float pr = 1.f, pi = 0.f;
    T2[n * 16] = make_float2(1.f, 0.f);
    for (int a = 1; a < 16; ++a) {
      float t2 = pr * xr - pi * xi; pi = pr * xi + pi * xr; pr = t2;
      T2[n * 16 + a] = make_float2(pr, pi);
    }
    float mr2 = pr * xr - pi * xi, mi2 = pr * xi + pi * xr;   // E^256
    Mv[n] = make_float2(mr2, mi2);
  }
  __syncthreads();
  float kr[4] = {0.f, 0.f, 0.f, 0.f}, ki[4] = {0.f, 0.f, 0.f, 0.f};
  const int a_lo = tid & 15, a_hi = tid >> 4;
  for (int nn = 0; nn < NST; ++nn) {
    float2 t1 = T1[nn * 16 + a_lo];
    float2 t2v = T2[nn * 16 + a_hi];
    float pr = t1.x * t2v.x - t1.y * t2v.y;   // E^tid
    float pi = t1.x * t2v.y + t1.y * t2v.x;
    float2 c = cb[nn], m = Mv[nn];
#pragma unroll
    for (int q = 0; q < 4; ++q) {
      kr[q] += c.x * pr - c.y * pi;
      ki[q] += c.x * pi + c.y * pr;
      float t2 = pr * m.x - pi * m.y;         // p *= E^256
      pi = pr * m.y + pi * m.x;
      pr = t2;
    }
  }
  __syncthreads();   // powering done before bufB (tables) is clobbered by FFT
#pragma unroll
  for (int q = 0; q < 4; ++q) {
    int l = tid + (q << 8);
    bufA[IDX2(l)] = make_float2(kr[q], ki[q]);
  }
  fft2048<-1, true>(bufA, bufB, tw, tid);   // result in bufA
  float2* kfh = kf + (size_t)blk * 1025;
#pragma unroll
  for (int q = 0; q < 4; ++q) {
    int k = tid + (q << 8);
    kfh[k] = bufA[IDX2(k)];
  }
  if (tid == 0) kfh[1024] = bufA[IDX2(1024)];
}

// Two rows packed per complex FFT; spectral multiply + Hermitian extension
// (irfft bin 0/1024 imag-drop); packed inverse.
__global__ __launch_bounds__(256) void k_conv(
    const float* __restrict__ xnT, const float2* __restrict__ kf,
    const float* __restrict__ D, const float2* __restrict__ tw, float* __restrict__ yT) {
  int blk = blockIdx.x;                 // b*128 + hp
  int b_ = blk >> 7, hp = blk & 127;
  int h0 = hp * 2, h1 = h0 + 1;
  int r0 = b_ * H + h0;
  int tid = threadIdx.x;
  __shared__ float2 bufA[FBUF], bufB[FBUF];
  float u0[4], u1[4];
  const float* x0 = xnT + (size_t)r0 * LL;
  const float* x1 = x0 + LL;
#pragma unroll
  for (int q = 0; q < 4; ++q) {
    int l = tid + (q << 8);
    float v0 = x0[l], v1 = x1[l];
    u0[q] = v0; u1[q] = v1;
    bufA[IDX2(l)] = make_float2(v0, v1);      // upper half implicit zero (PADDED)
  }
  fft2048<-1, true>(bufA, bufB, tw, tid);     // F = FFT(u0 + i*u1) in bufA
  const float2* kf0 = kf + (size_t)h0 * 1025;
  const float2* kf1 = kf + (size_t)h1 * 1025;
#pragma unroll
  for (int q = 0; q < 4; ++q) {
    int k = tid + (q << 8);
    if (k == 0) {
      float2 k0 = kf0[0], k1 = kf1[0];
      float2 F0 = bufA[IDX2(0)], Fn = bufA[IDX2(1024)];
      bufB[IDX2(0)]    = make_float2(F0.x * k0.x, F0.y * k1.x);
      float2 k0n = kf0[1024], k1n = kf1[1024];
      bufB[IDX2(1024)] = make_float2(Fn.x * k0n.x, Fn.y * k1n.x);
    } else {
      float2 F = bufA[IDX2(k)], G = bufA[IDX2(2048 - k)];
      float u0r = 0.5f * (F.x + G.x), u0i = 0.5f * (F.y - G.y);   // U0[k]
      float dr_ = 0.5f * (F.x - G.x), di_ = 0.5f * (F.y + G.y);
      float u1r = di_, u1i = -dr_;                                // U1[k]
      float2 k0 = kf0[k], k1 = kf1[k];
      float z0r = u0r * k0.x - u0i * k0.y, z0i = u0r * k0.y + u0i * k0.x;
      float z1r = u1r * k1.x - u1i * k1.y, z1i = u1r * k1.y + u1i * k1.x;
      bufB[IDX2(k)]        = make_float2(z0r - z1i, z0i + z1r);
      bufB[IDX2(2048 - k)] = make_float2(z0r + z1i, z1r - z0i);
    }
  }
  fft2048<1, false>(bufB, bufA, tw, tid);     // z0 + i*z1 in bufB (both real)
  float Dh0 = D[h0], Dh1 = D[h1];
  float* y0 = yT + (size_t)r0 * LL;
  float* y1 = y0 + LL;
#pragma unroll
  for (int q = 0; q < 4; ++q) {
    int l = tid + (q << 8);
    float2 z = bufB[IDX2(l)];
    y0[l] = z.x * (1.0f / NFFT) + Dh0 * u0[q];
    y1[l] = z.y * (1.0f / NFFT) + Dh1 * u1[q];
  }
}

// x += yT (gathered via LDS tile); LN -> xn2 (bf16)
__global__ __launch_bounds__(256) void k_ln2(
    float* __restrict__ x, const float* __restrict__ yT,
    const float* __restrict__ lw, const float* __restrict__ lb, short* __restrict__ xn2) {
  int blk = blockIdx.x;
  int b_ = blk >> 6, l0 = (blk & 63) << 4;
  int tid = threadIdx.x, wv = tid >> 6, lane = tid & 63;
  __shared__ float T[16][256];
  {
    const float* src = yT + ((size_t)(b_ * H + tid)) * LL + l0;
    float tmp[16];
#pragma unroll
    for (int l = 0; l < 16; l += 4) {
      float4 v = *(const float4*)&src[l];
      tmp[l] = v.x; tmp[l + 1] = v.y; tmp[l + 2] = v.z; tmp[l + 3] = v.w;
    }
#pragma unroll
    for (int l = 0; l < 16; ++l) T[l][tid] = tmp[l];
  }
  __syncthreads();
  float4 w4 = *(const float4*)&lw[lane * 4];
  float4 c4 = *(const float4*)&lb[lane * 4];
#pragma unroll
  for (int rr = 0; rr < 4; ++rr) {
    int lr = wv * 4 + rr;
    float* rowx = x + (((size_t)(b_ << 10) + l0 + lr)) * H;
    float4 v = *(const float4*)&rowx[lane * 4];
    float4 yv = *(const float4*)&T[lr][lane * 4];
    v.x += yv.x; v.y += yv.y; v.z += yv.z; v.w += yv.w;
    *(float4*)&rowx[lane * 4] = v;
    float s = v.x + v.y + v.z + v.w;
#pragma unroll
    for (int o = 32; o > 0; o >>= 1) s += __shfl_xor(s, o, 64);
    float m = s * (1.0f / H);
    float dx = v.x - m, dy = v.y - m, dz = v.z - m, dw = v.w - m;
    float q = dx * dx + dy * dy + dz * dz + dw * dw;
#pragma unroll
    for (int o = 32; o > 0; o >>= 1) q += __shfl_xor(q, o, 64);
    float rs = rsqrtf(q * (1.0f / H) + 1e-5f);
    short4v s4;
    s4.x = f2bf(dx * rs * w4.x + c4.x);
    s4.y = f2bf(dy * rs * w4.y + c4.y);
    s4.z = f2bf(dz * rs * w4.z + c4.z);
    s4.w = f2bf(dw * rs * w4.w + c4.w);
    *(short4v*)&xn2[(((size_t)(b_ << 10) + l0 + lr)) * H + lane * 4] = s4;
  }
}

// MFMA bf16 GEMM (gemm1): C[M,512] = A[M,256] @ W1^T, GELU, bf16 out.
// Tile 64x128, 4 waves (2x2), wave tile 32x64 = 2x4 frags, K-step 64.
__global__ __launch_bounds__(256) void k_gemm1(
    const short* __restrict__ A, const short* __restrict__ Bw,
    const float* __restrict__ bias, short* __restrict__ Gout) {
  const int K = 256, Nfull = 512;
  const int m0 = blockIdx.x * 64;
  const int c0 = blockIdx.y * 128;
  const int tid = threadIdx.x;
  const int lane = tid & 63;
  const int wr = (tid >> 6) >> 1, wc = (tid >> 6) & 1;
  __shared__ short Al[64][72];
  __shared__ short Bl[128][72];
  f32x4 acc[2][4];
#pragma unroll
  for (int m = 0; m < 2; ++m)
#pragma unroll
    for (int n = 0; n < 4; ++n) acc[m][n] = (f32x4){0.f, 0.f, 0.f, 0.f};

  for (int kk = 0; kk < K; kk += 64) {
    __syncthreads();
#pragma unroll
    for (int it = 0; it < 2; ++it) {
      int c = tid + (it << 8);
      int row = c >> 3, off = (c & 7) * 8;
      *(int4v*)&Al[row][off] = *(const int4v*)(A + (size_t)(m0 + row) * K + kk + off);
    }
#pragma unroll
    for (int it = 0; it < 4; ++it) {
      int c = tid + (it << 8);
      int row = c >> 3, off = (c & 7) * 8;
      *(int4v*)&Bl[row][off] = *(const int4v*)(Bw + (size_t)(c0 + row) * K + kk + off);
    }
    __syncthreads();
#pragma unroll
    for (int kc = 0; kc < 2; ++kc) {
      const int ko = kc * 32 + (lane >> 4) * 8;
      bf16x8 af[2], bf[4];
#pragma unroll
      for (int m = 0; m < 2; ++m)
        af[m] = *(const bf16x8*)&Al[wr * 32 + m * 16 + (lane & 15)][ko];
#pragma unroll
      for (int n = 0; n < 4; ++n)
        bf[n] = *(const bf16x8*)&Bl[wc * 64 + n * 16 + (lane & 15)][ko];
#pragma unroll
      for (int m = 0; m < 2; ++m)
#pragma unroll
        for (int n = 0; n < 4; ++n)
          acc[m][n] = __builtin_amdgcn_mfma_f32_16x16x32_bf16(af[m], bf[n], acc[m][n], 0, 0, 0);
    }
  }
#pragma unroll
  for (int m = 0; m < 2; ++m)
#pragma unroll
    for (int n = 0; n < 4; ++n) {
      int col = c0 + wc * 64 + n * 16 + (lane & 15);
      float bv = bias[col];
#pragma unroll
      for (int r = 0; r < 4; ++r) {
        int row = m0 + wr * 32 + m * 16 + (lane >> 4) * 4 + r;
        float v = acc[m][n][r] + bv;
        v = 0.5f * v * (1.0f + erff(v * 0.70710678118654752f));
        Gout[(size_t)row * Nfull + col] = f2bf(v);
      }
    }
}

// Fused gemm2 (+bias+residual) + {next-layer LN1 + xnT write | output proj}.
// Tile 32x256 (full N), grid 256 blocks, 4 waves 1x4 (wave = 32x64: 2m x 4n).
// A = g1 [8192][512] bf16, Bw = W2 [256][512] bf16.
#define TXS 260   // Txn row stride (floats); 260*4 % 16 == 0
template <bool LAST>
__global__ __launch_bounds__(256) void k_gemm2f(
    const short* __restrict__ A, const short* __restrict__ Bw,
    const float* __restrict__ bias, float* __restrict__ x,
    const float* __restrict__ lnw, const float* __restrict__ lnb, float* __restrict__ xnT,
    const float* __restrict__ Wout, const float* __restrict__ bout, float* __restrict__ out) {
  const int K = 512;
  const int m0 = blockIdx.x * 32;
  const int b_ = m0 >> 10, l0 = m0 & 1023;
  const int tid = threadIdx.x;
  const int lane = tid & 63;
  const int wid = tid >> 6;            // 0..3 -> col group
  __shared__ __attribute__((aligned(16))) char smem[43520];
  short* Al  = (short*)smem;                         // [32][72]   4608 B
  short* Bl  = (short*)(smem + 4608);                // [256][72]  36864 B
  float* Txn = (float*)smem;                         // [32][TXS]  33280 B (overlays Al/Bl after loop)
  float* red = (float*)(smem + 33280);               // [4][32][2] 1024 B
  float* wlds = (float*)(smem + 34304);              // [8][258]   8256 B (LAST only)

  f32x4 acc[2][4];
#pragma unroll
  for (int m = 0; m < 2; ++m)
#pragma unroll
    for (int n = 0; n < 4; ++n) acc[m][n] = (f32x4){0.f, 0.f, 0.f, 0.f};

  for (int kk = 0; kk < K; kk += 64) {
    __syncthreads();
    {
      int row = tid >> 3, off = (tid & 7) * 8;
      *(int4v*)&Al[row * 72 + off] = *(const int4v*)(A + (size_t)(m0 + row) * K + kk + off);
    }
#pragma unroll
    for (int it = 0; it < 8; ++it) {
      int c = tid + (it << 8);
      int row = c >> 3, off = (c & 7) * 8;
      *(int4v*)&Bl[row * 72 + off] = *(const int4v*)(Bw + (size_t)row * K + kk + off);
    }
    __syncthreads();
#pragma unroll
    for (int kc = 0; kc < 2; ++kc) {
      const int ko = kc * 32 + (lane >> 4) * 8;
      bf16x8 af[2], bf[4];
#pragma unroll
      for (int m = 0; m < 2; ++m)
        af[m] = *(const bf16x8*)&Al[(m * 16 + (lane & 15)) * 72 + ko];
#pragma unroll
      for (int n = 0; n < 4; ++n)
        bf[n] = *(const bf16x8*)&Bl[(wid * 64 + n * 16 + (lane & 15)) * 72 + ko];
#pragma unroll
      for (int m = 0; m < 2; ++m)
#pragma unroll
        for (int n = 0; n < 4; ++n)
          acc[m][n] = __builtin_amdgcn_mfma_f32_16x16x32_bf16(af[m], bf[n], acc[m][n], 0, 0, 0);
    }
  }
  __syncthreads();   // Al/Bl dead; Txn region free

  // v = acc + bias + x_residual   (per-lane cols: wid*64 + n*16 + (lane&15))
  float bv[4], wl[4], bl[4];
#pragma unroll
  for (int n = 0; n < 4; ++n) {
    int col = wid * 64 + n * 16 + (lane & 15);
    bv[n] = bias[col];
    if (!LAST) { wl[n] = lnw[col]; bl[n] = lnb[col]; }
  }
  float sum[2][4], sq[2][4];   // per (m, rf)
#pragma unroll
  for (int m = 0; m < 2; ++m)
#pragma unroll
    for (int r = 0; r < 4; ++r) { sum[m][r] = 0.f; sq[m][r] = 0.f; }
#pragma unroll
  for (int m = 0; m < 2; ++m)
#pragma unroll
    for (int n = 0; n < 4; ++n) {
      int col = wid * 64 + n * 16 + (lane & 15);
#pragma unroll
      for (int r = 0; r < 4; ++r) {
        int row = m * 16 + (lane >> 4) * 4 + r;
        float v = acc[m][n][r] + bv[n] + x[(size_t)(m0 + row) * H + col];
        acc[m][n][r] = v;
        if (LAST) Txn[row * TXS + col] = v;
        sum[m][r] += v; sq[m][r] += v * v;
      }
    }

  if (LAST) {
    // stage Wout [8][256] -> wlds [8][258]
#pragma unroll
    for (int it = 0; it < 8; ++it) {
      int idx = tid + (it << 8);
      wlds[(idx >> 8) * 258 + (idx & 255)] = Wout[idx];
    }
    __syncthreads();
    int row = tid >> 3, co = tid & 7;
    float p = bout[co];
    const float* tr = Txn + row * TXS;
    const float* wr = wlds + co * 258;
#pragma unroll 4
    for (int c = 0; c < H; ++c) p += tr[c] * wr[c];
    out[((b_ * COUT + co) << 10) + l0 + row] = p;
  } else {
    // cross-lane (16-group) + cross-wave LN stats
#pragma unroll
    for (int m = 0; m < 2; ++m)
#pragma unroll
      for (int r = 0; r < 4; ++r) {
#pragma unroll
        for (int o = 1; o < 16; o <<= 1) {
          sum[m][r] += __shfl_xor(sum[m][r], o, 64);
          sq[m][r]  += __shfl_xor(sq[m][r], o, 64);
        }
      }
    if ((lane & 15) == 0) {
#pragma unroll
      for (int m = 0; m < 2; ++m)
#pragma unroll
        for (int r = 0; r < 4; ++r) {
          int row = m * 16 + (lane >> 4) * 4 + r;
          red[(wid * 32 + row) * 2]     = sum[m][r];
          red[(wid * 32 + row) * 2 + 1] = sq[m][r];
        }
    }
    __syncthreads();
    // write x (residual out) + compute normalized into Txn
#pragma unroll
    for (int m = 0; m < 2; ++m) {
#pragma unroll
      for (int r = 0; r < 4; ++r) {
        int row = m * 16 + (lane >> 4) * 4 + r;
        float S = 0.f, Q = 0.f;
#pragma unroll
        for (int w = 0; w < 4; ++w) { S += red[(w * 32 + row) * 2]; Q += red[(w * 32 + row) * 2 + 1]; }
        float mean = S * (1.0f / H);
        float var = Q * (1.0f / H) - mean * mean;
        float rs = rsqrtf(var + 1e-5f);
#pragma unroll
        for (int n = 0; n < 4; ++n) {
          int col = wid * 64 + n * 16 + (lane & 15);
          float v = acc[m][n][r];
          x[(size_t)(m0 + row) * H + col] = v;
          Txn[row * TXS + col] = (v - mean) * rs * wl[n] + bl[n];
        }
      }
    }
    __syncthreads();
    // transposed copy: thread = h, 32 l-contiguous floats -> xnT
    float tmp[32];
#pragma unroll
    for (int l = 0; l < 32; ++l) tmp[l] = Txn[l * TXS + tid];
    float* dst = xnT + ((size_t)(b_ * H + tid)) * LL + l0;
#pragma unroll
    for (int l = 0; l < 32; l += 4) {
      float4 v = {tmp[l], tmp[l + 1], tmp[l + 2], tmp[l + 3]};
      *(float4*)&dst[l] = v;
    }
  }
}

extern "C" void kernel_launch(void* const* d_in, const int* in_sizes, int n_in,
                              void* d_out, int out_size, void* d_ws, size_t ws_size,
                              hipStream_t stream) {
  const float* stim  = (const float*)d_in[0];
  const float* init  = (const float*)d_in[1];
  const float* A_re  = (const float*)d_in[2];
  const float* A_im  = (const float*)d_in[3];
  const float* C_re  = (const float*)d_in[4];
  const float* C_im  = (const float*)d_in[5];
  const float* Dp    = (const float*)d_in[6];
  const float* lstep = (const float*)d_in[7];
  const float* ln1w  = (const float*)d_in[8];
  const float* ln1b  = (const float*)d_in[9];
  const float* ln2w  = (const float*)d_in[10];
  const float* ln2b  = (const float*)d_in[11];
  const float* W1    = (const float*)d_in[12];
  const float* b1    = (const float*)d_in[13];
  const float* W2    = (const float*)d_in[14];
  const float* b2    = (const float*)d_in[15];
  const float* Win   = (const float*)d_in[16];
  const float* bin   = (const float*)d_in[17];
  const float* Wst   = (const float*)d_in[18];
  const float* bst   = (const float*)d_in[19];
  const float* Wout  = (const float*)d_in[20];
  const float* bout  = (const float*)d_in[21];
  float* out = (float*)d_out;
  float* ws = (float*)d_ws;

  size_t o = 0;
  auto alloc = [&](size_t nfloats) { size_t r = o; o += (nfloats + 63) & ~(size_t)63; return r; };
  float*  x    = ws + alloc((size_t)BB * LL * H);
  float*  xnT  = ws + alloc((size_t)BB * H * LL);
  float*  yT   = ws + alloc((size_t)BB * H * LL);
  short*  xn2  = (short*)(ws + alloc((size_t)BB * LL * H / 2));
  short*  g1   = (short*)(ws + alloc((size_t)BB * LL * 512 / 2));
  float2* kf   = (float2*)(ws + alloc((size_t)NL * H * 1025 * 2));
  short*  W1bf = (short*)(ws + alloc((size_t)NL * 512 * 256 / 2));
  short*  W2bf = (short*)(ws + alloc((size_t)NL * 256 * 512 / 2));
  float*  WinT = ws + alloc((size_t)64 * 256);
  float*  sp   = ws + alloc((size_t)BB * H);
  float2* tw   = (float2*)(ws + alloc((size_t)2048 * 2));
  (void)ws_size; (void)in_sizes; (void)n_in; (void)out_size;

  k_setup<<<2048, 256, 0, stream>>>(W1, W2, Win, init, Wst, bst, bin,
                                    W1bf, W2bf, WinT, sp, tw);
  k_kernelfft<<<NL * H, 256, 0, stream>>>(A_re, A_im, C_re, C_im, lstep, tw, kf);
  k_in_ln1<<<BB * 64, 256, 0, stream>>>(stim, WinT, sp, ln1w, ln1b, x, xnT);

  for (int i = 0; i < NL; ++i) {
    k_conv<<<BB * H / 2, 256, 0, stream>>>(xnT, kf + (size_t)i * H * 1025,
                                           Dp + i * H, tw, yT);
    k_ln2<<<BB * 64, 256, 0, stream>>>(x, yT, ln2w + i * H, ln2b + i * H, xn2);
    dim3 g1grid(128, 4);
    k_gemm1<<<g1grid, 256, 0, stream>>>(xn2, W1bf + (size_t)i * 512 * 256, b1 + i * 512, g1);
    if (i < NL - 1) {
      k_gemm2f<false><<<256, 256, 0, stream>>>(
          g1, W2bf + (size_t)i * 256 * 512, b2 + i * H, x,
          ln1w + (i + 1) * H, ln1b + (i + 1) * H, xnT, nullptr, nullptr, nullptr);
    } else {
      k_gemm2f<true><<<256, 256, 0, stream>>>(
          g1, W2bf + (size_t)i * 256 * 512, b2 + i * H, x,
          nullptr, nullptr, nullptr, Wout, bout, out);
    }
  }
}

// Round 7
// 242.818 us; speedup vs baseline: 3.9018x; 1.0483x over previous
//
#include <hip/hip_runtime.h>
#include <math.h>

#define NL   4
#define H    256
#define NST  64
#define CIN  64
#define COUT 8
#define BB   8
#define LL   1024
#define NFFT 2048

typedef __attribute__((ext_vector_type(8))) short bf16x8;
typedef __attribute__((ext_vector_type(4))) short short4v;
typedef __attribute__((ext_vector_type(4))) int   int4v;
typedef __attribute__((ext_vector_type(4))) float f32x4;

__device__ __forceinline__ short f2bf(float f) {
  union { float f; unsigned u; } v; v.f = f;
  unsigned r = (v.u + 0x7fffu + ((v.u >> 16) & 1u)) >> 16;
  return (short)r;
}
// pad every 16 float2 (128B) -> strided stage writes stay ~2-way (free)
__device__ __forceinline__ int IDX2(int a) { return a + (a >> 4); }
#define FBUF 2176   // 2048 + 128 pad

__device__ __forceinline__ float2 cadd(float2 a, float2 b) { return make_float2(a.x + b.x, a.y + b.y); }
__device__ __forceinline__ float2 csub(float2 a, float2 b) { return make_float2(a.x - b.x, a.y - b.y); }

// ---------------------------------------------------------------------------
// 2048-pt FFT, float2 LDS: 3 radix-8 Stockham stages (m=1,8,64) + final
// twiddle-free radix-4 (m=512). dst[R*jm + k + d*m] = DFT_R(a)_d * W_N^{d*jm}.
// Input in b0 at IDX2(); result lands in b0. PADDED: upper half (>=1024) zero.
// tw[t] = W_2048^t = e^{-i pi t/1024}, t in [0,2048).
// ---------------------------------------------------------------------------
template <int SGN, bool PADDED>
__device__ __forceinline__ void fft2048(float2* b0, float2* b1,
                                        const float2* __restrict__ tw, int tid) {
  const float RH = 0.70710678118654752f;
  float2 *s = b0, *d = b1;
#pragma unroll
  for (int st = 0; st < 3; ++st) {
    const int m = 1 << (3 * st);            // 1, 8, 64
    __syncthreads();
    const int k  = tid & (m - 1);
    const int jm = tid - k;                 // multiple of m, < 256
    float2 a0 = s[IDX2(tid)];
    float2 a1 = s[IDX2(tid + 256)];
    float2 a2 = s[IDX2(tid + 512)];
    float2 a3 = s[IDX2(tid + 768)];
    float2 a4, a5, a6, a7;
    if (PADDED && st == 0) {
      a4 = make_float2(0.f, 0.f); a5 = a4; a6 = a4; a7 = a4;
    } else {
      a4 = s[IDX2(tid + 1024)];
      a5 = s[IDX2(tid + 1280)];
      a6 = s[IDX2(tid + 1536)];
      a7 = s[IDX2(tid + 1792)];
    }
    float2 s0 = cadd(a0, a4), s1 = csub(a0, a4), s2 = cadd(a2, a6), s3 = csub(a2, a6);
    float2 mi = (SGN < 0) ? make_float2(s3.y, -s3.x) : make_float2(-s3.y, s3.x);
    float2 E0 = cadd(s0, s2), E1 = cadd(s1, mi), E2 = csub(s0, s2), E3 = csub(s1, mi);
    float2 t0 = cadd(a1, a5), t1 = csub(a1, a5), t2 = cadd(a3, a7), t3 = csub(a3, a7);
    float2 mj = (SGN < 0) ? make_float2(t3.y, -t3.x) : make_float2(-t3.y, t3.x);
    float2 O0 = cadd(t0, t2), O1 = cadd(t1, mj), O2 = csub(t0, t2), O3 = csub(t1, mj);
    float2 W0 = O0;
    float2 W1 = (SGN < 0) ? make_float2((O1.x + O1.y) * RH, (O1.y - O1.x) * RH)
                          : make_float2((O1.x - O1.y) * RH, (O1.x + O1.y) * RH);
    float2 W2 = (SGN < 0) ? make_float2(O2.y, -O2.x) : make_float2(-O2.y, O2.x);
    float2 W3 = (SGN < 0) ? make_float2((O3.y - O3.x) * RH, -(O3.x + O3.y) * RH)
                          : make_float2(-(O3.x + O3.y) * RH, (O3.x - O3.y) * RH);
    float2 A[8];
    A[0] = cadd(E0, W0); A[4] = csub(E0, W0);
    A[1] = cadd(E1, W1); A[5] = csub(E1, W1);
    A[2] = cadd(E2, W2); A[6] = csub(E2, W2);
    A[3] = cadd(E3, W3); A[7] = csub(E3, W3);
    const int base = 8 * jm + k;
    d[IDX2(base)] = A[0];
#pragma unroll
    for (int dd = 1; dd < 8; ++dd) {
      float2 w = tw[dd * jm];
      float wi = (SGN < 0) ? w.y : -w.y;
      float2 v = A[dd];
      d[IDX2(base + dd * m)] = make_float2(v.x * w.x - v.y * wi, v.x * wi + v.y * w.x);
    }
    float2* tp = s; s = d; d = tp;
  }
  __syncthreads();
#pragma unroll
  for (int q = 0; q < 2; ++q) {
    const int t = tid + (q << 8);           // [0,512)
    float2 x0 = s[IDX2(t)], x1 = s[IDX2(t + 512)];
    float2 x2 = s[IDX2(t + 1024)], x3 = s[IDX2(t + 1536)];
    float2 s0 = cadd(x0, x2), s1 = csub(x0, x2), s2 = cadd(x1, x3), s3 = csub(x1, x3);
    float2 mi = (SGN < 0) ? make_float2(s3.y, -s3.x) : make_float2(-s3.y, s3.x);
    d[IDX2(t)]        = cadd(s0, s2);
    d[IDX2(t + 512)]  = cadd(s1, mi);
    d[IDX2(t + 1024)] = csub(s0, s2);
    d[IDX2(t + 1536)] = csub(s1, mi);
  }
  __syncthreads();   // result in b0
}

// setup: twiddles (2048), bf16 weight copies, Win transpose, state projection
__global__ __launch_bounds__(256) void k_setup(
    const float* __restrict__ W1, const float* __restrict__ W2, const float* __restrict__ Win,
    const float* __restrict__ init, const float* __restrict__ Wst,
    const float* __restrict__ bst, const float* __restrict__ bin,
    short* __restrict__ W1bf, short* __restrict__ W2bf, float* __restrict__ WinT,
    float* __restrict__ sp, float2* __restrict__ tw) {
  int idx = blockIdx.x * 256 + threadIdx.x;
  if (idx < 2048) {
    float s, c;
    sincosf(3.14159265358979323846f * (float)idx / 1024.0f, &s, &c);
    tw[idx] = make_float2(c, -s);
  }
  if (idx < NL * 512 * 256) {
    W1bf[idx] = f2bf(W1[idx]);
    W2bf[idx] = f2bf(W2[idx]);
  }
  if (idx < 256 * 64) {
    int hh = idx / 64, c = idx % 64;
    WinT[c * 256 + hh] = Win[idx];
  }
  if (idx < BB * H) {
    int b = idx >> 8, h = idx & 255;
    float acc = bin[h] + bst[h];
#pragma unroll
    for (int c = 0; c < COUT; ++c) acc += init[b * COUT + c] * Wst[h * COUT + c];
    sp[idx] = acc;
  }
}

// Fused input-proj + LN1(layer0): 16 l-rows per block; writes x (pre-LN) and
// xnT (transposed normalized).
__global__ __launch_bounds__(256) void k_in_ln1(
    const float* __restrict__ stim, const float* __restrict__ WinT,
    const float* __restrict__ sp, const float* __restrict__ lw, const float* __restrict__ lb,
    float* __restrict__ x, float* __restrict__ xnT) {
  int blk = blockIdx.x;               // b*64 + ltile
  int b_ = blk >> 6, l0 = (blk & 63) << 4;
  int tid = threadIdx.x, wv = tid >> 6, lane = tid & 63;
  __shared__ float sc[16][CIN];
  __shared__ float T[16][256];
#pragma unroll
  for (int it = 0; it < 4; ++it) {
    int idx = tid + (it << 8);
    int r = idx & 15, c = idx >> 4;
    sc[r][c] = stim[(b_ * CIN + c) * LL + l0 + r];
  }
  __syncthreads();
  float4 sp4 = *(const float4*)&sp[b_ * H + lane * 4];
  float4 acc[4] = {sp4, sp4, sp4, sp4};
  for (int c = 0; c < CIN; ++c) {
    float4 wv4 = *(const float4*)&WinT[c * H + lane * 4];
#pragma unroll
    for (int rr = 0; rr < 4; ++rr) {
      float s = sc[wv * 4 + rr][c];
      acc[rr].x += s * wv4.x; acc[rr].y += s * wv4.y;
      acc[rr].z += s * wv4.z; acc[rr].w += s * wv4.w;
    }
  }
  float4 w4 = *(const float4*)&lw[lane * 4];
  float4 c4 = *(const float4*)&lb[lane * 4];
#pragma unroll
  for (int rr = 0; rr < 4; ++rr) {
    int lr = wv * 4 + rr;
    float4 v = acc[rr];
    *(float4*)&x[(((size_t)(b_ << 10) + l0 + lr)) * H + lane * 4] = v;
    float s = v.x + v.y + v.z + v.w;
#pragma unroll
    for (int o = 32; o > 0; o >>= 1) s += __shfl_xor(s, o, 64);
    float m = s * (1.0f / H);
    float dx = v.x - m, dy = v.y - m, dz = v.z - m, dw = v.w - m;
    float q = dx * dx + dy * dy + dz * dz + dw * dw;
#pragma unroll
    for (int o = 32; o > 0; o >>= 1) q += __shfl_xor(q, o, 64);
    float rs = rsqrtf(q * (1.0f / H) + 1e-5f);
    float4 o4;
    o4.x = dx * rs * w4.x + c4.x; o4.y = dy * rs * w4.y + c4.y;
    o4.z = dz * rs * w4.z + c4.z; o4.w = dw * rs * w4.w + c4.w;
    *(float4*)&T[lr][lane * 4] = o4;
  }
  __syncthreads();
  float tmp[16];
#pragma unroll
  for (int l = 0; l < 16; ++l) tmp[l] = T[l][tid];
  float* dst = xnT + ((size_t)(b_ * H + tid)) * LL + l0;
#pragma unroll
  for (int l = 0; l < 16; l += 4) {
    float4 v = {tmp[l], tmp[l + 1], tmp[l + 2], tmp[l + 3]};
    *(float4*)&dst[l] = v;
  }
}

// All layers: blk = i*H + h. K[l] = sum_n cb_n * E_n^l with E^l = T1[l&15] *
// T2[l>>4 & 15] * M^(l>>8) from per-n LDS tables. Then forward FFT.
__global__ __launch_bounds__(256) void k_kernelfft(
    const float* __restrict__ A_re, const float* __restrict__ A_im,
    const float* __restrict__ C_re, const float* __restrict__ C_im,
    const float* __restrict__ log_step, const float2* __restrict__ tw,
    float2* __restrict__ kf) {
  int blk = blockIdx.x;                 // i*H + h
  int i = blk >> 8;
  int tid = threadIdx.x;
  __shared__ float2 cb[NST], Mv[NST];
  __shared__ float2 bufA[FBUF], bufB[FBUF];
  float2* T1 = bufB;                    // [n][16], overlays FFT scratch
  float2* T2 = bufB + 1024;             // [n][16]
  float step = expf(log_step[blk]);
  int n = tid & 63, g = tid >> 6;
  float Ar = A_re[i * NST + n], Ai = A_im[i * NST + n];
  float dr = step * Ar, di = step * Ai;
  float er = expf(dr);
  float sn, cs; sincosf(di, &sn, &cs);
  float Er = er * cs, Ei = er * sn;     // E = exp(dA)
  if (g == 0) {
    float nr = Er - 1.0f, ni = Ei;
    float dnm = Ar * Ar + Ai * Ai;
    float qr = (nr * Ar + ni * Ai) / dnm;    // (exp(dA)-1)/A
    float qi = (ni * Ar - nr * Ai) / dnm;
    float Cr = C_re[(size_t)blk * NST + n], Ci = C_im[(size_t)blk * NST + n];
    cb[n] = make_float2(Cr * qr - Ci * qi, Cr * qi + Ci * qr);
    float pr = 1.f, pi = 0.f;
    T1[n * 16] = make_float2(1.f, 0.f);
    for (int a = 1; a < 16; ++a) {
      float t2 = pr * Er - pi * Ei; pi = pr * Ei + pi * Er; pr = t2;
      T1[n * 16 + a] = make_float2(pr, pi);
    }
  } else if (g == 1) {
    float xr = Er, xi = Ei;
#pragma unroll
    for (int j = 0; j < 4; ++j) { float t2 = xr * xr - xi * xi; xi = 2.f * xr * xi; xr = t2; }
    float pr = 1.f, pi = 0.f;
    T2[n * 16] = make_float2(1.f, 0.f);
    for (int a = 1; a < 16; ++a) {
      float t2 = pr * xr - pi * xi; pi = pr * xi + pi * xr; pr = t2;
      T2[n * 16 + a] = make_float2(pr, pi);
    }
    float mr2 = pr * xr - pi * xi, mi2 = pr * xi + pi * xr;   // E^256
    Mv[n] = make_float2(mr2, mi2);
  }
  __syncthreads();
  float kr[4] = {0.f, 0.f, 0.f, 0.f}, ki[4] = {0.f, 0.f, 0.f, 0.f};
  const int a_lo = tid & 15, a_hi = tid >> 4;
  for (int nn = 0; nn < NST; ++nn) {
    float2 t1 = T1[nn * 16 + a_lo];
    float2 t2v = T2[nn * 16 + a_hi];
    float pr = t1.x * t2v.x - t1.y * t2v.y;   // E^tid
    float pi = t1.x * t2v.y + t1.y * t2v.x;
    float2 c = cb[nn], m = Mv[nn];
#pragma unroll
    for (int q = 0; q < 4; ++q) {
      kr[q] += c.x * pr - c.y * pi;
      ki[q] += c.x * pi + c.y * pr;
      float t2 = pr * m.x - pi * m.y;         // p *= E^256
      pi = pr * m.y + pi * m.x;
      pr = t2;
    }
  }
  __syncthreads();   // powering done before bufB (tables) is clobbered by FFT
#pragma unroll
  for (int q = 0; q < 4; ++q) {
    int l = tid + (q << 8);
    bufA[IDX2(l)] = make_float2(kr[q], ki[q]);
  }
  fft2048<-1, true>(bufA, bufB, tw, tid);   // result in bufA
  float2* kfh = kf + (size_t)blk * 1025;
#pragma unroll
  for (int q = 0; q < 4; ++q) {
    int k = tid + (q << 8);
    kfh[k] = bufA[IDX2(k)];
  }
  if (tid == 0) kfh[1024] = bufA[IDX2(1024)];
}

// Two rows packed per complex FFT; spectral multiply + Hermitian extension
// (irfft bin 0/1024 imag-drop); packed inverse.
__global__ __launch_bounds__(256) void k_conv(
    const float* __restrict__ xnT, const float2* __restrict__ kf,
    const float* __restrict__ D, const float2* __restrict__ tw, float* __restrict__ yT) {
  int blk = blockIdx.x;                 // b*128 + hp
  int b_ = blk >> 7, hp = blk & 127;
  int h0 = hp * 2, h1 = h0 + 1;
  int r0 = b_ * H + h0;
  int tid = threadIdx.x;
  __shared__ float2 bufA[FBUF], bufB[FBUF];
  float u0[4], u1[4];
  const float* x0 = xnT + (size_t)r0 * LL;
  const float* x1 = x0 + LL;
#pragma unroll
  for (int q = 0; q < 4; ++q) {
    int l = tid + (q << 8);
    float v0 = x0[l], v1 = x1[l];
    u0[q] = v0; u1[q] = v1;
    bufA[IDX2(l)] = make_float2(v0, v1);      // upper half implicit zero (PADDED)
  }
  fft2048<-1, true>(bufA, bufB, tw, tid);     // F = FFT(u0 + i*u1) in bufA
  const float2* kf0 = kf + (size_t)h0 * 1025;
  const float2* kf1 = kf + (size_t)h1 * 1025;
#pragma unroll
  for (int q = 0; q < 4; ++q) {
    int k = tid + (q << 8);
    if (k == 0) {
      float2 k0 = kf0[0], k1 = kf1[0];
      float2 F0 = bufA[IDX2(0)], Fn = bufA[IDX2(1024)];
      bufB[IDX2(0)]    = make_float2(F0.x * k0.x, F0.y * k1.x);
      float2 k0n = kf0[1024], k1n = kf1[1024];
      bufB[IDX2(1024)] = make_float2(Fn.x * k0n.x, Fn.y * k1n.x);
    } else {
      float2 F = bufA[IDX2(k)], G = bufA[IDX2(2048 - k)];
      float u0r = 0.5f * (F.x + G.x), u0i = 0.5f * (F.y - G.y);   // U0[k]
      float dr_ = 0.5f * (F.x - G.x), di_ = 0.5f * (F.y + G.y);
      float u1r = di_, u1i = -dr_;                                // U1[k]
      float2 k0 = kf0[k], k1 = kf1[k];
      float z0r = u0r * k0.x - u0i * k0.y, z0i = u0r * k0.y + u0i * k0.x;
      float z1r = u1r * k1.x - u1i * k1.y, z1i = u1r * k1.y + u1i * k1.x;
      bufB[IDX2(k)]        = make_float2(z0r - z1i, z0i + z1r);
      bufB[IDX2(2048 - k)] = make_float2(z0r + z1i, z1r - z0i);
    }
  }
  fft2048<1, false>(bufB, bufA, tw, tid);     // z0 + i*z1 in bufB (both real)
  float Dh0 = D[h0], Dh1 = D[h1];
  float* y0 = yT + (size_t)r0 * LL;
  float* y1 = y0 + LL;
#pragma unroll
  for (int q = 0; q < 4; ++q) {
    int l = tid + (q << 8);
    float2 z = bufB[IDX2(l)];
    y0[l] = z.x * (1.0f / NFFT) + Dh0 * u0[q];
    y1[l] = z.y * (1.0f / NFFT) + Dh1 * u1[q];
  }
}

// ---------------------------------------------------------------------------
// Mega MLP kernel: per 32-row tile (grid 256, 1 block/CU):
//  A: v = x + yT-gather (kept in REGISTERS); LN2 -> bf16 A1 in LDS
//  B: GEMM1 (K=256) from A1, W1 staged per K=32 -> +b1, GELU -> bf16 A2 in LDS
//  C: GEMM2 (K=512) from A2, W2 staged per K=32
//  D: vf = acc2 + b2 + v; then next-layer LN1 + xnT write, or output proj.
// LDS overlay: A1[32][264]s @0 (16.9K) | B1[512][40]s @16896 (40.9K) |
//              A2[32][520]s @0 (33.3K) | B2[256][40]s @33280 (20.5K) |
//              Txn[32][260]f @0, wlds[8][258]f @33280 (LAST) | red @57856 (1K)
// ---------------------------------------------------------------------------
#define TXS 260
template <bool LAST>
__global__ __launch_bounds__(256) void k_mlp(
    const short* __restrict__ W1p, const float* __restrict__ b1p,
    const short* __restrict__ W2p, const float* __restrict__ b2p,
    float* __restrict__ x, const float* __restrict__ yT,
    const float* __restrict__ ln2w, const float* __restrict__ ln2b,
    const float* __restrict__ ln1w, const float* __restrict__ ln1b,
    float* __restrict__ xnT,
    const float* __restrict__ Wout, const float* __restrict__ bout,
    float* __restrict__ out) {
  const int m0 = blockIdx.x * 32;
  const int b_ = m0 >> 10, l0 = m0 & 1023;
  const int tid = threadIdx.x;
  const int lane = tid & 63, wid = tid >> 6;
  const int rg = lane >> 4, cl = lane & 15;
  __shared__ __attribute__((aligned(16))) char smem[58880];
  short* A1  = (short*)smem;                 // [32][264]
  short* B1  = (short*)(smem + 16896);       // [512][40]
  short* A2  = (short*)smem;                 // [32][520]
  short* B2  = (short*)(smem + 33280);       // [256][40]
  float* Txn = (float*)smem;                 // [32][260] (LAST)
  float* wlds = (float*)(smem + 33280);      // [8][258]  (LAST)
  float* red = (float*)(smem + 57856);       // [4][32][2]

  // ---- Phase A: residual add (registers) + LN2 -> A1 bf16 ----
  float v[2][4][4];
  float wl2[4], bl2[4];
#pragma unroll
  for (int n = 0; n < 4; ++n) {
    int col = wid * 64 + n * 16 + cl;
    wl2[n] = ln2w[col]; bl2[n] = ln2b[col];
  }
  float sum[2][4], sq[2][4];
#pragma unroll
  for (int m = 0; m < 2; ++m)
#pragma unroll
    for (int r = 0; r < 4; ++r) { sum[m][r] = 0.f; sq[m][r] = 0.f; }
#pragma unroll
  for (int m = 0; m < 2; ++m)
#pragma unroll
    for (int n = 0; n < 4; ++n) {
      int col = wid * 64 + n * 16 + cl;
      float4 y4 = *(const float4*)&yT[((size_t)(b_ * H + col)) * LL + l0 + m * 16 + rg * 4];
      float yv[4] = {y4.x, y4.y, y4.z, y4.w};
#pragma unroll
      for (int r = 0; r < 4; ++r) {
        int row = m * 16 + rg * 4 + r;
        float val = x[(size_t)(m0 + row) * H + col] + yv[r];
        v[m][n][r] = val;
        sum[m][r] += val; sq[m][r] += val * val;
      }
    }
#pragma unroll
  for (int m = 0; m < 2; ++m)
#pragma unroll
    for (int r = 0; r < 4; ++r) {
#pragma unroll
      for (int o = 1; o < 16; o <<= 1) {
        sum[m][r] += __shfl_xor(sum[m][r], o, 64);
        sq[m][r]  += __shfl_xor(sq[m][r], o, 64);
      }
    }
  if (cl == 0) {
#pragma unroll
    for (int m = 0; m < 2; ++m)
#pragma unroll
      for (int r = 0; r < 4; ++r) {
        int row = m * 16 + rg * 4 + r;
        red[(wid * 32 + row) * 2]     = sum[m][r];
        red[(wid * 32 + row) * 2 + 1] = sq[m][r];
      }
  }
  __syncthreads();
#pragma unroll
  for (int m = 0; m < 2; ++m)
#pragma unroll
    for (int r = 0; r < 4; ++r) {
      int row = m * 16 + rg * 4 + r;
      float S = 0.f, Q = 0.f;
#pragma unroll
      for (int w = 0; w < 4; ++w) { S += red[(w * 32 + row) * 2]; Q += red[(w * 32 + row) * 2 + 1]; }
      float mean = S * (1.0f / H);
      float var = Q * (1.0f / H) - mean * mean;
      float rs = rsqrtf(var + 1e-5f);
#pragma unroll
      for (int n = 0; n < 4; ++n) {
        int col = wid * 64 + n * 16 + cl;
        A1[row * 264 + col] = f2bf((v[m][n][r] - mean) * rs * wl2[n] + bl2[n]);
      }
    }

  // ---- Phase B: GEMM1 (32x512, K=256) ----
  f32x4 acc1[2][8];
#pragma unroll
  for (int m = 0; m < 2; ++m)
#pragma unroll
    for (int n = 0; n < 8; ++n) acc1[m][n] = (f32x4){0.f, 0.f, 0.f, 0.f};
  for (int kk = 0; kk < 256; kk += 32) {
    __syncthreads();
#pragma unroll
    for (int it = 0; it < 8; ++it) {
      int idx = tid + (it << 8);            // 0..2047
      int row = idx >> 2, seg = (idx & 3) * 8;
      *(int4v*)&B1[row * 40 + seg] = *(const int4v*)(W1p + (size_t)row * 256 + kk + seg);
    }
    __syncthreads();
    bf16x8 af[2], bfv[8];
#pragma unroll
    for (int m = 0; m < 2; ++m)
      af[m] = *(const bf16x8*)&A1[(m * 16 + cl) * 264 + kk + rg * 8];
#pragma unroll
    for (int n = 0; n < 8; ++n)
      bfv[n] = *(const bf16x8*)&B1[(wid * 128 + n * 16 + cl) * 40 + rg * 8];
#pragma unroll
    for (int m = 0; m < 2; ++m)
#pragma unroll
      for (int n = 0; n < 8; ++n)
        acc1[m][n] = __builtin_amdgcn_mfma_f32_16x16x32_bf16(af[m], bfv[n], acc1[m][n], 0, 0, 0);
  }
  __syncthreads();   // A1/B1 dead
  // +b1, GELU -> A2 bf16
#pragma unroll
  for (int m = 0; m < 2; ++m)
#pragma unroll
    for (int n = 0; n < 8; ++n) {
      int col = wid * 128 + n * 16 + cl;
      float bb = b1p[col];
#pragma unroll
      for (int r = 0; r < 4; ++r) {
        int row = m * 16 + rg * 4 + r;
        float g = acc1[m][n][r] + bb;
        g = 0.5f * g * (1.0f + erff(g * 0.70710678118654752f));
        A2[row * 520 + col] = f2bf(g);
      }
    }

  // ---- Phase C: GEMM2 (32x256, K=512) ----
  f32x4 acc2[2][4];
#pragma unroll
  for (int m = 0; m < 2; ++m)
#pragma unroll
    for (int n = 0; n < 4; ++n) acc2[m][n] = (f32x4){0.f, 0.f, 0.f, 0.f};
  for (int kk = 0; kk < 512; kk += 32) {
    __syncthreads();
#pragma unroll
    for (int it = 0; it < 4; ++it) {
      int idx = tid + (it << 8);            // 0..1023
      int row = idx >> 2, seg = (idx & 3) * 8;
      *(int4v*)&B2[row * 40 + seg] = *(const int4v*)(W2p + (size_t)row * 512 + kk + seg);
    }
    __syncthreads();
    bf16x8 af[2], bfv[4];
#pragma unroll
    for (int m = 0; m < 2; ++m)
      af[m] = *(const bf16x8*)&A2[(m * 16 + cl) * 520 + kk + rg * 8];
#pragma unroll
    for (int n = 0; n < 4; ++n)
      bfv[n] = *(const bf16x8*)&B2[(wid * 64 + n * 16 + cl) * 40 + rg * 8];
#pragma unroll
    for (int m = 0; m < 2; ++m)
#pragma unroll
      for (int n = 0; n < 4; ++n)
        acc2[m][n] = __builtin_amdgcn_mfma_f32_16x16x32_bf16(af[m], bfv[n], acc2[m][n], 0, 0, 0);
  }
  __syncthreads();   // A2/B2 dead

  // ---- Phase D: vf = acc2 + b2 + v; LN1-next + xnT | output proj ----
  float bv[4], wl1[4], bl1[4];
#pragma unroll
  for (int n = 0; n < 4; ++n) {
    int col = wid * 64 + n * 16 + cl;
    bv[n] = b2p[col];
    if (!LAST) { wl1[n] = ln1w[col]; bl1[n] = ln1b[col]; }
  }
#pragma unroll
  for (int m = 0; m < 2; ++m)
#pragma unroll
    for (int r = 0; r < 4; ++r) { sum[m][r] = 0.f; sq[m][r] = 0.f; }
#pragma unroll
  for (int m = 0; m < 2; ++m)
#pragma unroll
    for (int n = 0; n < 4; ++n) {
      int col = wid * 64 + n * 16 + cl;
#pragma unroll
      for (int r = 0; r < 4; ++r) {
        int row = m * 16 + rg * 4 + r;
        float vf = acc2[m][n][r] + bv[n] + v[m][n][r];
        acc2[m][n][r] = vf;
        if (LAST) Txn[row * TXS + col] = vf;
        sum[m][r] += vf; sq[m][r] += vf * vf;
      }
    }

  if (LAST) {
#pragma unroll
    for (int it = 0; it < 8; ++it) {
      int idx = tid + (it << 8);
      wlds[(idx >> 8) * 258 + (idx & 255)] = Wout[idx];
    }
    __syncthreads();
    int row = tid >> 3, co = tid & 7;
    float p = bout[co];
    const float* tr = Txn + row * TXS;
    const float* wr = wlds + co * 258;
#pragma unroll 4
    for (int c = 0; c < H; ++c) p += tr[c] * wr[c];
    out[((b_ * COUT + co) << 10) + l0 + row] = p;
  } else {
#pragma unroll
    for (int m = 0; m < 2; ++m)
#pragma unroll
      for (int r = 0; r < 4; ++r) {
#pragma unroll
        for (int o = 1; o < 16; o <<= 1) {
          sum[m][r] += __shfl_xor(sum[m][r], o, 64);
          sq[m][r]  += __shfl_xor(sq[m][r], o, 64);
        }
      }
    if (cl == 0) {
#pragma unroll
      for (int m = 0; m < 2; ++m)
#pragma unroll
        for (int r = 0; r < 4; ++r) {
          int row = m * 16 + rg * 4 + r;
          red[(wid * 32 + row) * 2]     = sum[m][r];
          red[(wid * 32 + row) * 2 + 1] = sq[m][r];
        }
    }
    __syncthreads();
#pragma unroll
    for (int m = 0; m < 2; ++m) {
#pragma unroll
      for (int r = 0; r < 4; ++r) {
        int row = m * 16 + rg * 4 + r;
        float S = 0.f, Q = 0.f;
#pragma unroll
        for (int w = 0; w < 4; ++w) { S += red[(w * 32 + row) * 2]; Q += red[(w * 32 + row) * 2 + 1]; }
        float mean = S * (1.0f / H);
        float var = Q * (1.0f / H) - mean * mean;
        float rs = rsqrtf(var + 1e-5f);
#pragma unroll
        for (int n = 0; n < 4; ++n) {
          int col = wid * 64 + n * 16 + cl;
          float vf = acc2[m][n][r];
          x[(size_t)(m0 + row) * H + col] = vf;
          Txn[row * TXS + col] = (vf - mean) * rs * wl1[n] + bl1[n];
        }
      }
    }
    __syncthreads();
    float tmp[32];
#pragma unroll
    for (int l = 0; l < 32; ++l) tmp[l] = Txn[l * TXS + tid];
    float* dst = xnT + ((size_t)(b_ * H + tid)) * LL + l0;
#pragma unroll
    for (int l = 0; l < 32; l += 4) {
      float4 v4 = {tmp[l], tmp[l + 1], tmp[l + 2], tmp[l + 3]};
      *(float4*)&dst[l] = v4;
    }
  }
}

extern "C" void kernel_launch(void* const* d_in, const int* in_sizes, int n_in,
                              void* d_out, int out_size, void* d_ws, size_t ws_size,
                              hipStream_t stream) {
  const float* stim  = (const float*)d_in[0];
  const float* init  = (const float*)d_in[1];
  const float* A_re  = (const float*)d_in[2];
  const float* A_im  = (const float*)d_in[3];
  const float* C_re  = (const float*)d_in[4];
  const float* C_im  = (const float*)d_in[5];
  const float* Dp    = (const float*)d_in[6];
  const float* lstep = (const float*)d_in[7];
  const float* ln1w  = (const float*)d_in[8];
  const float* ln1b  = (const float*)d_in[9];
  const float* ln2w  = (const float*)d_in[10];
  const float* ln2b  = (const float*)d_in[11];
  const float* W1    = (const float*)d_in[12];
  const float* b1    = (const float*)d_in[13];
  const float* W2    = (const float*)d_in[14];
  const float* b2    = (const float*)d_in[15];
  const float* Win   = (const float*)d_in[16];
  const float* bin   = (const float*)d_in[17];
  const float* Wst   = (const float*)d_in[18];
  const float* bst   = (const float*)d_in[19];
  const float* Wout  = (const float*)d_in[20];
  const float* bout  = (const float*)d_in[21];
  float* out = (float*)d_out;
  float* ws = (float*)d_ws;

  size_t o = 0;
  auto alloc = [&](size_t nfloats) { size_t r = o; o += (nfloats + 63) & ~(size_t)63; return r; };
  float*  x    = ws + alloc((size_t)BB * LL * H);
  float*  xnT  = ws + alloc((size_t)BB * H * LL);
  float*  yT   = ws + alloc((size_t)BB * H * LL);
  float2* kf   = (float2*)(ws + alloc((size_t)NL * H * 1025 * 2));
  short*  W1bf = (short*)(ws + alloc((size_t)NL * 512 * 256 / 2));
  short*  W2bf = (short*)(ws + alloc((size_t)NL * 256 * 512 / 2));
  float*  WinT = ws + alloc((size_t)64 * 256);
  float*  sp   = ws + alloc((size_t)BB * H);
  float2* tw   = (float2*)(ws + alloc((size_t)2048 * 2));
  (void)ws_size; (void)in_sizes; (void)n_in; (void)out_size;

  k_setup<<<2048, 256, 0, stream>>>(W1, W2, Win, init, Wst, bst, bin,
                                    W1bf, W2bf, WinT, sp, tw);
  k_kernelfft<<<NL * H, 256, 0, stream>>>(A_re, A_im, C_re, C_im, lstep, tw, kf);
  k_in_ln1<<<BB * 64, 256, 0, stream>>>(stim, WinT, sp, ln1w, ln1b, x, xnT);

  for (int i = 0; i < NL; ++i) {
    k_conv<<<BB * H / 2, 256, 0, stream>>>(xnT, kf + (size_t)i * H * 1025,
                                           Dp + i * H, tw, yT);
    if (i < NL - 1) {
      k_mlp<false><<<256, 256, 0, stream>>>(
          W1bf + (size_t)i * 512 * 256, b1 + i * 512,
          W2bf + (size_t)i * 256 * 512, b2 + i * H,
          x, yT, ln2w + i * H, ln2b + i * H,
          ln1w + (i + 1) * H, ln1b + (i + 1) * H, xnT,
          nullptr, nullptr, nullptr);
    } else {
      k_mlp<true><<<256, 256, 0, stream>>>(
          W1bf + (size_t)i * 512 * 256, b1 + i * 512,
          W2bf + (size_t)i * 256 * 512, b2 + i * H,
          x, yT, ln2w + i * H, ln2b + i * H,
          nullptr, nullptr, nullptr,
          Wout, bout, out);
    }
  }
}

// Round 8
// 224.827 us; speedup vs baseline: 4.2140x; 1.0800x over previous
//
#include <hip/hip_runtime.h>
#include <math.h>

#define NL   4
#define H    256
#define NST  64
#define CIN  64
#define COUT 8
#define BB   8
#define LL   1024
#define NFFT 2048

typedef __attribute__((ext_vector_type(8))) short bf16x8;
typedef __attribute__((ext_vector_type(4))) short short4v;
typedef __attribute__((ext_vector_type(4))) int   int4v;
typedef __attribute__((ext_vector_type(4))) float f32x4;

__device__ __forceinline__ short f2bf(float f) {
  union { float f; unsigned u; } v; v.f = f;
  unsigned r = (v.u + 0x7fffu + ((v.u >> 16) & 1u)) >> 16;
  return (short)r;
}
// pad every 16 float2 (128B) -> strided stage writes stay ~2-way (free)
__device__ __forceinline__ int IDX2(int a) { return a + (a >> 4); }
#define FBUF 2176   // 2048 + 128 pad

__device__ __forceinline__ float2 cadd(float2 a, float2 b) { return make_float2(a.x + b.x, a.y + b.y); }
__device__ __forceinline__ float2 csub(float2 a, float2 b) { return make_float2(a.x - b.x, a.y - b.y); }

// ---------------------------------------------------------------------------
// 2048-pt FFT, float2 LDS: 3 radix-8 Stockham stages (m=1,8,64) + final
// twiddle-free radix-4 (m=512). dst[R*jm + k + d*m] = DFT_R(a)_d * W_N^{d*jm}.
// Input in b0 at IDX2(); result lands in b0. PADDED: upper half (>=1024) zero.
// tw[t] = W_2048^t = e^{-i pi t/1024}, t in [0,2048).
// ---------------------------------------------------------------------------
template <int SGN, bool PADDED>
__device__ __forceinline__ void fft2048(float2* b0, float2* b1,
                                        const float2* __restrict__ tw, int tid) {
  const float RH = 0.70710678118654752f;
  float2 *s = b0, *d = b1;
#pragma unroll
  for (int st = 0; st < 3; ++st) {
    const int m = 1 << (3 * st);            // 1, 8, 64
    __syncthreads();
    const int k  = tid & (m - 1);
    const int jm = tid - k;                 // multiple of m, < 256
    float2 a0 = s[IDX2(tid)];
    float2 a1 = s[IDX2(tid + 256)];
    float2 a2 = s[IDX2(tid + 512)];
    float2 a3 = s[IDX2(tid + 768)];
    float2 a4, a5, a6, a7;
    if (PADDED && st == 0) {
      a4 = make_float2(0.f, 0.f); a5 = a4; a6 = a4; a7 = a4;
    } else {
      a4 = s[IDX2(tid + 1024)];
      a5 = s[IDX2(tid + 1280)];
      a6 = s[IDX2(tid + 1536)];
      a7 = s[IDX2(tid + 1792)];
    }
    float2 s0 = cadd(a0, a4), s1 = csub(a0, a4), s2 = cadd(a2, a6), s3 = csub(a2, a6);
    float2 mi = (SGN < 0) ? make_float2(s3.y, -s3.x) : make_float2(-s3.y, s3.x);
    float2 E0 = cadd(s0, s2), E1 = cadd(s1, mi), E2 = csub(s0, s2), E3 = csub(s1, mi);
    float2 t0 = cadd(a1, a5), t1 = csub(a1, a5), t2 = cadd(a3, a7), t3 = csub(a3, a7);
    float2 mj = (SGN < 0) ? make_float2(t3.y, -t3.x) : make_float2(-t3.y, t3.x);
    float2 O0 = cadd(t0, t2), O1 = cadd(t1, mj), O2 = csub(t0, t2), O3 = csub(t1, mj);
    float2 W0 = O0;
    float2 W1 = (SGN < 0) ? make_float2((O1.x + O1.y) * RH, (O1.y - O1.x) * RH)
                          : make_float2((O1.x - O1.y) * RH, (O1.x + O1.y) * RH);
    float2 W2 = (SGN < 0) ? make_float2(O2.y, -O2.x) : make_float2(-O2.y, O2.x);
    float2 W3 = (SGN < 0) ? make_float2((O3.y - O3.x) * RH, -(O3.x + O3.y) * RH)
                          : make_float2(-(O3.x + O3.y) * RH, (O3.x - O3.y) * RH);
    float2 A[8];
    A[0] = cadd(E0, W0); A[4] = csub(E0, W0);
    A[1] = cadd(E1, W1); A[5] = csub(E1, W1);
    A[2] = cadd(E2, W2); A[6] = csub(E2, W2);
    A[3] = cadd(E3, W3); A[7] = csub(E3, W3);
    const int base = 8 * jm + k;
    d[IDX2(base)] = A[0];
#pragma unroll
    for (int dd = 1; dd < 8; ++dd) {
      float2 w = tw[dd * jm];
      float wi = (SGN < 0) ? w.y : -w.y;
      float2 v = A[dd];
      d[IDX2(base + dd * m)] = make_float2(v.x * w.x - v.y * wi, v.x * wi + v.y * w.x);
    }
    float2* tp = s; s = d; d = tp;
  }
  __syncthreads();
#pragma unroll
  for (int q = 0; q < 2; ++q) {
    const int t = tid + (q << 8);           // [0,512)
    float2 x0 = s[IDX2(t)], x1 = s[IDX2(t + 512)];
    float2 x2 = s[IDX2(t + 1024)], x3 = s[IDX2(t + 1536)];
    float2 s0 = cadd(x0, x2), s1 = csub(x0, x2), s2 = cadd(x1, x3), s3 = csub(x1, x3);
    float2 mi = (SGN < 0) ? make_float2(s3.y, -s3.x) : make_float2(-s3.y, s3.x);
    d[IDX2(t)]        = cadd(s0, s2);
    d[IDX2(t + 512)]  = cadd(s1, mi);
    d[IDX2(t + 1024)] = csub(s0, s2);
    d[IDX2(t + 1536)] = csub(s1, mi);
  }
  __syncthreads();   // result in b0
}

// setup: twiddles (2048), bf16 weight copies, Win transpose, state projection
__global__ __launch_bounds__(256) void k_setup(
    const float* __restrict__ W1, const float* __restrict__ W2, const float* __restrict__ Win,
    const float* __restrict__ init, const float* __restrict__ Wst,
    const float* __restrict__ bst, const float* __restrict__ bin,
    short* __restrict__ W1bf, short* __restrict__ W2bf, float* __restrict__ WinT,
    float* __restrict__ sp, float2* __restrict__ tw) {
  int idx = blockIdx.x * 256 + threadIdx.x;
  if (idx < 2048) {
    float s, c;
    sincosf(3.14159265358979323846f * (float)idx / 1024.0f, &s, &c);
    tw[idx] = make_float2(c, -s);
  }
  if (idx < NL * 512 * 256) {
    W1bf[idx] = f2bf(W1[idx]);
    W2bf[idx] = f2bf(W2[idx]);
  }
  if (idx < 256 * 64) {
    int hh = idx / 64, c = idx % 64;
    WinT[c * 256 + hh] = Win[idx];
  }
  if (idx < BB * H) {
    int b = idx >> 8, h = idx & 255;
    float acc = bin[h] + bst[h];
#pragma unroll
    for (int c = 0; c < COUT; ++c) acc += init[b * COUT + c] * Wst[h * COUT + c];
    sp[idx] = acc;
  }
}

// Fused input-proj + LN1(layer0): 16 l-rows per block; writes x (pre-LN) and
// xnT (transposed normalized).
__global__ __launch_bounds__(256) void k_in_ln1(
    const float* __restrict__ stim, const float* __restrict__ WinT,
    const float* __restrict__ sp, const float* __restrict__ lw, const float* __restrict__ lb,
    float* __restrict__ x, float* __restrict__ xnT) {
  int blk = blockIdx.x;               // b*64 + ltile
  int b_ = blk >> 6, l0 = (blk & 63) << 4;
  int tid = threadIdx.x, wv = tid >> 6, lane = tid & 63;
  __shared__ float sc[16][CIN];
  __shared__ float T[16][256];
#pragma unroll
  for (int it = 0; it < 4; ++it) {
    int idx = tid + (it << 8);
    int r = idx & 15, c = idx >> 4;
    sc[r][c] = stim[(b_ * CIN + c) * LL + l0 + r];
  }
  __syncthreads();
  float4 sp4 = *(const float4*)&sp[b_ * H + lane * 4];
  float4 acc[4] = {sp4, sp4, sp4, sp4};
  for (int c = 0; c < CIN; ++c) {
    float4 wv4 = *(const float4*)&WinT[c * H + lane * 4];
#pragma unroll
    for (int rr = 0; rr < 4; ++rr) {
      float s = sc[wv * 4 + rr][c];
      acc[rr].x += s * wv4.x; acc[rr].y += s * wv4.y;
      acc[rr].z += s * wv4.z; acc[rr].w += s * wv4.w;
    }
  }
  float4 w4 = *(const float4*)&lw[lane * 4];
  float4 c4 = *(const float4*)&lb[lane * 4];
#pragma unroll
  for (int rr = 0; rr < 4; ++rr) {
    int lr = wv * 4 + rr;
    float4 v = acc[rr];
    *(float4*)&x[(((size_t)(b_ << 10) + l0 + lr)) * H + lane * 4] = v;
    float s = v.x + v.y + v.z + v.w;
#pragma unroll
    for (int o = 32; o > 0; o >>= 1) s += __shfl_xor(s, o, 64);
    float m = s * (1.0f / H);
    float dx = v.x - m, dy = v.y - m, dz = v.z - m, dw = v.w - m;
    float q = dx * dx + dy * dy + dz * dz + dw * dw;
#pragma unroll
    for (int o = 32; o > 0; o >>= 1) q += __shfl_xor(q, o, 64);
    float rs = rsqrtf(q * (1.0f / H) + 1e-5f);
    float4 o4;
    o4.x = dx * rs * w4.x + c4.x; o4.y = dy * rs * w4.y + c4.y;
    o4.z = dz * rs * w4.z + c4.z; o4.w = dw * rs * w4.w + c4.w;
    *(float4*)&T[lr][lane * 4] = o4;
  }
  __syncthreads();
  float tmp[16];
#pragma unroll
  for (int l = 0; l < 16; ++l) tmp[l] = T[l][tid];
  float* dst = xnT + ((size_t)(b_ * H + tid)) * LL + l0;
#pragma unroll
  for (int l = 0; l < 16; l += 4) {
    float4 v = {tmp[l], tmp[l + 1], tmp[l + 2], tmp[l + 3]};
    *(float4*)&dst[l] = v;
  }
}

// All layers: blk = i*H + h. K[l] = sum_n cb_n * E_n^l with E^l = T1[l&15] *
// T2[l>>4 & 15] * M^(l>>8) from per-n LDS tables. Then forward FFT.
__global__ __launch_bounds__(256) void k_kernelfft(
    const float* __restrict__ A_re, const float* __restrict__ A_im,
    const float* __restrict__ C_re, const float* __restrict__ C_im,
    const float* __restrict__ log_step, const float2* __restrict__ tw,
    float2* __restrict__ kf) {
  int blk = blockIdx.x;                 // i*H + h
  int i = blk >> 8;
  int tid = threadIdx.x;
  __shared__ float2 cb[NST], Mv[NST];
  __shared__ float2 bufA[FBUF], bufB[FBUF];
  float2* T1 = bufB;                    // [n][16], overlays FFT scratch
  float2* T2 = bufB + 1024;             // [n][16]
  float step = expf(log_step[blk]);
  int n = tid & 63, g = tid >> 6;
  float Ar = A_re[i * NST + n], Ai = A_im[i * NST + n];
  float dr = step * Ar, di = step * Ai;
  float er = expf(dr);
  float sn, cs; sincosf(di, &sn, &cs);
  float Er = er * cs, Ei = er * sn;     // E = exp(dA)
  if (g == 0) {
    float nr = Er - 1.0f, ni = Ei;
    float dnm = Ar * Ar + Ai * Ai;
    float qr = (nr * Ar + ni * Ai) / dnm;    // (exp(dA)-1)/A
    float qi = (ni * Ar - nr * Ai) / dnm;
    float Cr = C_re[(size_t)blk * NST + n], Ci = C_im[(size_t)blk * NST + n];
    cb[n] = make_float2(Cr * qr - Ci * qi, Cr * qi + Ci * qr);
    float pr = 1.f, pi = 0.f;
    T1[n * 16] = make_float2(1.f, 0.f);
    for (int a = 1; a < 16; ++a) {
      float t2 = pr * Er - pi * Ei; pi = pr * Ei + pi * Er; pr = t2;
      T1[n * 16 + a] = make_float2(pr, pi);
    }
  } else if (g == 1) {
    float xr = Er, xi = Ei;
#pragma unroll
    for (int j = 0; j < 4; ++j) { float t2 = xr * xr - xi * xi; xi = 2.f * xr * xi; xr = t2; }
    float pr = 1.f, pi = 0.f;
    T2[n * 16] = make_float2(1.f, 0.f);
    for (int a = 1; a < 16; ++a) {
      float t2 = pr * xr - pi * xi; pi = pr * xi + pi * xr; pr = t2;
      T2[n * 16 + a] = make_float2(pr, pi);
    }
    float mr2 = pr * xr - pi * xi, mi2 = pr * xi + pi * xr;   // E^256
    Mv[n] = make_float2(mr2, mi2);
  }
  __syncthreads();
  float kr[4] = {0.f, 0.f, 0.f, 0.f}, ki[4] = {0.f, 0.f, 0.f, 0.f};
  const int a_lo = tid & 15, a_hi = tid >> 4;
  for (int nn = 0; nn < NST; ++nn) {
    float2 t1 = T1[nn * 16 + a_lo];
    float2 t2v = T2[nn * 16 + a_hi];
    float pr = t1.x * t2v.x - t1.y * t2v.y;   // E^tid
    float pi = t1.x * t2v.y + t1.y * t2v.x;
    float2 c = cb[nn], m = Mv[nn];
#pragma unroll
    for (int q = 0; q < 4; ++q) {
      kr[q] += c.x * pr - c.y * pi;
      ki[q] += c.x * pi + c.y * pr;
      float t2 = pr * m.x - pi * m.y;         // p *= E^256
      pi = pr * m.y + pi * m.x;
      pr = t2;
    }
  }
  __syncthreads();   // powering done before bufB (tables) is clobbered by FFT
#pragma unroll
  for (int q = 0; q < 4; ++q) {
    int l = tid + (q << 8);
    bufA[IDX2(l)] = make_float2(kr[q], ki[q]);
  }
  fft2048<-1, true>(bufA, bufB, tw, tid);   // result in bufA
  float2* kfh = kf + (size_t)blk * 1025;
#pragma unroll
  for (int q = 0; q < 4; ++q) {
    int k = tid + (q << 8);
    kfh[k] = bufA[IDX2(k)];
  }
  if (tid == 0) kfh[1024] = bufA[IDX2(1024)];
}

// Two rows packed per complex FFT; spectral multiply + Hermitian extension
// (irfft bin 0/1024 imag-drop); packed inverse.
__global__ __launch_bounds__(256) void k_conv(
    const float* __restrict__ xnT, const float2* __restrict__ kf,
    const float* __restrict__ D, const float2* __restrict__ tw, float* __restrict__ yT) {
  int blk = blockIdx.x;                 // b*128 + hp
  int b_ = blk >> 7, hp = blk & 127;
  int h0 = hp * 2, h1 = h0 + 1;
  int r0 = b_ * H + h0;
  int tid = threadIdx.x;
  __shared__ float2 bufA[FBUF], bufB[FBUF];
  float u0[4], u1[4];
  const float* x0 = xnT + (size_t)r0 * LL;
  const float* x1 = x0 + LL;
#pragma unroll
  for (int q = 0; q < 4; ++q) {
    int l = tid + (q << 8);
    float v0 = x0[l], v1 = x1[l];
    u0[q] = v0; u1[q] = v1;
    bufA[IDX2(l)] = make_float2(v0, v1);      // upper half implicit zero (PADDED)
  }
  fft2048<-1, true>(bufA, bufB, tw, tid);     // F = FFT(u0 + i*u1) in bufA
  const float2* kf0 = kf + (size_t)h0 * 1025;
  const float2* kf1 = kf + (size_t)h1 * 1025;
#pragma unroll
  for (int q = 0; q < 4; ++q) {
    int k = tid + (q << 8);
    if (k == 0) {
      float2 k0 = kf0[0], k1 = kf1[0];
      float2 F0 = bufA[IDX2(0)], Fn = bufA[IDX2(1024)];
      bufB[IDX2(0)]    = make_float2(F0.x * k0.x, F0.y * k1.x);
      float2 k0n = kf0[1024], k1n = kf1[1024];
      bufB[IDX2(1024)] = make_float2(Fn.x * k0n.x, Fn.y * k1n.x);
    } else {
      float2 F = bufA[IDX2(k)], G = bufA[IDX2(2048 - k)];
      float u0r = 0.5f * (F.x + G.x), u0i = 0.5f * (F.y - G.y);   // U0[k]
      float dr_ = 0.5f * (F.x - G.x), di_ = 0.5f * (F.y + G.y);
      float u1r = di_, u1i = -dr_;                                // U1[k]
      float2 k0 = kf0[k], k1 = kf1[k];
      float z0r = u0r * k0.x - u0i * k0.y, z0i = u0r * k0.y + u0i * k0.x;
      float z1r = u1r * k1.x - u1i * k1.y, z1i = u1r * k1.y + u1i * k1.x;
      bufB[IDX2(k)]        = make_float2(z0r - z1i, z0i + z1r);
      bufB[IDX2(2048 - k)] = make_float2(z0r + z1i, z1r - z0i);
    }
  }
  fft2048<1, false>(bufB, bufA, tw, tid);     // z0 + i*z1 in bufB (both real)
  float Dh0 = D[h0], Dh1 = D[h1];
  float* y0 = yT + (size_t)r0 * LL;
  float* y1 = y0 + LL;
#pragma unroll
  for (int q = 0; q < 4; ++q) {
    int l = tid + (q << 8);
    float2 z = bufB[IDX2(l)];
    y0[l] = z.x * (1.0f / NFFT) + Dh0 * u0[q];
    y1[l] = z.y * (1.0f / NFFT) + Dh1 * u1[q];
  }
}

// ---------------------------------------------------------------------------
// Mega MLP kernel with register-double-buffered weight staging:
//  A: v = x + yT-gather (registers); LN2 -> bf16 A1 in LDS
//  B: GEMM1 (K=256, 8 steps) — W1 step s+1 loaded to regs during step s MFMAs
//  C: GEMM2 (K=512, 16 steps) — same pipeline
//  D: vf = acc2 + b2 + v; next-layer LN1 + xnT write, or output projection.
// LDS overlay: A1[32][264]s @0 | B1[512][40]s @16896 | A2[32][520]s @0 |
//              B2[256][40]s @33280 | Txn/wlds (LAST) | red @57856
// ---------------------------------------------------------------------------
#define TXS 260
#define LOAD1(dst, kk) _Pragma("unroll") \
  for (int it = 0; it < 8; ++it) { int idx = tid + (it << 8); \
    dst[it] = *(const int4v*)(W1p + (size_t)(idx >> 2) * 256 + (kk) + (idx & 3) * 8); }
#define STORE1(src) _Pragma("unroll") \
  for (int it = 0; it < 8; ++it) { int idx = tid + (it << 8); \
    *(int4v*)&B1[(idx >> 2) * 40 + (idx & 3) * 8] = src[it]; }
#define LOAD2(dst, kk) _Pragma("unroll") \
  for (int it = 0; it < 4; ++it) { int idx = tid + (it << 8); \
    dst[it] = *(const int4v*)(W2p + (size_t)(idx >> 2) * 512 + (kk) + (idx & 3) * 8); }
#define STORE2(src) _Pragma("unroll") \
  for (int it = 0; it < 4; ++it) { int idx = tid + (it << 8); \
    *(int4v*)&B2[(idx >> 2) * 40 + (idx & 3) * 8] = src[it]; }

template <bool LAST>
__global__ __launch_bounds__(256, 1) void k_mlp(
    const short* __restrict__ W1p, const float* __restrict__ b1p,
    const short* __restrict__ W2p, const float* __restrict__ b2p,
    float* __restrict__ x, const float* __restrict__ yT,
    const float* __restrict__ ln2w, const float* __restrict__ ln2b,
    const float* __restrict__ ln1w, const float* __restrict__ ln1b,
    float* __restrict__ xnT,
    const float* __restrict__ Wout, const float* __restrict__ bout,
    float* __restrict__ out) {
  const int m0 = blockIdx.x * 32;
  const int b_ = m0 >> 10, l0 = m0 & 1023;
  const int tid = threadIdx.x;
  const int lane = tid & 63, wid = tid >> 6;
  const int rg = lane >> 4, cl = lane & 15;
  __shared__ __attribute__((aligned(16))) char smem[58880];
  short* A1  = (short*)smem;                 // [32][264]
  short* B1  = (short*)(smem + 16896);       // [512][40]
  short* A2  = (short*)smem;                 // [32][520]
  short* B2  = (short*)(smem + 33280);       // [256][40]
  float* Txn = (float*)smem;                 // [32][260] (LAST)
  float* wlds = (float*)(smem + 33280);      // [8][258]  (LAST)
  float* red = (float*)(smem + 57856);       // [4][32][2]

  // prefetch W1 K-step 0 immediately — hides under phase A
  int4v stA[8], stB[8];
  LOAD1(stA, 0);

  // ---- Phase A: residual add (registers) + LN2 -> A1 bf16 ----
  float v[2][4][4];
  float wl2[4], bl2[4];
#pragma unroll
  for (int n = 0; n < 4; ++n) {
    int col = wid * 64 + n * 16 + cl;
    wl2[n] = ln2w[col]; bl2[n] = ln2b[col];
  }
  float sum[2][4], sq[2][4];
#pragma unroll
  for (int m = 0; m < 2; ++m)
#pragma unroll
    for (int r = 0; r < 4; ++r) { sum[m][r] = 0.f; sq[m][r] = 0.f; }
#pragma unroll
  for (int m = 0; m < 2; ++m)
#pragma unroll
    for (int n = 0; n < 4; ++n) {
      int col = wid * 64 + n * 16 + cl;
      float4 y4 = *(const float4*)&yT[((size_t)(b_ * H + col)) * LL + l0 + m * 16 + rg * 4];
      float yv[4] = {y4.x, y4.y, y4.z, y4.w};
#pragma unroll
      for (int r = 0; r < 4; ++r) {
        int row = m * 16 + rg * 4 + r;
        float val = x[(size_t)(m0 + row) * H + col] + yv[r];
        v[m][n][r] = val;
        sum[m][r] += val; sq[m][r] += val * val;
      }
    }
#pragma unroll
  for (int m = 0; m < 2; ++m)
#pragma unroll
    for (int r = 0; r < 4; ++r) {
#pragma unroll
      for (int o = 1; o < 16; o <<= 1) {
        sum[m][r] += __shfl_xor(sum[m][r], o, 64);
        sq[m][r]  += __shfl_xor(sq[m][r], o, 64);
      }
    }
  if (cl == 0) {
#pragma unroll
    for (int m = 0; m < 2; ++m)
#pragma unroll
      for (int r = 0; r < 4; ++r) {
        int row = m * 16 + rg * 4 + r;
        red[(wid * 32 + row) * 2]     = sum[m][r];
        red[(wid * 32 + row) * 2 + 1] = sq[m][r];
      }
  }
  __syncthreads();
#pragma unroll
  for (int m = 0; m < 2; ++m)
#pragma unroll
    for (int r = 0; r < 4; ++r) {
      int row = m * 16 + rg * 4 + r;
      float S = 0.f, Q = 0.f;
#pragma unroll
      for (int w = 0; w < 4; ++w) { S += red[(w * 32 + row) * 2]; Q += red[(w * 32 + row) * 2 + 1]; }
      float mean = S * (1.0f / H);
      float var = Q * (1.0f / H) - mean * mean;
      float rs = rsqrtf(var + 1e-5f);
#pragma unroll
      for (int n = 0; n < 4; ++n) {
        int col = wid * 64 + n * 16 + cl;
        A1[row * 264 + col] = f2bf((v[m][n][r] - mean) * rs * wl2[n] + bl2[n]);
      }
    }

  // ---- Phase B: GEMM1 (32x512, K=256), pipelined weight staging ----
  f32x4 acc1[2][8];
#pragma unroll
  for (int m = 0; m < 2; ++m)
#pragma unroll
    for (int n = 0; n < 8; ++n) acc1[m][n] = (f32x4){0.f, 0.f, 0.f, 0.f};
#pragma unroll
  for (int s = 0; s < 8; ++s) {
    const int kk = s * 32;
    __syncthreads();                 // prev-step frag reads done (s=0: nothing)
    if (s & 1) { STORE1(stB); } else { STORE1(stA); }
    if (s < 7) {
      if (s & 1) { LOAD1(stA, kk + 32); } else { LOAD1(stB, kk + 32); }
    }
    __syncthreads();                 // B1 (and A1 at s=0) visible
    bf16x8 af[2], bfv[8];
#pragma unroll
    for (int m = 0; m < 2; ++m)
      af[m] = *(const bf16x8*)&A1[(m * 16 + cl) * 264 + kk + rg * 8];
#pragma unroll
    for (int n = 0; n < 8; ++n)
      bfv[n] = *(const bf16x8*)&B1[(wid * 128 + n * 16 + cl) * 40 + rg * 8];
#pragma unroll
    for (int m = 0; m < 2; ++m)
#pragma unroll
      for (int n = 0; n < 8; ++n)
        acc1[m][n] = __builtin_amdgcn_mfma_f32_16x16x32_bf16(af[m], bfv[n], acc1[m][n], 0, 0, 0);
  }
  // prefetch W2 K-step 0 — hides under GELU epilogue
  int4v s2A[4], s2B[4];
  LOAD2(s2A, 0);
  __syncthreads();   // A1/B1 dead
  // +b1, GELU -> A2 bf16
#pragma unroll
  for (int m = 0; m < 2; ++m)
#pragma unroll
    for (int n = 0; n < 8; ++n) {
      int col = wid * 128 + n * 16 + cl;
      float bb = b1p[col];
#pragma unroll
      for (int r = 0; r < 4; ++r) {
        int row = m * 16 + rg * 4 + r;
        float g = acc1[m][n][r] + bb;
        g = 0.5f * g * (1.0f + erff(g * 0.70710678118654752f));
        A2[row * 520 + col] = f2bf(g);
      }
    }

  // ---- Phase C: GEMM2 (32x256, K=512), pipelined weight staging ----
  f32x4 acc2[2][4];
#pragma unroll
  for (int m = 0; m < 2; ++m)
#pragma unroll
    for (int n = 0; n < 4; ++n) acc2[m][n] = (f32x4){0.f, 0.f, 0.f, 0.f};
#pragma unroll
  for (int s = 0; s < 16; ++s) {
    const int kk = s * 32;
    __syncthreads();
    if (s & 1) { STORE2(s2B); } else { STORE2(s2A); }
    if (s < 15) {
      if (s & 1) { LOAD2(s2A, kk + 32); } else { LOAD2(s2B, kk + 32); }
    }
    __syncthreads();
    bf16x8 af[2], bfv[4];
#pragma unroll
    for (int m = 0; m < 2; ++m)
      af[m] = *(const bf16x8*)&A2[(m * 16 + cl) * 520 + kk + rg * 8];
#pragma unroll
    for (int n = 0; n < 4; ++n)
      bfv[n] = *(const bf16x8*)&B2[(wid * 64 + n * 16 + cl) * 40 + rg * 8];
#pragma unroll
    for (int m = 0; m < 2; ++m)
#pragma unroll
      for (int n = 0; n < 4; ++n)
        acc2[m][n] = __builtin_amdgcn_mfma_f32_16x16x32_bf16(af[m], bfv[n], acc2[m][n], 0, 0, 0);
  }
  __syncthreads();   // A2/B2 dead

  // ---- Phase D: vf = acc2 + b2 + v; LN1-next + xnT | output proj ----
  float bv[4], wl1[4], bl1[4];
#pragma unroll
  for (int n = 0; n < 4; ++n) {
    int col = wid * 64 + n * 16 + cl;
    bv[n] = b2p[col];
    if (!LAST) { wl1[n] = ln1w[col]; bl1[n] = ln1b[col]; }
  }
#pragma unroll
  for (int m = 0; m < 2; ++m)
#pragma unroll
    for (int r = 0; r < 4; ++r) { sum[m][r] = 0.f; sq[m][r] = 0.f; }
#pragma unroll
  for (int m = 0; m < 2; ++m)
#pragma unroll
    for (int n = 0; n < 4; ++n) {
      int col = wid * 64 + n * 16 + cl;
#pragma unroll
      for (int r = 0; r < 4; ++r) {
        int row = m * 16 + rg * 4 + r;
        float vf = acc2[m][n][r] + bv[n] + v[m][n][r];
        acc2[m][n][r] = vf;
        if (LAST) Txn[row * TXS + col] = vf;
        sum[m][r] += vf; sq[m][r] += vf * vf;
      }
    }

  if (LAST) {
#pragma unroll
    for (int it = 0; it < 8; ++it) {
      int idx = tid + (it << 8);
      wlds[(idx >> 8) * 258 + (idx & 255)] = Wout[idx];
    }
    __syncthreads();
    int row = tid >> 3, co = tid & 7;
    float p = bout[co];
    const float* tr = Txn + row * TXS;
    const float* wr = wlds + co * 258;
#pragma unroll 4
    for (int c = 0; c < H; ++c) p += tr[c] * wr[c];
    out[((b_ * COUT + co) << 10) + l0 + row] = p;
  } else {
#pragma unroll
    for (int m = 0; m < 2; ++m)
#pragma unroll
      for (int r = 0; r < 4; ++r) {
#pragma unroll
        for (int o = 1; o < 16; o <<= 1) {
          sum[m][r] += __shfl_xor(sum[m][r], o, 64);
          sq[m][r]  += __shfl_xor(sq[m][r], o, 64);
        }
      }
    if (cl == 0) {
#pragma unroll
      for (int m = 0; m < 2; ++m)
#pragma unroll
        for (int r = 0; r < 4; ++r) {
          int row = m * 16 + rg * 4 + r;
          red[(wid * 32 + row) * 2]     = sum[m][r];
          red[(wid * 32 + row) * 2 + 1] = sq[m][r];
        }
    }
    __syncthreads();
#pragma unroll
    for (int m = 0; m < 2; ++m) {
#pragma unroll
      for (int r = 0; r < 4; ++r) {
        int row = m * 16 + rg * 4 + r;
        float S = 0.f, Q = 0.f;
#pragma unroll
        for (int w = 0; w < 4; ++w) { S += red[(w * 32 + row) * 2]; Q += red[(w * 32 + row) * 2 + 1]; }
        float mean = S * (1.0f / H);
        float var = Q * (1.0f / H) - mean * mean;
        float rs = rsqrtf(var + 1e-5f);
#pragma unroll
        for (int n = 0; n < 4; ++n) {
          int col = wid * 64 + n * 16 + cl;
          float vf = acc2[m][n][r];
          x[(size_t)(m0 + row) * H + col] = vf;
          Txn[row * TXS + col] = (vf - mean) * rs * wl1[n] + bl1[n];
        }
      }
    }
    __syncthreads();
    float tmp[32];
#pragma unroll
    for (int l = 0; l < 32; ++l) tmp[l] = Txn[l * TXS + tid];
    float* dst = xnT + ((size_t)(b_ * H + tid)) * LL + l0;
#pragma unroll
    for (int l = 0; l < 32; l += 4) {
      float4 v4 = {tmp[l], tmp[l + 1], tmp[l + 2], tmp[l + 3]};
      *(float4*)&dst[l] = v4;
    }
  }
}

extern "C" void kernel_launch(void* const* d_in, const int* in_sizes, int n_in,
                              void* d_out, int out_size, void* d_ws, size_t ws_size,
                              hipStream_t stream) {
  const float* stim  = (const float*)d_in[0];
  const float* init  = (const float*)d_in[1];
  const float* A_re  = (const float*)d_in[2];
  const float* A_im  = (const float*)d_in[3];
  const float* C_re  = (const float*)d_in[4];
  const float* C_im  = (const float*)d_in[5];
  const float* Dp    = (const float*)d_in[6];
  const float* lstep = (const float*)d_in[7];
  const float* ln1w  = (const float*)d_in[8];
  const float* ln1b  = (const float*)d_in[9];
  const float* ln2w  = (const float*)d_in[10];
  const float* ln2b  = (const float*)d_in[11];
  const float* W1    = (const float*)d_in[12];
  const float* b1    = (const float*)d_in[13];
  const float* W2    = (const float*)d_in[14];
  const float* b2    = (const float*)d_in[15];
  const float* Win   = (const float*)d_in[16];
  const float* bin   = (const float*)d_in[17];
  const float* Wst   = (const float*)d_in[18];
  const float* bst   = (const float*)d_in[19];
  const float* Wout  = (const float*)d_in[20];
  const float* bout  = (const float*)d_in[21];
  float* out = (float*)d_out;
  float* ws = (float*)d_ws;

  size_t o = 0;
  auto alloc = [&](size_t nfloats) { size_t r = o; o += (nfloats + 63) & ~(size_t)63; return r; };
  float*  x    = ws + alloc((size_t)BB * LL * H);
  float*  xnT  = ws + alloc((size_t)BB * H * LL);
  float*  yT   = ws + alloc((size_t)BB * H * LL);
  float2* kf   = (float2*)(ws + alloc((size_t)NL * H * 1025 * 2));
  short*  W1bf = (short*)(ws + alloc((size_t)NL * 512 * 256 / 2));
  short*  W2bf = (short*)(ws + alloc((size_t)NL * 256 * 512 / 2));
  float*  WinT = ws + alloc((size_t)64 * 256);
  float*  sp   = ws + alloc((size_t)BB * H);
  float2* tw   = (float2*)(ws + alloc((size_t)2048 * 2));
  (void)ws_size; (void)in_sizes; (void)n_in; (void)out_size;

  k_setup<<<2048, 256, 0, stream>>>(W1, W2, Win, init, Wst, bst, bin,
                                    W1bf, W2bf, WinT, sp, tw);
  k_kernelfft<<<NL * H, 256, 0, stream>>>(A_re, A_im, C_re, C_im, lstep, tw, kf);
  k_in_ln1<<<BB * 64, 256, 0, stream>>>(stim, WinT, sp, ln1w, ln1b, x, xnT);

  for (int i = 0; i < NL; ++i) {
    k_conv<<<BB * H / 2, 256, 0, stream>>>(xnT, kf + (size_t)i * H * 1025,
                                           Dp + i * H, tw, yT);
    if (i < NL - 1) {
      k_mlp<false><<<256, 256, 0, stream>>>(
          W1bf + (size_t)i * 512 * 256, b1 + i * 512,
          W2bf + (size_t)i * 256 * 512, b2 + i * H,
          x, yT, ln2w + i * H, ln2b + i * H,
          ln1w + (i + 1) * H, ln1b + (i + 1) * H, xnT,
          nullptr, nullptr, nullptr);
    } else {
      k_mlp<true><<<256, 256, 0, stream>>>(
          W1bf + (size_t)i * 512 * 256, b1 + i * 512,
          W2bf + (size_t)i * 256 * 512, b2 + i * H,
          x, yT, ln2w + i * H, ln2b + i * H,
          nullptr, nullptr, nullptr,
          Wout, bout, out);
    }
  }
}